// Round 1
// baseline (834.080 us; speedup 1.0000x reference)
//
#include <hip/hip_runtime.h>
#include <cstdint>
#include <cstddef>

// ---------------------------------------------------------------------------
// TGNN fused pipeline v8 = v7 with seg_kernel re-tiled from M=64 (50-row
// half-segments, 2 blocks/CU) to M=32 (25-row quarter-segments, 4 blocks/CU).
// Theory: v7 was latency-bound at 2 waves/SIMD (MfmaUtil 31.7, VALUBusy 20.9,
// Occupancy 22.3 -- no pipe saturated). LDS/block 71680->35840 doubles
// residency. Row-padding ratio unchanged (25/32 == 50/64), total MFMA same.
// Register lesson (R3/R4/R6): unified VGPR+AGPR file. Peak live acc halves
// (96->48 regs), so (256,4)'s 128-VGPR cap is safe; watch for spills anyway.
// ---------------------------------------------------------------------------

typedef __bf16 bf16;
typedef __attribute__((ext_vector_type(8))) __bf16 bf16x8;
typedef __attribute__((ext_vector_type(4))) __bf16 bf16x4;
typedef __attribute__((ext_vector_type(4))) float floatx4;

#define GRP 100
#define RQ 25           // rows per quarter-segment

// packed-ws element offsets (bf16 elements)
#define WOFF_AW 0
#define WOFF_BW 8192
#define WOFF_P1 12288
#define WOFF_P2 208896
#define WOFF_P3 339968
#define WOFF_F1 602112
#define WOFF_F2 1126400
#define WOFF_PS 1142784          // partial sums [8000][1024] bf16
#define WOFF_H2 9334784          // h2 [2000][512] bf16

// LDS strides (bf16 elems): %8==0 (16B-aligned b128 rows)
#define LSTR_P  168
#define LSTR_H  392
#define LSTR_H2 136
#define LSTR_H3 264

static __device__ __forceinline__ floatx4 mfma16(bf16x8 a, bf16x8 b, floatx4 c) {
  return __builtin_amdgcn_mfma_f32_16x16x32_bf16(a, b, c, 0, 0, 0);
}

// ---------------------------------------------------------------------------
// Coalesced weight repack: 32k x 64n tiles through an LDS transpose.
// fp32 [K][N] row-major -> bf16 ((nc*KT+kt)*CW + nl)*32 + kk, CW=128.
// 550 standard tiles + 16 tiles for f2w (CW=32). Proven correct in R6.
// (byte-identical to v7)
// ---------------------------------------------------------------------------
__global__ __launch_bounds__(256) void pack_lds(
    const float* __restrict__ aw, const float* __restrict__ bw,
    const float* __restrict__ p1w, const float* __restrict__ p2w,
    const float* __restrict__ p3w, const float* __restrict__ f1w,
    const float* __restrict__ f2w, bf16* __restrict__ wpk) {
  __shared__ float t[32][65];
  const int tid = threadIdx.x;
  int b = blockIdx.x;

  if (b < 550) {
    const float* src; int dstoff, K, N, tt;
    if (b < 4)        { src = aw;  dstoff = WOFF_AW; K = 64;   N = 128;  tt = b; }
    else if (b < 6)   { src = bw;  dstoff = WOFF_BW; K = 32;   N = 128;  tt = b - 4; }
    else if (b < 102) { src = p1w; dstoff = WOFF_P1; K = 384;  N = 512;  tt = b - 6; }
    else if (b < 166) { src = p2w; dstoff = WOFF_P2; K = 512;  N = 256;  tt = b - 102; }
    else if (b < 294) { src = p3w; dstoff = WOFF_P3; K = 256;  N = 1024; tt = b - 166; }
    else              { src = f1w; dstoff = WOFF_F1; K = 1024; N = 512;  tt = b - 294; }
    const int KT = K >> 5;
    const int kt = tt % KT;
    const int n0 = (tt / KT) * 64;
    for (int i = tid; i < 2048; i += 256) {
      int r = i >> 6, c = i & 63;
      t[r][c] = src[(size_t)(kt * 32 + r) * N + n0 + c];
    }
    __syncthreads();
    const int nc = n0 >> 7, nl0 = n0 & 127;
    bf16* dst = wpk + dstoff + ((size_t)(nc * KT + kt) * 128 + nl0) * 32;
    int o = tid * 8;
    int nl = o >> 5, kk = o & 31;
    bf16x8 v;
#pragma unroll
    for (int i = 0; i < 8; ++i) v[i] = (bf16)t[kk + i][nl];
    *(bf16x8*)(dst + nl * 32 + kk) = v;
  } else {
    const int kt = b - 550;
    for (int i = tid; i < 1024; i += 256) {
      int r = i >> 5, c = i & 31;
      t[r][c] = f2w[(size_t)(kt * 32 + r) * 32 + c];
    }
    __syncthreads();
    if (tid < 128) {
      int o = tid * 8;
      int nl = o >> 5, kk = o & 31;
      bf16x8 v;
#pragma unroll
      for (int i = 0; i < 8; ++i) v[i] = (bf16)t[kk + i][nl];
      *(bf16x8*)(wpk + WOFF_F2 + kt * 1024 + nl * 32 + kk) = v;
    }
  }
}

// kstep, 2 B-frags from global: 2 A-reads, 4 MFMA (M=32: mt<2)
static __device__ __forceinline__ void kstep2(const bf16* __restrict__ Ab,
                                              int astride, int acol,
                                              const bf16* __restrict__ b0p,
                                              const bf16* __restrict__ b1p,
                                              floatx4* acc, int lm, int lq) {
  bf16x8 b0 = *(const bf16x8*)b0p;
  bf16x8 b1 = *(const bf16x8*)b1p;
#pragma unroll
  for (int mt = 0; mt < 2; ++mt) {
    bf16x8 a = *(const bf16x8*)(Ab + (mt * 16 + lm) * astride + acol + lq * 8);
    acc[mt * 2]     = mfma16(a, b0, acc[mt * 2]);
    acc[mt * 2 + 1] = mfma16(a, b1, acc[mt * 2 + 1]);
  }
}

// kstep, 4 consecutive B-frags from global: 2 A-reads, 8 MFMA (M=32)
static __device__ __forceinline__ void kstep4(const bf16* __restrict__ Ab,
                                              int astride, int acol,
                                              const bf16* __restrict__ bp,
                                              floatx4* acc, int lm, int lq) {
  bf16x8 bf[4];
#pragma unroll
  for (int j = 0; j < 4; ++j) bf[j] = *(const bf16x8*)(bp + j * 512);
#pragma unroll
  for (int mt = 0; mt < 2; ++mt) {
    bf16x8 a = *(const bf16x8*)(Ab + (mt * 16 + lm) * astride + acol + lq * 8);
#pragma unroll
    for (int j = 0; j < 4; ++j)
      acc[mt * 4 + j] = mfma16(a, bf[j], acc[mt * 4 + j]);
  }
}

// epilogue for 2-N-tile acc: relu(acc+bias) -> LDS (M=32: mt<2)
static __device__ __forceinline__ void epi2(const floatx4* acc,
                                            const float* __restrict__ bias,
                                            bf16* dst, int dstride, int w,
                                            int lm, int lq) {
#pragma unroll
  for (int mt = 0; mt < 2; ++mt)
#pragma unroll
    for (int j = 0; j < 2; ++j) {
      int col = (w + 4 * j) * 16 + lm;
      float bv = bias[col];
      floatx4 c = acc[mt * 2 + j];
#pragma unroll
      for (int r = 0; r < 4; ++r) {
        float v = c[r] + bv;
        v = v > 0.f ? v : 0.f;
        dst[(mt * 16 + lq * 4 + r) * dstride + col] = (bf16)v;
      }
    }
}

// ---------------------------------------------------------------------------
// seg_kernel: one block per QUARTER-segment (25 rows, M=32).
// LDS: hbuf 25088 + pbuf 10752 = 35840 B -> 4 blocks/CU (16 waves/CU).
// ---------------------------------------------------------------------------
__global__ __launch_bounds__(256, 4) void seg_kernel(
    const float* __restrict__ pairs, const float* __restrict__ ab,
    const float* __restrict__ bb, const float* __restrict__ p1b,
    const float* __restrict__ p2b, const bf16* __restrict__ wpk,
    bf16* __restrict__ psum) {
  __shared__ __align__(16) bf16 hbuf[32 * LSTR_H];  // h[32,384] then h3[32,256]
  __shared__ __align__(16) bf16 pbuf[32 * LSTR_P];  // pairs bf16, then h2 chunk

  const int tid = threadIdx.x;
  const int w = tid >> 6;
  const int lane = tid & 63;
  const int lm = lane & 15;
  const int lq = lane >> 4;
  const int blk = blockIdx.x;

  // ---- stage pairs quarter-tile [25,160] fp32 -> bf16 LDS, zero pad rows ----
  {
    const float4* src = (const float4*)(pairs + (size_t)blk * (RQ * 160));
    for (int i = tid; i < RQ * 40; i += 256) {
      int row = i / 40;
      int c4 = (i - row * 40) * 4;
      float4 v = src[i];
      bf16x4 o = {(bf16)v.x, (bf16)v.y, (bf16)v.z, (bf16)v.w};
      *(bf16x4*)(pbuf + row * LSTR_P + c4) = o;
    }
    for (int i = tid; i < 7 * 160; i += 256) {
      int row = RQ + i / 160;
      int c = i - (i / 160) * 160;
      pbuf[row * LSTR_P + c] = (bf16)0.0f;
    }
  }
  __syncthreads();

  const floatx4 fz = {0.f, 0.f, 0.f, 0.f};
  floatx4 acc[8];
  floatx4 acc3[8];

  // ---------------- embed: a1 / a2 / be -> hbuf[32,384] ----------------
#pragma unroll
  for (int t = 0; t < 4; ++t) acc[t] = fz;
#pragma unroll
  for (int kt = 0; kt < 2; ++kt)
    kstep2(pbuf, LSTR_P, kt * 32,
           wpk + WOFF_AW + ((size_t)(kt * 128 + w * 16 + lm)) * 32 + lq * 8,
           wpk + WOFF_AW + ((size_t)(kt * 128 + (w + 4) * 16 + lm)) * 32 + lq * 8,
           acc, lm, lq);
  epi2(acc, ab, hbuf, LSTR_H, w, lm, lq);
#pragma unroll
  for (int t = 0; t < 4; ++t) acc[t] = fz;
#pragma unroll
  for (int kt = 0; kt < 2; ++kt)
    kstep2(pbuf, LSTR_P, 64 + kt * 32,
           wpk + WOFF_AW + ((size_t)(kt * 128 + w * 16 + lm)) * 32 + lq * 8,
           wpk + WOFF_AW + ((size_t)(kt * 128 + (w + 4) * 16 + lm)) * 32 + lq * 8,
           acc, lm, lq);
  epi2(acc, ab, hbuf + 128, LSTR_H, w, lm, lq);
#pragma unroll
  for (int t = 0; t < 4; ++t) acc[t] = fz;
  kstep2(pbuf, LSTR_P, 128,
         wpk + WOFF_BW + ((size_t)(w * 16 + lm)) * 32 + lq * 8,
         wpk + WOFF_BW + ((size_t)((w + 4) * 16 + lm)) * 32 + lq * 8,
         acc, lm, lq);
  epi2(acc, bb, hbuf + 256, LSTR_H, w, lm, lq);

  __syncthreads();

  // ------- p1 (4 N-chunks of 128), each fused into p2 K-accumulation -------
#pragma unroll
  for (int t = 0; t < 8; ++t) acc3[t] = fz;

  for (int nc = 0; nc < 4; ++nc) {
#pragma unroll
    for (int t = 0; t < 4; ++t) acc[t] = fz;
#pragma unroll
    for (int kt = 0; kt < 12; ++kt)
      kstep2(hbuf, LSTR_H, kt * 32,
             wpk + WOFF_P1 + ((size_t)((nc * 12 + kt) * 128 + w * 16 + lm)) * 32 + lq * 8,
             wpk + WOFF_P1 + ((size_t)((nc * 12 + kt) * 128 + (w + 4) * 16 + lm)) * 32 + lq * 8,
             acc, lm, lq);
    __syncthreads();                       // prior p2 reads of pbuf done
    epi2(acc, p1b + nc * 128, pbuf, LSTR_H2, w, lm, lq);
    __syncthreads();                       // h2 chunk visible
#pragma unroll
    for (int kt2 = 0; kt2 < 4; ++kt2)
      kstep4(pbuf, LSTR_H2, kt2 * 32,
             wpk + WOFF_P2 +
                 ((size_t)(((w >> 1) * 16 + nc * 4 + kt2) * 128 + (w & 1) * 64 + lm)) * 32 +
                 lq * 8,
             acc3, lm, lq);
  }

  // p2 epilogue: h3 = relu(acc3 + p2b) -> hbuf (stride 264)
#pragma unroll
  for (int mt = 0; mt < 2; ++mt)
#pragma unroll
    for (int s = 0; s < 4; ++s) {
      int cl = w * 64 + s * 16 + lm;
      float bv = p2b[cl];
      floatx4 c = acc3[mt * 4 + s];
#pragma unroll
      for (int r = 0; r < 4; ++r) {
        float v = c[r] + bv;
        v = v > 0.f ? v : 0.f;
        hbuf[(mt * 16 + lq * 4 + r) * LSTR_H3 + cl] = (bf16)v;
      }
    }
  __syncthreads();

  // ---------------- p3 (4 N-chunks of 256) + masked column sums ----------
  // valid rows: 0..24. mt=0 rows 0..15 all; mt=1 rows 16+lq*4+r:
  // lq<2 -> all 4, lq==2 -> r==0 only (row 24), lq==3 -> none.
  const int wn = w >> 1;
  const int wl = (w & 1) * 64;
  for (int c = 0; c < 4; ++c) {
#pragma unroll
    for (int t = 0; t < 8; ++t) acc[t] = fz;
#pragma unroll
    for (int kt = 0; kt < 8; ++kt)
      kstep4(hbuf, LSTR_H3, kt * 32,
             wpk + WOFF_P3 + ((size_t)(((2 * c + wn) * 8 + kt) * 128 + wl + lm)) * 32 + lq * 8,
             acc, lm, lq);
#pragma unroll
    for (int j = 0; j < 4; ++j) {
      floatx4 c0 = acc[j];
      floatx4 c1 = acc[4 + j];
      float cs = c0[0] + c0[1] + c0[2] + c0[3];
      if (lq < 2)       cs += c1[0] + c1[1] + c1[2] + c1[3];
      else if (lq == 2) cs += c1[0];
      cs += __shfl_xor(cs, 16, 64);
      cs += __shfl_xor(cs, 32, 64);
      if (lq == 0) {
        int col = c * 256 + w * 64 + j * 16 + lm;
        psum[(size_t)blk * 1024 + col] = (bf16)cs;
      }
    }
  }
}

// ---------------------------------------------------------------------------
// head1: combine (mean + p3 bias) + f1 chunk. 500 blocks = 125 row-groups
// x 4 col-chunks of 128. Now combines 4 quarter-segment partial sums.
// ---------------------------------------------------------------------------
__global__ __launch_bounds__(256, 2) void head1_kernel(
    const bf16* __restrict__ wpk, const bf16* __restrict__ psum,
    const int* __restrict__ idxp, const float* __restrict__ p3b,
    const float* __restrict__ f1b, bf16* __restrict__ h2) {
  __shared__ __align__(16) bf16 hp[16 * 1032];

  const int tid = threadIdx.x;
  const int w = tid >> 6;
  const int lane = tid & 63;
  const int lm = lane & 15;
  const int lq = lane >> 4;
  const int rg = blockIdx.x >> 2;
  const int cc = blockIdx.x & 3;
  const int r0 = rg * 16;
  const floatx4 fz = {0.f, 0.f, 0.f, 0.f};

  for (int i = tid; i < 16 * 1024; i += 256) {
    int row = i >> 10;
    int c = i & 1023;
    int seg = r0 + row;
    float s = (float)psum[(size_t)(4 * seg) * 1024 + c] +
              (float)psum[(size_t)(4 * seg + 1) * 1024 + c] +
              (float)psum[(size_t)(4 * seg + 2) * 1024 + c] +
              (float)psum[(size_t)(4 * seg + 3) * 1024 + c];
    hp[row * 1032 + c] = (bf16)(s / (float)idxp[seg] + p3b[c]);
  }
  __syncthreads();

  floatx4 a2[2];
  a2[0] = fz; a2[1] = fz;
#pragma unroll 8
  for (int kt = 0; kt < 32; ++kt) {
    bf16x8 a = *(const bf16x8*)(hp + lm * 1032 + kt * 32 + lq * 8);
#pragma unroll
    for (int j = 0; j < 2; ++j) {
      bf16x8 b = *(const bf16x8*)(wpk + WOFF_F1 +
                    ((size_t)((cc * 32 + kt) * 128 + (2 * w + j) * 16 + lm)) * 32 + lq * 8);
      a2[j] = mfma16(a, b, a2[j]);
    }
  }
#pragma unroll
  for (int j = 0; j < 2; ++j) {
    int col = cc * 128 + (2 * w + j) * 16 + lm;
    float bv = f1b[col];
#pragma unroll
    for (int r = 0; r < 4; ++r) {
      float v = a2[j][r] + bv;
      v = v > 0.f ? v : 0.f;
      h2[(size_t)(r0 + lq * 4 + r) * 512 + col] = (bf16)v;
    }
  }
}

// ---------------------------------------------------------------------------
// head2: f2 (relu) + f3. Wave-per-16-rows, 32 blocks x 4 waves. (unchanged)
// ---------------------------------------------------------------------------
__global__ __launch_bounds__(256, 2) void head2_kernel(
    const bf16* __restrict__ wpk, const bf16* __restrict__ h2,
    const float* __restrict__ f2b, const float* __restrict__ f3w,
    const float* __restrict__ f3b, float* __restrict__ out) {
  __shared__ __align__(16) bf16 h3s[4][16 * 40];

  const int tid = threadIdx.x;
  const int w = tid >> 6;
  const int lane = tid & 63;
  const int lm = lane & 15;
  const int lq = lane >> 4;
  const int rg = blockIdx.x * 4 + w;
  if (rg >= 125) return;
  const int r0 = rg * 16;
  const floatx4 fz = {0.f, 0.f, 0.f, 0.f};

  floatx4 c2[2];
  c2[0] = fz; c2[1] = fz;
#pragma unroll
  for (int kt = 0; kt < 16; ++kt) {
    bf16x8 a = *(const bf16x8*)(h2 + (size_t)(r0 + lm) * 512 + kt * 32 + lq * 8);
#pragma unroll
    for (int j = 0; j < 2; ++j) {
      bf16x8 b = *(const bf16x8*)(wpk + WOFF_F2 +
                    ((size_t)(kt * 32 + j * 16 + lm)) * 32 + lq * 8);
      c2[j] = mfma16(a, b, c2[j]);
    }
  }
#pragma unroll
  for (int j = 0; j < 2; ++j) {
    int col = j * 16 + lm;
    float bv = f2b[col];
#pragma unroll
    for (int r = 0; r < 4; ++r) {
      float v = c2[j][r] + bv;
      v = v > 0.f ? v : 0.f;
      h3s[w][(lq * 4 + r) * 40 + col] = (bf16)v;
    }
  }
  float ps = 0.f;
#pragma unroll
  for (int jj = 0; jj < 8; ++jj)
    ps += (float)h3s[w][lm * 40 + lq * 8 + jj] * f3w[lq * 8 + jj];
  ps += __shfl_xor(ps, 16, 64);
  ps += __shfl_xor(ps, 32, 64);
  if (lq == 0) out[r0 + lm] = ps + f3b[0];
}

// ---------------------------------------------------------------------------
extern "C" void kernel_launch(void* const* d_in, const int* in_sizes, int n_in,
                              void* d_out, int out_size, void* d_ws,
                              size_t ws_size, hipStream_t stream) {
  (void)in_sizes; (void)n_in; (void)out_size; (void)ws_size;
  const float* pairs = (const float*)d_in[0];
  const int*   idxp  = (const int*)d_in[1];
  // d_in[2] = ref_feats (unused by the reference)
  const float* aw  = (const float*)d_in[3];
  const float* ab  = (const float*)d_in[4];
  const float* bw  = (const float*)d_in[5];
  const float* bb  = (const float*)d_in[6];
  const float* p1w = (const float*)d_in[7];
  const float* p1b = (const float*)d_in[8];
  const float* p2w = (const float*)d_in[9];
  const float* p2b = (const float*)d_in[10];
  const float* p3w = (const float*)d_in[11];
  const float* p3b = (const float*)d_in[12];
  const float* f1w = (const float*)d_in[13];
  const float* f1b = (const float*)d_in[14];
  const float* f2w = (const float*)d_in[15];
  const float* f2b = (const float*)d_in[16];
  const float* f3w = (const float*)d_in[17];
  const float* f3b = (const float*)d_in[18];

  bf16* wpk = (bf16*)d_ws;

  pack_lds<<<566, 256, 0, stream>>>(aw, bw, p1w, p2w, p3w, f1w, f2w, wpk);
  seg_kernel<<<8000, 256, 0, stream>>>(pairs, ab, bb, p1b, p2b, wpk,
                                       wpk + WOFF_PS);
  head1_kernel<<<500, 256, 0, stream>>>(wpk, wpk + WOFF_PS, idxp, p3b, f1b,
                                        wpk + WOFF_H2);
  head2_kernel<<<32, 256, 0, stream>>>(wpk, wpk + WOFF_H2, f2b, f3w, f3b,
                                       (float*)d_out);
}

// Round 2
// 787.555 us; speedup vs baseline: 1.0591x; 1.0591x over previous
//
#include <hip/hip_runtime.h>
#include <cstdint>
#include <cstddef>

// ---------------------------------------------------------------------------
// TGNN fused pipeline v9 = v8 (M=32 quarter-segments) with seg_kernel
// launch_bounds (256,4) -> (256,3).
// v8 post-mortem: (256,4) caps unified VGPR+AGPR at 128/wave; compiler split
// 64 arch + 64 acc and spilled the ~90-reg arch live set to scratch
// (WRITE_SIZE 8MB -> 107MB, VGPR_Count 64, MfmaUtil 19.5). Theory intact:
// occupancy is the lever, spill was the poison.
// v9 target: 3 waves/SIMD (cap ~170 regs) holds ~100 arch + 48 acc spill-free.
// M=32 peak acc-live: p1/p2 fusion acc3[8]+acc[4] = 48 regs; p3 acc[8] = 32.
// LDS 35840 B allows 4 blocks/CU -> registers are the binding limit at 3.
// Pass/fail signal: WRITE_SIZE ~16.5MB (psum only) = no spill.
// ---------------------------------------------------------------------------

typedef __bf16 bf16;
typedef __attribute__((ext_vector_type(8))) __bf16 bf16x8;
typedef __attribute__((ext_vector_type(4))) __bf16 bf16x4;
typedef __attribute__((ext_vector_type(4))) float floatx4;

#define GRP 100
#define RQ 25           // rows per quarter-segment

// packed-ws element offsets (bf16 elements)
#define WOFF_AW 0
#define WOFF_BW 8192
#define WOFF_P1 12288
#define WOFF_P2 208896
#define WOFF_P3 339968
#define WOFF_F1 602112
#define WOFF_F2 1126400
#define WOFF_PS 1142784          // partial sums [8000][1024] bf16
#define WOFF_H2 9334784          // h2 [2000][512] bf16

// LDS strides (bf16 elems): %8==0 (16B-aligned b128 rows)
#define LSTR_P  168
#define LSTR_H  392
#define LSTR_H2 136
#define LSTR_H3 264

static __device__ __forceinline__ floatx4 mfma16(bf16x8 a, bf16x8 b, floatx4 c) {
  return __builtin_amdgcn_mfma_f32_16x16x32_bf16(a, b, c, 0, 0, 0);
}

// ---------------------------------------------------------------------------
// Coalesced weight repack: 32k x 64n tiles through an LDS transpose.
// fp32 [K][N] row-major -> bf16 ((nc*KT+kt)*CW + nl)*32 + kk, CW=128.
// 550 standard tiles + 16 tiles for f2w (CW=32). Proven correct in R6.
// (byte-identical to v7/v8)
// ---------------------------------------------------------------------------
__global__ __launch_bounds__(256) void pack_lds(
    const float* __restrict__ aw, const float* __restrict__ bw,
    const float* __restrict__ p1w, const float* __restrict__ p2w,
    const float* __restrict__ p3w, const float* __restrict__ f1w,
    const float* __restrict__ f2w, bf16* __restrict__ wpk) {
  __shared__ float t[32][65];
  const int tid = threadIdx.x;
  int b = blockIdx.x;

  if (b < 550) {
    const float* src; int dstoff, K, N, tt;
    if (b < 4)        { src = aw;  dstoff = WOFF_AW; K = 64;   N = 128;  tt = b; }
    else if (b < 6)   { src = bw;  dstoff = WOFF_BW; K = 32;   N = 128;  tt = b - 4; }
    else if (b < 102) { src = p1w; dstoff = WOFF_P1; K = 384;  N = 512;  tt = b - 6; }
    else if (b < 166) { src = p2w; dstoff = WOFF_P2; K = 512;  N = 256;  tt = b - 102; }
    else if (b < 294) { src = p3w; dstoff = WOFF_P3; K = 256;  N = 1024; tt = b - 166; }
    else              { src = f1w; dstoff = WOFF_F1; K = 1024; N = 512;  tt = b - 294; }
    const int KT = K >> 5;
    const int kt = tt % KT;
    const int n0 = (tt / KT) * 64;
    for (int i = tid; i < 2048; i += 256) {
      int r = i >> 6, c = i & 63;
      t[r][c] = src[(size_t)(kt * 32 + r) * N + n0 + c];
    }
    __syncthreads();
    const int nc = n0 >> 7, nl0 = n0 & 127;
    bf16* dst = wpk + dstoff + ((size_t)(nc * KT + kt) * 128 + nl0) * 32;
    int o = tid * 8;
    int nl = o >> 5, kk = o & 31;
    bf16x8 v;
#pragma unroll
    for (int i = 0; i < 8; ++i) v[i] = (bf16)t[kk + i][nl];
    *(bf16x8*)(dst + nl * 32 + kk) = v;
  } else {
    const int kt = b - 550;
    for (int i = tid; i < 1024; i += 256) {
      int r = i >> 5, c = i & 31;
      t[r][c] = f2w[(size_t)(kt * 32 + r) * 32 + c];
    }
    __syncthreads();
    if (tid < 128) {
      int o = tid * 8;
      int nl = o >> 5, kk = o & 31;
      bf16x8 v;
#pragma unroll
      for (int i = 0; i < 8; ++i) v[i] = (bf16)t[kk + i][nl];
      *(bf16x8*)(wpk + WOFF_F2 + kt * 1024 + nl * 32 + kk) = v;
    }
  }
}

// kstep, 2 B-frags from global: 2 A-reads, 4 MFMA (M=32: mt<2)
static __device__ __forceinline__ void kstep2(const bf16* __restrict__ Ab,
                                              int astride, int acol,
                                              const bf16* __restrict__ b0p,
                                              const bf16* __restrict__ b1p,
                                              floatx4* acc, int lm, int lq) {
  bf16x8 b0 = *(const bf16x8*)b0p;
  bf16x8 b1 = *(const bf16x8*)b1p;
#pragma unroll
  for (int mt = 0; mt < 2; ++mt) {
    bf16x8 a = *(const bf16x8*)(Ab + (mt * 16 + lm) * astride + acol + lq * 8);
    acc[mt * 2]     = mfma16(a, b0, acc[mt * 2]);
    acc[mt * 2 + 1] = mfma16(a, b1, acc[mt * 2 + 1]);
  }
}

// kstep, 4 consecutive B-frags from global: 2 A-reads, 8 MFMA (M=32)
static __device__ __forceinline__ void kstep4(const bf16* __restrict__ Ab,
                                              int astride, int acol,
                                              const bf16* __restrict__ bp,
                                              floatx4* acc, int lm, int lq) {
  bf16x8 bf[4];
#pragma unroll
  for (int j = 0; j < 4; ++j) bf[j] = *(const bf16x8*)(bp + j * 512);
#pragma unroll
  for (int mt = 0; mt < 2; ++mt) {
    bf16x8 a = *(const bf16x8*)(Ab + (mt * 16 + lm) * astride + acol + lq * 8);
#pragma unroll
    for (int j = 0; j < 4; ++j)
      acc[mt * 4 + j] = mfma16(a, bf[j], acc[mt * 4 + j]);
  }
}

// epilogue for 2-N-tile acc: relu(acc+bias) -> LDS (M=32: mt<2)
static __device__ __forceinline__ void epi2(const floatx4* acc,
                                            const float* __restrict__ bias,
                                            bf16* dst, int dstride, int w,
                                            int lm, int lq) {
#pragma unroll
  for (int mt = 0; mt < 2; ++mt)
#pragma unroll
    for (int j = 0; j < 2; ++j) {
      int col = (w + 4 * j) * 16 + lm;
      float bv = bias[col];
      floatx4 c = acc[mt * 2 + j];
#pragma unroll
      for (int r = 0; r < 4; ++r) {
        float v = c[r] + bv;
        v = v > 0.f ? v : 0.f;
        dst[(mt * 16 + lq * 4 + r) * dstride + col] = (bf16)v;
      }
    }
}

// ---------------------------------------------------------------------------
// seg_kernel: one block per QUARTER-segment (25 rows, M=32).
// LDS: hbuf 25088 + pbuf 10752 = 35840 B (4 blocks/CU possible);
// registers bind at 3 waves/SIMD under (256,3).
// ---------------------------------------------------------------------------
__global__ __launch_bounds__(256, 3) void seg_kernel(
    const float* __restrict__ pairs, const float* __restrict__ ab,
    const float* __restrict__ bb, const float* __restrict__ p1b,
    const float* __restrict__ p2b, const bf16* __restrict__ wpk,
    bf16* __restrict__ psum) {
  __shared__ __align__(16) bf16 hbuf[32 * LSTR_H];  // h[32,384] then h3[32,256]
  __shared__ __align__(16) bf16 pbuf[32 * LSTR_P];  // pairs bf16, then h2 chunk

  const int tid = threadIdx.x;
  const int w = tid >> 6;
  const int lane = tid & 63;
  const int lm = lane & 15;
  const int lq = lane >> 4;
  const int blk = blockIdx.x;

  // ---- stage pairs quarter-tile [25,160] fp32 -> bf16 LDS, zero pad rows ----
  {
    const float4* src = (const float4*)(pairs + (size_t)blk * (RQ * 160));
    for (int i = tid; i < RQ * 40; i += 256) {
      int row = i / 40;
      int c4 = (i - row * 40) * 4;
      float4 v = src[i];
      bf16x4 o = {(bf16)v.x, (bf16)v.y, (bf16)v.z, (bf16)v.w};
      *(bf16x4*)(pbuf + row * LSTR_P + c4) = o;
    }
    for (int i = tid; i < 7 * 160; i += 256) {
      int row = RQ + i / 160;
      int c = i - (i / 160) * 160;
      pbuf[row * LSTR_P + c] = (bf16)0.0f;
    }
  }
  __syncthreads();

  const floatx4 fz = {0.f, 0.f, 0.f, 0.f};
  floatx4 acc[8];
  floatx4 acc3[8];

  // ---------------- embed: a1 / a2 / be -> hbuf[32,384] ----------------
#pragma unroll
  for (int t = 0; t < 4; ++t) acc[t] = fz;
#pragma unroll
  for (int kt = 0; kt < 2; ++kt)
    kstep2(pbuf, LSTR_P, kt * 32,
           wpk + WOFF_AW + ((size_t)(kt * 128 + w * 16 + lm)) * 32 + lq * 8,
           wpk + WOFF_AW + ((size_t)(kt * 128 + (w + 4) * 16 + lm)) * 32 + lq * 8,
           acc, lm, lq);
  epi2(acc, ab, hbuf, LSTR_H, w, lm, lq);
#pragma unroll
  for (int t = 0; t < 4; ++t) acc[t] = fz;
#pragma unroll
  for (int kt = 0; kt < 2; ++kt)
    kstep2(pbuf, LSTR_P, 64 + kt * 32,
           wpk + WOFF_AW + ((size_t)(kt * 128 + w * 16 + lm)) * 32 + lq * 8,
           wpk + WOFF_AW + ((size_t)(kt * 128 + (w + 4) * 16 + lm)) * 32 + lq * 8,
           acc, lm, lq);
  epi2(acc, ab, hbuf + 128, LSTR_H, w, lm, lq);
#pragma unroll
  for (int t = 0; t < 4; ++t) acc[t] = fz;
  kstep2(pbuf, LSTR_P, 128,
         wpk + WOFF_BW + ((size_t)(w * 16 + lm)) * 32 + lq * 8,
         wpk + WOFF_BW + ((size_t)((w + 4) * 16 + lm)) * 32 + lq * 8,
         acc, lm, lq);
  epi2(acc, bb, hbuf + 256, LSTR_H, w, lm, lq);

  __syncthreads();

  // ------- p1 (4 N-chunks of 128), each fused into p2 K-accumulation -------
#pragma unroll
  for (int t = 0; t < 8; ++t) acc3[t] = fz;

  for (int nc = 0; nc < 4; ++nc) {
#pragma unroll
    for (int t = 0; t < 4; ++t) acc[t] = fz;
#pragma unroll
    for (int kt = 0; kt < 12; ++kt)
      kstep2(hbuf, LSTR_H, kt * 32,
             wpk + WOFF_P1 + ((size_t)((nc * 12 + kt) * 128 + w * 16 + lm)) * 32 + lq * 8,
             wpk + WOFF_P1 + ((size_t)((nc * 12 + kt) * 128 + (w + 4) * 16 + lm)) * 32 + lq * 8,
             acc, lm, lq);
    __syncthreads();                       // prior p2 reads of pbuf done
    epi2(acc, p1b + nc * 128, pbuf, LSTR_H2, w, lm, lq);
    __syncthreads();                       // h2 chunk visible
#pragma unroll
    for (int kt2 = 0; kt2 < 4; ++kt2)
      kstep4(pbuf, LSTR_H2, kt2 * 32,
             wpk + WOFF_P2 +
                 ((size_t)(((w >> 1) * 16 + nc * 4 + kt2) * 128 + (w & 1) * 64 + lm)) * 32 +
                 lq * 8,
             acc3, lm, lq);
  }

  // p2 epilogue: h3 = relu(acc3 + p2b) -> hbuf (stride 264)
#pragma unroll
  for (int mt = 0; mt < 2; ++mt)
#pragma unroll
    for (int s = 0; s < 4; ++s) {
      int cl = w * 64 + s * 16 + lm;
      float bv = p2b[cl];
      floatx4 c = acc3[mt * 4 + s];
#pragma unroll
      for (int r = 0; r < 4; ++r) {
        float v = c[r] + bv;
        v = v > 0.f ? v : 0.f;
        hbuf[(mt * 16 + lq * 4 + r) * LSTR_H3 + cl] = (bf16)v;
      }
    }
  __syncthreads();

  // ---------------- p3 (4 N-chunks of 256) + masked column sums ----------
  // valid rows: 0..24. mt=0 rows 0..15 all; mt=1 rows 16+lq*4+r:
  // lq<2 -> all 4, lq==2 -> r==0 only (row 24), lq==3 -> none.
  const int wn = w >> 1;
  const int wl = (w & 1) * 64;
  for (int c = 0; c < 4; ++c) {
#pragma unroll
    for (int t = 0; t < 8; ++t) acc[t] = fz;
#pragma unroll
    for (int kt = 0; kt < 8; ++kt)
      kstep4(hbuf, LSTR_H3, kt * 32,
             wpk + WOFF_P3 + ((size_t)(((2 * c + wn) * 8 + kt) * 128 + wl + lm)) * 32 + lq * 8,
             acc, lm, lq);
#pragma unroll
    for (int j = 0; j < 4; ++j) {
      floatx4 c0 = acc[j];
      floatx4 c1 = acc[4 + j];
      float cs = c0[0] + c0[1] + c0[2] + c0[3];
      if (lq < 2)       cs += c1[0] + c1[1] + c1[2] + c1[3];
      else if (lq == 2) cs += c1[0];
      cs += __shfl_xor(cs, 16, 64);
      cs += __shfl_xor(cs, 32, 64);
      if (lq == 0) {
        int col = c * 256 + w * 64 + j * 16 + lm;
        psum[(size_t)blk * 1024 + col] = (bf16)cs;
      }
    }
  }
}

// ---------------------------------------------------------------------------
// head1: combine (mean + p3 bias) + f1 chunk. 500 blocks = 125 row-groups
// x 4 col-chunks of 128. Combines 4 quarter-segment partial sums.
// ---------------------------------------------------------------------------
__global__ __launch_bounds__(256, 2) void head1_kernel(
    const bf16* __restrict__ wpk, const bf16* __restrict__ psum,
    const int* __restrict__ idxp, const float* __restrict__ p3b,
    const float* __restrict__ f1b, bf16* __restrict__ h2) {
  __shared__ __align__(16) bf16 hp[16 * 1032];

  const int tid = threadIdx.x;
  const int w = tid >> 6;
  const int lane = tid & 63;
  const int lm = lane & 15;
  const int lq = lane >> 4;
  const int rg = blockIdx.x >> 2;
  const int cc = blockIdx.x & 3;
  const int r0 = rg * 16;
  const floatx4 fz = {0.f, 0.f, 0.f, 0.f};

  for (int i = tid; i < 16 * 1024; i += 256) {
    int row = i >> 10;
    int c = i & 1023;
    int seg = r0 + row;
    float s = (float)psum[(size_t)(4 * seg) * 1024 + c] +
              (float)psum[(size_t)(4 * seg + 1) * 1024 + c] +
              (float)psum[(size_t)(4 * seg + 2) * 1024 + c] +
              (float)psum[(size_t)(4 * seg + 3) * 1024 + c];
    hp[row * 1032 + c] = (bf16)(s / (float)idxp[seg] + p3b[c]);
  }
  __syncthreads();

  floatx4 a2[2];
  a2[0] = fz; a2[1] = fz;
#pragma unroll 8
  for (int kt = 0; kt < 32; ++kt) {
    bf16x8 a = *(const bf16x8*)(hp + lm * 1032 + kt * 32 + lq * 8);
#pragma unroll
    for (int j = 0; j < 2; ++j) {
      bf16x8 b = *(const bf16x8*)(wpk + WOFF_F1 +
                    ((size_t)((cc * 32 + kt) * 128 + (2 * w + j) * 16 + lm)) * 32 + lq * 8);
      a2[j] = mfma16(a, b, a2[j]);
    }
  }
#pragma unroll
  for (int j = 0; j < 2; ++j) {
    int col = cc * 128 + (2 * w + j) * 16 + lm;
    float bv = f1b[col];
#pragma unroll
    for (int r = 0; r < 4; ++r) {
      float v = a2[j][r] + bv;
      v = v > 0.f ? v : 0.f;
      h2[(size_t)(r0 + lq * 4 + r) * 512 + col] = (bf16)v;
    }
  }
}

// ---------------------------------------------------------------------------
// head2: f2 (relu) + f3. Wave-per-16-rows, 32 blocks x 4 waves. (unchanged)
// ---------------------------------------------------------------------------
__global__ __launch_bounds__(256, 2) void head2_kernel(
    const bf16* __restrict__ wpk, const bf16* __restrict__ h2,
    const float* __restrict__ f2b, const float* __restrict__ f3w,
    const float* __restrict__ f3b, float* __restrict__ out) {
  __shared__ __align__(16) bf16 h3s[4][16 * 40];

  const int tid = threadIdx.x;
  const int w = tid >> 6;
  const int lane = tid & 63;
  const int lm = lane & 15;
  const int lq = lane >> 4;
  const int rg = blockIdx.x * 4 + w;
  if (rg >= 125) return;
  const int r0 = rg * 16;
  const floatx4 fz = {0.f, 0.f, 0.f, 0.f};

  floatx4 c2[2];
  c2[0] = fz; c2[1] = fz;
#pragma unroll
  for (int kt = 0; kt < 16; ++kt) {
    bf16x8 a = *(const bf16x8*)(h2 + (size_t)(r0 + lm) * 512 + kt * 32 + lq * 8);
#pragma unroll
    for (int j = 0; j < 2; ++j) {
      bf16x8 b = *(const bf16x8*)(wpk + WOFF_F2 +
                    ((size_t)(kt * 32 + j * 16 + lm)) * 32 + lq * 8);
      c2[j] = mfma16(a, b, c2[j]);
    }
  }
#pragma unroll
  for (int j = 0; j < 2; ++j) {
    int col = j * 16 + lm;
    float bv = f2b[col];
#pragma unroll
    for (int r = 0; r < 4; ++r) {
      float v = c2[j][r] + bv;
      v = v > 0.f ? v : 0.f;
      h3s[w][(lq * 4 + r) * 40 + col] = (bf16)v;
    }
  }
  float ps = 0.f;
#pragma unroll
  for (int jj = 0; jj < 8; ++jj)
    ps += (float)h3s[w][lm * 40 + lq * 8 + jj] * f3w[lq * 8 + jj];
  ps += __shfl_xor(ps, 16, 64);
  ps += __shfl_xor(ps, 32, 64);
  if (lq == 0) out[r0 + lm] = ps + f3b[0];
}

// ---------------------------------------------------------------------------
extern "C" void kernel_launch(void* const* d_in, const int* in_sizes, int n_in,
                              void* d_out, int out_size, void* d_ws,
                              size_t ws_size, hipStream_t stream) {
  (void)in_sizes; (void)n_in; (void)out_size; (void)ws_size;
  const float* pairs = (const float*)d_in[0];
  const int*   idxp  = (const int*)d_in[1];
  // d_in[2] = ref_feats (unused by the reference)
  const float* aw  = (const float*)d_in[3];
  const float* ab  = (const float*)d_in[4];
  const float* bw  = (const float*)d_in[5];
  const float* bb  = (const float*)d_in[6];
  const float* p1w = (const float*)d_in[7];
  const float* p1b = (const float*)d_in[8];
  const float* p2w = (const float*)d_in[9];
  const float* p2b = (const float*)d_in[10];
  const float* p3w = (const float*)d_in[11];
  const float* p3b = (const float*)d_in[12];
  const float* f1w = (const float*)d_in[13];
  const float* f1b = (const float*)d_in[14];
  const float* f2w = (const float*)d_in[15];
  const float* f2b = (const float*)d_in[16];
  const float* f3w = (const float*)d_in[17];
  const float* f3b = (const float*)d_in[18];

  bf16* wpk = (bf16*)d_ws;

  pack_lds<<<566, 256, 0, stream>>>(aw, bw, p1w, p2w, p3w, f1w, f2w, wpk);
  seg_kernel<<<8000, 256, 0, stream>>>(pairs, ab, bb, p1b, p2b, wpk,
                                       wpk + WOFF_PS);
  head1_kernel<<<500, 256, 0, stream>>>(wpk, wpk + WOFF_PS, idxp, p3b, f1b,
                                        wpk + WOFF_H2);
  head2_kernel<<<32, 256, 0, stream>>>(wpk, wpk + WOFF_H2, f2b, f3w, f3b,
                                       (float*)d_out);
}

// Round 3
// 586.525 us; speedup vs baseline: 1.4221x; 1.3427x over previous
//
#include <hip/hip_runtime.h>
#include <cstdint>
#include <cstddef>

// ---------------------------------------------------------------------------
// TGNN fused pipeline v10 = v7 (M=64, proven 431us seg_kernel) with the
// 22% zero-row padding eliminated via sliding 64-row windows.
// v8/v9 post-mortem: M=32 halved MFMA per K-step but kept the same B-loads/
// addressing/barriers -> overhead:MFMA doubled; more occupancy couldn't pay
// for it (MfmaUtil*dur invariant: v7 137, v9 135). M=64 restored.
// v10: 3125 blocks cover rows [64b, 64b+64) with NO padding (GROUP=100 > 64
// so a window straddles at most 2 segments). p3 column-sum splits at
// sp = 100*(s0+1) - 64*blk via 0/1 mask (cs0 = masked fma-sum, cs1 = tot-cs0),
// writes psum[2b] (seg s0) and psum[2b+1] (seg s0+1). head1 gathers the 2-3
// contributing blocks per segment; empty slot-1 entries are never read.
// Register lesson (R3/R4/R6/v8): unified VGPR+AGPR file; live set ~220 ->
// keep __launch_bounds__(256,2); anything tighter spills (WRITE_SIZE check).
// ---------------------------------------------------------------------------

typedef __bf16 bf16;
typedef __attribute__((ext_vector_type(8))) __bf16 bf16x8;
typedef __attribute__((ext_vector_type(4))) __bf16 bf16x4;
typedef __attribute__((ext_vector_type(4))) float floatx4;

#define GRP 100
#define NWIN 3125        // 200000 rows / 64

// packed-ws element offsets (bf16 elements)
#define WOFF_AW 0
#define WOFF_BW 8192
#define WOFF_P1 12288
#define WOFF_P2 208896
#define WOFF_P3 339968
#define WOFF_F1 602112
#define WOFF_F2 1126400
#define WOFF_PS 1142784          // partial sums [6250][1024] bf16
#define WOFF_H2 7542784          // h2 [2000][512] bf16

// LDS strides (bf16 elems): %8==0 (16B-aligned b128 rows)
#define LSTR_P  168
#define LSTR_H  392
#define LSTR_H2 136
#define LSTR_H3 264

static __device__ __forceinline__ floatx4 mfma16(bf16x8 a, bf16x8 b, floatx4 c) {
  return __builtin_amdgcn_mfma_f32_16x16x32_bf16(a, b, c, 0, 0, 0);
}

// ---------------------------------------------------------------------------
// Coalesced weight repack: 32k x 64n tiles through an LDS transpose.
// fp32 [K][N] row-major -> bf16 ((nc*KT+kt)*CW + nl)*32 + kk, CW=128.
// 550 standard tiles + 16 tiles for f2w (CW=32). Proven correct in R6.
// (byte-identical to v7)
// ---------------------------------------------------------------------------
__global__ __launch_bounds__(256) void pack_lds(
    const float* __restrict__ aw, const float* __restrict__ bw,
    const float* __restrict__ p1w, const float* __restrict__ p2w,
    const float* __restrict__ p3w, const float* __restrict__ f1w,
    const float* __restrict__ f2w, bf16* __restrict__ wpk) {
  __shared__ float t[32][65];
  const int tid = threadIdx.x;
  int b = blockIdx.x;

  if (b < 550) {
    const float* src; int dstoff, K, N, tt;
    if (b < 4)        { src = aw;  dstoff = WOFF_AW; K = 64;   N = 128;  tt = b; }
    else if (b < 6)   { src = bw;  dstoff = WOFF_BW; K = 32;   N = 128;  tt = b - 4; }
    else if (b < 102) { src = p1w; dstoff = WOFF_P1; K = 384;  N = 512;  tt = b - 6; }
    else if (b < 166) { src = p2w; dstoff = WOFF_P2; K = 512;  N = 256;  tt = b - 102; }
    else if (b < 294) { src = p3w; dstoff = WOFF_P3; K = 256;  N = 1024; tt = b - 166; }
    else              { src = f1w; dstoff = WOFF_F1; K = 1024; N = 512;  tt = b - 294; }
    const int KT = K >> 5;
    const int kt = tt % KT;
    const int n0 = (tt / KT) * 64;
    for (int i = tid; i < 2048; i += 256) {
      int r = i >> 6, c = i & 63;
      t[r][c] = src[(size_t)(kt * 32 + r) * N + n0 + c];
    }
    __syncthreads();
    const int nc = n0 >> 7, nl0 = n0 & 127;
    bf16* dst = wpk + dstoff + ((size_t)(nc * KT + kt) * 128 + nl0) * 32;
    int o = tid * 8;
    int nl = o >> 5, kk = o & 31;
    bf16x8 v;
#pragma unroll
    for (int i = 0; i < 8; ++i) v[i] = (bf16)t[kk + i][nl];
    *(bf16x8*)(dst + nl * 32 + kk) = v;
  } else {
    const int kt = b - 550;
    for (int i = tid; i < 1024; i += 256) {
      int r = i >> 5, c = i & 31;
      t[r][c] = f2w[(size_t)(kt * 32 + r) * 32 + c];
    }
    __syncthreads();
    if (tid < 128) {
      int o = tid * 8;
      int nl = o >> 5, kk = o & 31;
      bf16x8 v;
#pragma unroll
      for (int i = 0; i < 8; ++i) v[i] = (bf16)t[kk + i][nl];
      *(bf16x8*)(wpk + WOFF_F2 + kt * 1024 + nl * 32 + kk) = v;
    }
  }
}

// kstep, 2 B-frags from global: 4 A-reads, 8 MFMA (M=64)
static __device__ __forceinline__ void kstep2(const bf16* __restrict__ Ab,
                                              int astride, int acol,
                                              const bf16* __restrict__ b0p,
                                              const bf16* __restrict__ b1p,
                                              floatx4* acc, int lm, int lq) {
  bf16x8 b0 = *(const bf16x8*)b0p;
  bf16x8 b1 = *(const bf16x8*)b1p;
#pragma unroll
  for (int mt = 0; mt < 4; ++mt) {
    bf16x8 a = *(const bf16x8*)(Ab + (mt * 16 + lm) * astride + acol + lq * 8);
    acc[mt * 2]     = mfma16(a, b0, acc[mt * 2]);
    acc[mt * 2 + 1] = mfma16(a, b1, acc[mt * 2 + 1]);
  }
}

// kstep, 4 consecutive B-frags from global: 4 A-reads, 16 MFMA (M=64)
static __device__ __forceinline__ void kstep4(const bf16* __restrict__ Ab,
                                              int astride, int acol,
                                              const bf16* __restrict__ bp,
                                              floatx4* acc, int lm, int lq) {
  bf16x8 bf[4];
#pragma unroll
  for (int j = 0; j < 4; ++j) bf[j] = *(const bf16x8*)(bp + j * 512);
#pragma unroll
  for (int mt = 0; mt < 4; ++mt) {
    bf16x8 a = *(const bf16x8*)(Ab + (mt * 16 + lm) * astride + acol + lq * 8);
#pragma unroll
    for (int j = 0; j < 4; ++j)
      acc[mt * 4 + j] = mfma16(a, bf[j], acc[mt * 4 + j]);
  }
}

// epilogue for 2-N-tile acc: relu(acc+bias) -> LDS (M=64)
static __device__ __forceinline__ void epi2(const floatx4* acc,
                                            const float* __restrict__ bias,
                                            bf16* dst, int dstride, int w,
                                            int lm, int lq) {
#pragma unroll
  for (int mt = 0; mt < 4; ++mt)
#pragma unroll
    for (int j = 0; j < 2; ++j) {
      int col = (w + 4 * j) * 16 + lm;
      float bv = bias[col];
      floatx4 c = acc[mt * 2 + j];
#pragma unroll
      for (int r = 0; r < 4; ++r) {
        float v = c[r] + bv;
        v = v > 0.f ? v : 0.f;
        dst[(mt * 16 + lq * 4 + r) * dstride + col] = (bf16)v;
      }
    }
}

// ---------------------------------------------------------------------------
// seg_kernel: one block per 64-row WINDOW (no padding). Window straddles at
// most 2 segments; p3 column-sums are split at the boundary into 2 psum slots.
// LDS: hbuf 50176 + pbuf 21504 = 71680 B -> 2 blocks/CU.
// ---------------------------------------------------------------------------
__global__ __launch_bounds__(256, 2) void seg_kernel(
    const float* __restrict__ pairs, const float* __restrict__ ab,
    const float* __restrict__ bb, const float* __restrict__ p1b,
    const float* __restrict__ p2b, const bf16* __restrict__ wpk,
    bf16* __restrict__ psum) {
  __shared__ __align__(16) bf16 hbuf[64 * LSTR_H];  // h[64,384] then h3[64,256]
  __shared__ __align__(16) bf16 pbuf[64 * LSTR_P];  // pairs bf16, then h2 chunk

  const int tid = threadIdx.x;
  const int w = tid >> 6;
  const int lane = tid & 63;
  const int lm = lane & 15;
  const int lq = lane >> 4;
  const int blk = blockIdx.x;

  // ---- stage pairs window [64,160] fp32 -> bf16 LDS (all rows valid) ----
  {
    const float4* src = (const float4*)(pairs + (size_t)blk * (64 * 160));
    for (int i = tid; i < 64 * 40; i += 256) {
      int row = i / 40;
      int c4 = (i - row * 40) * 4;
      float4 v = src[i];
      bf16x4 o = {(bf16)v.x, (bf16)v.y, (bf16)v.z, (bf16)v.w};
      *(bf16x4*)(pbuf + row * LSTR_P + c4) = o;
    }
  }
  __syncthreads();

  const floatx4 fz = {0.f, 0.f, 0.f, 0.f};
  floatx4 acc[16];
  floatx4 acc3[16];

  // ---------------- embed: a1 / a2 / be -> hbuf[64,384] ----------------
#pragma unroll
  for (int t = 0; t < 8; ++t) acc[t] = fz;
#pragma unroll
  for (int kt = 0; kt < 2; ++kt)
    kstep2(pbuf, LSTR_P, kt * 32,
           wpk + WOFF_AW + ((size_t)(kt * 128 + w * 16 + lm)) * 32 + lq * 8,
           wpk + WOFF_AW + ((size_t)(kt * 128 + (w + 4) * 16 + lm)) * 32 + lq * 8,
           acc, lm, lq);
  epi2(acc, ab, hbuf, LSTR_H, w, lm, lq);
#pragma unroll
  for (int t = 0; t < 8; ++t) acc[t] = fz;
#pragma unroll
  for (int kt = 0; kt < 2; ++kt)
    kstep2(pbuf, LSTR_P, 64 + kt * 32,
           wpk + WOFF_AW + ((size_t)(kt * 128 + w * 16 + lm)) * 32 + lq * 8,
           wpk + WOFF_AW + ((size_t)(kt * 128 + (w + 4) * 16 + lm)) * 32 + lq * 8,
           acc, lm, lq);
  epi2(acc, ab, hbuf + 128, LSTR_H, w, lm, lq);
#pragma unroll
  for (int t = 0; t < 8; ++t) acc[t] = fz;
  kstep2(pbuf, LSTR_P, 128,
         wpk + WOFF_BW + ((size_t)(w * 16 + lm)) * 32 + lq * 8,
         wpk + WOFF_BW + ((size_t)((w + 4) * 16 + lm)) * 32 + lq * 8,
         acc, lm, lq);
  epi2(acc, bb, hbuf + 256, LSTR_H, w, lm, lq);

  __syncthreads();

  // ------- p1 (4 N-chunks of 128), each fused into p2 K-accumulation -------
#pragma unroll
  for (int t = 0; t < 16; ++t) acc3[t] = fz;

  for (int nc = 0; nc < 4; ++nc) {
#pragma unroll
    for (int t = 0; t < 8; ++t) acc[t] = fz;
#pragma unroll
    for (int kt = 0; kt < 12; ++kt)
      kstep2(hbuf, LSTR_H, kt * 32,
             wpk + WOFF_P1 + ((size_t)((nc * 12 + kt) * 128 + w * 16 + lm)) * 32 + lq * 8,
             wpk + WOFF_P1 + ((size_t)((nc * 12 + kt) * 128 + (w + 4) * 16 + lm)) * 32 + lq * 8,
             acc, lm, lq);
    __syncthreads();                       // prior p2 reads of pbuf done
    epi2(acc, p1b + nc * 128, pbuf, LSTR_H2, w, lm, lq);
    __syncthreads();                       // h2 chunk visible
#pragma unroll
    for (int kt2 = 0; kt2 < 4; ++kt2)
      kstep4(pbuf, LSTR_H2, kt2 * 32,
             wpk + WOFF_P2 +
                 ((size_t)(((w >> 1) * 16 + nc * 4 + kt2) * 128 + (w & 1) * 64 + lm)) * 32 +
                 lq * 8,
             acc3, lm, lq);
  }

  // p2 epilogue: h3 = relu(acc3 + p2b) -> hbuf (stride 264)
#pragma unroll
  for (int mt = 0; mt < 4; ++mt)
#pragma unroll
    for (int s = 0; s < 4; ++s) {
      int cl = w * 64 + s * 16 + lm;
      float bv = p2b[cl];
      floatx4 c = acc3[mt * 4 + s];
#pragma unroll
      for (int r = 0; r < 4; ++r) {
        float v = c[r] + bv;
        v = v > 0.f ? v : 0.f;
        hbuf[(mt * 16 + lq * 4 + r) * LSTR_H3 + cl] = (bf16)v;
      }
    }
  __syncthreads();

  // ------- p3 (4 N-chunks of 256) + straddle-split column sums -------
  // Window rows [64*blk, 64*blk+64) straddle segments s0, s0+1 at local
  // row sp = 100*(s0+1) - 64*blk (sp>=64 -> single segment, cs1 = ~0,
  // written to a slot head1 provably never reads).
  const int wn = w >> 1;
  const int wl = (w & 1) * 64;
  const int s0 = (64 * blk) / 100;
  const int sp = (s0 + 1) * 100 - 64 * blk;
  floatx4 msk[4];
#pragma unroll
  for (int mt = 0; mt < 4; ++mt)
#pragma unroll
    for (int r = 0; r < 4; ++r)
      msk[mt][r] = (mt * 16 + lq * 4 + r < sp) ? 1.f : 0.f;

  for (int c = 0; c < 4; ++c) {
#pragma unroll
    for (int t = 0; t < 16; ++t) acc[t] = fz;
#pragma unroll
    for (int kt = 0; kt < 8; ++kt)
      kstep4(hbuf, LSTR_H3, kt * 32,
             wpk + WOFF_P3 + ((size_t)(((2 * c + wn) * 8 + kt) * 128 + wl + lm)) * 32 + lq * 8,
             acc, lm, lq);
#pragma unroll
    for (int j = 0; j < 4; ++j) {
      float tot = 0.f, cs0 = 0.f;
#pragma unroll
      for (int mt = 0; mt < 4; ++mt) {
        floatx4 cc = acc[mt * 4 + j];
#pragma unroll
        for (int r = 0; r < 4; ++r) {
          tot += cc[r];
          cs0 = fmaf(cc[r], msk[mt][r], cs0);
        }
      }
      float cs1 = tot - cs0;
      cs0 += __shfl_xor(cs0, 16, 64);
      cs0 += __shfl_xor(cs0, 32, 64);
      cs1 += __shfl_xor(cs1, 16, 64);
      cs1 += __shfl_xor(cs1, 32, 64);
      if (lq == 0) {
        int col = c * 256 + w * 64 + j * 16 + lm;
        psum[(size_t)(2 * blk) * 1024 + col]     = (bf16)cs0;
        psum[(size_t)(2 * blk + 1) * 1024 + col] = (bf16)cs1;
      }
    }
  }
}

// ---------------------------------------------------------------------------
// head1: combine (mean + p3 bias) + f1 chunk. 500 blocks = 125 row-groups
// x 4 col-chunks of 128. Gathers 2-3 straddle-window partials per segment:
// blocks b in [(100s)>>6, (100s+99)>>6], slot 0 iff 64b >= 100s.
// ---------------------------------------------------------------------------
__global__ __launch_bounds__(256, 2) void head1_kernel(
    const bf16* __restrict__ wpk, const bf16* __restrict__ psum,
    const int* __restrict__ idxp, const float* __restrict__ p3b,
    const float* __restrict__ f1b, bf16* __restrict__ h2) {
  __shared__ __align__(16) bf16 hp[16 * 1032];

  const int tid = threadIdx.x;
  const int w = tid >> 6;
  const int lane = tid & 63;
  const int lm = lane & 15;
  const int lq = lane >> 4;
  const int rg = blockIdx.x >> 2;
  const int cc = blockIdx.x & 3;
  const int r0 = rg * 16;
  const floatx4 fz = {0.f, 0.f, 0.f, 0.f};

  for (int i = tid; i < 16 * 1024; i += 256) {
    int row = i >> 10;
    int c = i & 1023;
    int seg = r0 + row;
    int b_lo = (100 * seg) >> 6;
    int b_hi = (100 * seg + 99) >> 6;
    float s = 0.f;
    for (int b = b_lo; b <= b_hi; ++b) {
      int slot = (64 * b >= 100 * seg) ? 0 : 1;
      s += (float)psum[(size_t)(2 * b + slot) * 1024 + c];
    }
    hp[row * 1032 + c] = (bf16)(s / (float)idxp[seg] + p3b[c]);
  }
  __syncthreads();

  floatx4 a2[2];
  a2[0] = fz; a2[1] = fz;
#pragma unroll 8
  for (int kt = 0; kt < 32; ++kt) {
    bf16x8 a = *(const bf16x8*)(hp + lm * 1032 + kt * 32 + lq * 8);
#pragma unroll
    for (int j = 0; j < 2; ++j) {
      bf16x8 b = *(const bf16x8*)(wpk + WOFF_F1 +
                    ((size_t)((cc * 32 + kt) * 128 + (2 * w + j) * 16 + lm)) * 32 + lq * 8);
      a2[j] = mfma16(a, b, a2[j]);
    }
  }
#pragma unroll
  for (int j = 0; j < 2; ++j) {
    int col = cc * 128 + (2 * w + j) * 16 + lm;
    float bv = f1b[col];
#pragma unroll
    for (int r = 0; r < 4; ++r) {
      float v = a2[j][r] + bv;
      v = v > 0.f ? v : 0.f;
      h2[(size_t)(r0 + lq * 4 + r) * 512 + col] = (bf16)v;
    }
  }
}

// ---------------------------------------------------------------------------
// head2: f2 (relu) + f3. Wave-per-16-rows, 32 blocks x 4 waves. (unchanged)
// ---------------------------------------------------------------------------
__global__ __launch_bounds__(256, 2) void head2_kernel(
    const bf16* __restrict__ wpk, const bf16* __restrict__ h2,
    const float* __restrict__ f2b, const float* __restrict__ f3w,
    const float* __restrict__ f3b, float* __restrict__ out) {
  __shared__ __align__(16) bf16 h3s[4][16 * 40];

  const int tid = threadIdx.x;
  const int w = tid >> 6;
  const int lane = tid & 63;
  const int lm = lane & 15;
  const int lq = lane >> 4;
  const int rg = blockIdx.x * 4 + w;
  if (rg >= 125) return;
  const int r0 = rg * 16;
  const floatx4 fz = {0.f, 0.f, 0.f, 0.f};

  floatx4 c2[2];
  c2[0] = fz; c2[1] = fz;
#pragma unroll
  for (int kt = 0; kt < 16; ++kt) {
    bf16x8 a = *(const bf16x8*)(h2 + (size_t)(r0 + lm) * 512 + kt * 32 + lq * 8);
#pragma unroll
    for (int j = 0; j < 2; ++j) {
      bf16x8 b = *(const bf16x8*)(wpk + WOFF_F2 +
                    ((size_t)(kt * 32 + j * 16 + lm)) * 32 + lq * 8);
      c2[j] = mfma16(a, b, c2[j]);
    }
  }
#pragma unroll
  for (int j = 0; j < 2; ++j) {
    int col = j * 16 + lm;
    float bv = f2b[col];
#pragma unroll
    for (int r = 0; r < 4; ++r) {
      float v = c2[j][r] + bv;
      v = v > 0.f ? v : 0.f;
      h3s[w][(lq * 4 + r) * 40 + col] = (bf16)v;
    }
  }
  float ps = 0.f;
#pragma unroll
  for (int jj = 0; jj < 8; ++jj)
    ps += (float)h3s[w][lm * 40 + lq * 8 + jj] * f3w[lq * 8 + jj];
  ps += __shfl_xor(ps, 16, 64);
  ps += __shfl_xor(ps, 32, 64);
  if (lq == 0) out[r0 + lm] = ps + f3b[0];
}

// ---------------------------------------------------------------------------
extern "C" void kernel_launch(void* const* d_in, const int* in_sizes, int n_in,
                              void* d_out, int out_size, void* d_ws,
                              size_t ws_size, hipStream_t stream) {
  (void)in_sizes; (void)n_in; (void)out_size; (void)ws_size;
  const float* pairs = (const float*)d_in[0];
  const int*   idxp  = (const int*)d_in[1];
  // d_in[2] = ref_feats (unused by the reference)
  const float* aw  = (const float*)d_in[3];
  const float* ab  = (const float*)d_in[4];
  const float* bw  = (const float*)d_in[5];
  const float* bb  = (const float*)d_in[6];
  const float* p1w = (const float*)d_in[7];
  const float* p1b = (const float*)d_in[8];
  const float* p2w = (const float*)d_in[9];
  const float* p2b = (const float*)d_in[10];
  const float* p3w = (const float*)d_in[11];
  const float* p3b = (const float*)d_in[12];
  const float* f1w = (const float*)d_in[13];
  const float* f1b = (const float*)d_in[14];
  const float* f2w = (const float*)d_in[15];
  const float* f2b = (const float*)d_in[16];
  const float* f3w = (const float*)d_in[17];
  const float* f3b = (const float*)d_in[18];

  bf16* wpk = (bf16*)d_ws;

  pack_lds<<<566, 256, 0, stream>>>(aw, bw, p1w, p2w, p3w, f1w, f2w, wpk);
  seg_kernel<<<NWIN, 256, 0, stream>>>(pairs, ab, bb, p1b, p2b, wpk,
                                       wpk + WOFF_PS);
  head1_kernel<<<500, 256, 0, stream>>>(wpk, wpk + WOFF_PS, idxp, p3b, f1b,
                                        wpk + WOFF_H2);
  head2_kernel<<<32, 256, 0, stream>>>(wpk, wpk + WOFF_H2, f2b, f3w, f3b,
                                       (float*)d_out);
}

// Round 4
// 558.158 us; speedup vs baseline: 1.4943x; 1.0508x over previous
//
#include <hip/hip_runtime.h>
#include <cstdint>
#include <cstddef>

// ---------------------------------------------------------------------------
// TGNN fused pipeline v11 = v10 (sliding 64-row windows, no padding) with
// explicit 1-deep software pipelining of the p1/p2/p3 inner loops.
// v10 post-mortem: cycle model locked (2 waves/SIMD x 1192 MFMA x 19.4cy =
// 28-32% matrix util == measured). Wave timeline ~16% MFMA, rest = L2 B-load
// (~200cy) + LDS A-read latency issued just-before-use; compiler schedules
// for min regs (VGPR 108 of 256 cap) so only ~1 kt in flight.
// v11: rotate {a[4], b[2..4]} cur/next reg sets - issue kt+1 loads BEFORE
// kt's MFMA cluster; s_setprio(1/0) around MFMA (2 independent blocks/CU =
// drifting phases, the attn-like setprio regime). Embed phase untouched.
// Tripwires: VGPR_Count should rise to ~150-200 (pipeline materialized);
// WRITE_SIZE must stay 12.5MB (no spill; v8 lesson).
// ---------------------------------------------------------------------------

typedef __bf16 bf16;
typedef __attribute__((ext_vector_type(8))) __bf16 bf16x8;
typedef __attribute__((ext_vector_type(4))) __bf16 bf16x4;
typedef __attribute__((ext_vector_type(4))) float floatx4;

#define GRP 100
#define NWIN 3125        // 200000 rows / 64

// packed-ws element offsets (bf16 elements)
#define WOFF_AW 0
#define WOFF_BW 8192
#define WOFF_P1 12288
#define WOFF_P2 208896
#define WOFF_P3 339968
#define WOFF_F1 602112
#define WOFF_F2 1126400
#define WOFF_PS 1142784          // partial sums [6250][1024] bf16
#define WOFF_H2 7542784          // h2 [2000][512] bf16

// LDS strides (bf16 elems): %8==0 (16B-aligned b128 rows)
#define LSTR_P  168
#define LSTR_H  392
#define LSTR_H2 136
#define LSTR_H3 264

static __device__ __forceinline__ floatx4 mfma16(bf16x8 a, bf16x8 b, floatx4 c) {
  return __builtin_amdgcn_mfma_f32_16x16x32_bf16(a, b, c, 0, 0, 0);
}

// ---------------------------------------------------------------------------
// Coalesced weight repack: 32k x 64n tiles through an LDS transpose.
// fp32 [K][N] row-major -> bf16 ((nc*KT+kt)*CW + nl)*32 + kk, CW=128.
// 550 standard tiles + 16 tiles for f2w (CW=32). Proven correct in R6.
// (byte-identical to v7/v10)
// ---------------------------------------------------------------------------
__global__ __launch_bounds__(256) void pack_lds(
    const float* __restrict__ aw, const float* __restrict__ bw,
    const float* __restrict__ p1w, const float* __restrict__ p2w,
    const float* __restrict__ p3w, const float* __restrict__ f1w,
    const float* __restrict__ f2w, bf16* __restrict__ wpk) {
  __shared__ float t[32][65];
  const int tid = threadIdx.x;
  int b = blockIdx.x;

  if (b < 550) {
    const float* src; int dstoff, K, N, tt;
    if (b < 4)        { src = aw;  dstoff = WOFF_AW; K = 64;   N = 128;  tt = b; }
    else if (b < 6)   { src = bw;  dstoff = WOFF_BW; K = 32;   N = 128;  tt = b - 4; }
    else if (b < 102) { src = p1w; dstoff = WOFF_P1; K = 384;  N = 512;  tt = b - 6; }
    else if (b < 166) { src = p2w; dstoff = WOFF_P2; K = 512;  N = 256;  tt = b - 102; }
    else if (b < 294) { src = p3w; dstoff = WOFF_P3; K = 256;  N = 1024; tt = b - 166; }
    else              { src = f1w; dstoff = WOFF_F1; K = 1024; N = 512;  tt = b - 294; }
    const int KT = K >> 5;
    const int kt = tt % KT;
    const int n0 = (tt / KT) * 64;
    for (int i = tid; i < 2048; i += 256) {
      int r = i >> 6, c = i & 63;
      t[r][c] = src[(size_t)(kt * 32 + r) * N + n0 + c];
    }
    __syncthreads();
    const int nc = n0 >> 7, nl0 = n0 & 127;
    bf16* dst = wpk + dstoff + ((size_t)(nc * KT + kt) * 128 + nl0) * 32;
    int o = tid * 8;
    int nl = o >> 5, kk = o & 31;
    bf16x8 v;
#pragma unroll
    for (int i = 0; i < 8; ++i) v[i] = (bf16)t[kk + i][nl];
    *(bf16x8*)(dst + nl * 32 + kk) = v;
  } else {
    const int kt = b - 550;
    for (int i = tid; i < 1024; i += 256) {
      int r = i >> 5, c = i & 31;
      t[r][c] = f2w[(size_t)(kt * 32 + r) * 32 + c];
    }
    __syncthreads();
    if (tid < 128) {
      int o = tid * 8;
      int nl = o >> 5, kk = o & 31;
      bf16x8 v;
#pragma unroll
      for (int i = 0; i < 8; ++i) v[i] = (bf16)t[kk + i][nl];
      *(bf16x8*)(wpk + WOFF_F2 + kt * 1024 + nl * 32 + kk) = v;
    }
  }
}

// kstep, 2 B-frags from global: 4 A-reads, 8 MFMA (M=64) -- embed phase only
static __device__ __forceinline__ void kstep2(const bf16* __restrict__ Ab,
                                              int astride, int acol,
                                              const bf16* __restrict__ b0p,
                                              const bf16* __restrict__ b1p,
                                              floatx4* acc, int lm, int lq) {
  bf16x8 b0 = *(const bf16x8*)b0p;
  bf16x8 b1 = *(const bf16x8*)b1p;
#pragma unroll
  for (int mt = 0; mt < 4; ++mt) {
    bf16x8 a = *(const bf16x8*)(Ab + (mt * 16 + lm) * astride + acol + lq * 8);
    acc[mt * 2]     = mfma16(a, b0, acc[mt * 2]);
    acc[mt * 2 + 1] = mfma16(a, b1, acc[mt * 2 + 1]);
  }
}

// epilogue for 2-N-tile acc: relu(acc+bias) -> LDS (M=64)
static __device__ __forceinline__ void epi2(const floatx4* acc,
                                            const float* __restrict__ bias,
                                            bf16* dst, int dstride, int w,
                                            int lm, int lq) {
#pragma unroll
  for (int mt = 0; mt < 4; ++mt)
#pragma unroll
    for (int j = 0; j < 2; ++j) {
      int col = (w + 4 * j) * 16 + lm;
      float bv = bias[col];
      floatx4 c = acc[mt * 2 + j];
#pragma unroll
      for (int r = 0; r < 4; ++r) {
        float v = c[r] + bv;
        v = v > 0.f ? v : 0.f;
        dst[(mt * 16 + lq * 4 + r) * dstride + col] = (bf16)v;
      }
    }
}

// ---------------------------------------------------------------------------
// seg_kernel: one block per 64-row WINDOW (no padding). Window straddles at
// most 2 segments; p3 column-sums are split at the boundary into 2 psum slots.
// LDS: hbuf 50176 + pbuf 21504 = 71680 B -> 2 blocks/CU.
// p1/p2/p3 inner loops: explicit cur/next register rotation (1-deep pipeline).
// ---------------------------------------------------------------------------
__global__ __launch_bounds__(256, 2) void seg_kernel(
    const float* __restrict__ pairs, const float* __restrict__ ab,
    const float* __restrict__ bb, const float* __restrict__ p1b,
    const float* __restrict__ p2b, const bf16* __restrict__ wpk,
    bf16* __restrict__ psum) {
  __shared__ __align__(16) bf16 hbuf[64 * LSTR_H];  // h[64,384] then h3[64,256]
  __shared__ __align__(16) bf16 pbuf[64 * LSTR_P];  // pairs bf16, then h2 chunk

  const int tid = threadIdx.x;
  const int w = tid >> 6;
  const int lane = tid & 63;
  const int lm = lane & 15;
  const int lq = lane >> 4;
  const int blk = blockIdx.x;

  // ---- stage pairs window [64,160] fp32 -> bf16 LDS (all rows valid) ----
  {
    const float4* src = (const float4*)(pairs + (size_t)blk * (64 * 160));
    for (int i = tid; i < 64 * 40; i += 256) {
      int row = i / 40;
      int c4 = (i - row * 40) * 4;
      float4 v = src[i];
      bf16x4 o = {(bf16)v.x, (bf16)v.y, (bf16)v.z, (bf16)v.w};
      *(bf16x4*)(pbuf + row * LSTR_P + c4) = o;
    }
  }
  __syncthreads();

  const floatx4 fz = {0.f, 0.f, 0.f, 0.f};
  floatx4 acc[16];
  floatx4 acc3[16];

  // ---------------- embed: a1 / a2 / be -> hbuf[64,384] ----------------
#pragma unroll
  for (int t = 0; t < 8; ++t) acc[t] = fz;
#pragma unroll
  for (int kt = 0; kt < 2; ++kt)
    kstep2(pbuf, LSTR_P, kt * 32,
           wpk + WOFF_AW + ((size_t)(kt * 128 + w * 16 + lm)) * 32 + lq * 8,
           wpk + WOFF_AW + ((size_t)(kt * 128 + (w + 4) * 16 + lm)) * 32 + lq * 8,
           acc, lm, lq);
  epi2(acc, ab, hbuf, LSTR_H, w, lm, lq);
#pragma unroll
  for (int t = 0; t < 8; ++t) acc[t] = fz;
#pragma unroll
  for (int kt = 0; kt < 2; ++kt)
    kstep2(pbuf, LSTR_P, 64 + kt * 32,
           wpk + WOFF_AW + ((size_t)(kt * 128 + w * 16 + lm)) * 32 + lq * 8,
           wpk + WOFF_AW + ((size_t)(kt * 128 + (w + 4) * 16 + lm)) * 32 + lq * 8,
           acc, lm, lq);
  epi2(acc, ab, hbuf + 128, LSTR_H, w, lm, lq);
#pragma unroll
  for (int t = 0; t < 8; ++t) acc[t] = fz;
  kstep2(pbuf, LSTR_P, 128,
         wpk + WOFF_BW + ((size_t)(w * 16 + lm)) * 32 + lq * 8,
         wpk + WOFF_BW + ((size_t)((w + 4) * 16 + lm)) * 32 + lq * 8,
         acc, lm, lq);
  epi2(acc, bb, hbuf + 256, LSTR_H, w, lm, lq);

  __syncthreads();

  // ------- p1 (4 N-chunks of 128), each fused into p2 K-accumulation -------
#pragma unroll
  for (int t = 0; t < 16; ++t) acc3[t] = fz;

  for (int nc = 0; nc < 4; ++nc) {
#pragma unroll
    for (int t = 0; t < 8; ++t) acc[t] = fz;

    // ---- p1: h[64,384] @ p1w[:, nc*128..+128), pipelined ----
    {
      const bf16* bp = wpk + WOFF_P1 +
          ((size_t)(nc * 12) * 128 + w * 16 + lm) * 32 + lq * 8;
      bf16x8 b0n = *(const bf16x8*)(bp);
      bf16x8 b1n = *(const bf16x8*)(bp + 2048);   // +4*16 cols
      bf16x8 an[4];
#pragma unroll
      for (int mt = 0; mt < 4; ++mt)
        an[mt] = *(const bf16x8*)(hbuf + (mt * 16 + lm) * LSTR_H + lq * 8);
#pragma unroll
      for (int kt = 0; kt < 12; ++kt) {
        bf16x8 b0 = b0n, b1 = b1n;
        bf16x8 ac[4];
#pragma unroll
        for (int mt = 0; mt < 4; ++mt) ac[mt] = an[mt];
        if (kt < 11) {
          b0n = *(const bf16x8*)(bp + (size_t)(kt + 1) * 4096);
          b1n = *(const bf16x8*)(bp + (size_t)(kt + 1) * 4096 + 2048);
#pragma unroll
          for (int mt = 0; mt < 4; ++mt)
            an[mt] = *(const bf16x8*)(hbuf + (mt * 16 + lm) * LSTR_H +
                                      (kt + 1) * 32 + lq * 8);
        }
        __builtin_amdgcn_s_setprio(1);
#pragma unroll
        for (int mt = 0; mt < 4; ++mt) {
          acc[mt * 2]     = mfma16(ac[mt], b0, acc[mt * 2]);
          acc[mt * 2 + 1] = mfma16(ac[mt], b1, acc[mt * 2 + 1]);
        }
        __builtin_amdgcn_s_setprio(0);
      }
    }
    __syncthreads();                       // prior p2 reads of pbuf done
    epi2(acc, p1b + nc * 128, pbuf, LSTR_H2, w, lm, lq);
    __syncthreads();                       // h2 chunk visible

    // ---- p2: h2chunk[64,128] @ p2w chunk, accumulate acc3, pipelined ----
    {
      const bf16* bp = wpk + WOFF_P2 +
          ((size_t)(((w >> 1) * 16 + nc * 4) * 128 + (w & 1) * 64 + lm)) * 32 +
          lq * 8;
      bf16x8 bn[4];
#pragma unroll
      for (int j = 0; j < 4; ++j) bn[j] = *(const bf16x8*)(bp + j * 512);
      bf16x8 an[4];
#pragma unroll
      for (int mt = 0; mt < 4; ++mt)
        an[mt] = *(const bf16x8*)(pbuf + (mt * 16 + lm) * LSTR_H2 + lq * 8);
#pragma unroll
      for (int kt2 = 0; kt2 < 4; ++kt2) {
        bf16x8 bc[4], ac[4];
#pragma unroll
        for (int j = 0; j < 4; ++j) bc[j] = bn[j];
#pragma unroll
        for (int mt = 0; mt < 4; ++mt) ac[mt] = an[mt];
        if (kt2 < 3) {
#pragma unroll
          for (int j = 0; j < 4; ++j)
            bn[j] = *(const bf16x8*)(bp + (size_t)(kt2 + 1) * 4096 + j * 512);
#pragma unroll
          for (int mt = 0; mt < 4; ++mt)
            an[mt] = *(const bf16x8*)(pbuf + (mt * 16 + lm) * LSTR_H2 +
                                      (kt2 + 1) * 32 + lq * 8);
        }
        __builtin_amdgcn_s_setprio(1);
#pragma unroll
        for (int mt = 0; mt < 4; ++mt)
#pragma unroll
          for (int j = 0; j < 4; ++j)
            acc3[mt * 4 + j] = mfma16(ac[mt], bc[j], acc3[mt * 4 + j]);
        __builtin_amdgcn_s_setprio(0);
      }
    }
  }

  // p2 epilogue: h3 = relu(acc3 + p2b) -> hbuf (stride 264)
#pragma unroll
  for (int mt = 0; mt < 4; ++mt)
#pragma unroll
    for (int s = 0; s < 4; ++s) {
      int cl = w * 64 + s * 16 + lm;
      float bv = p2b[cl];
      floatx4 c = acc3[mt * 4 + s];
#pragma unroll
      for (int r = 0; r < 4; ++r) {
        float v = c[r] + bv;
        v = v > 0.f ? v : 0.f;
        hbuf[(mt * 16 + lq * 4 + r) * LSTR_H3 + cl] = (bf16)v;
      }
    }
  __syncthreads();

  // ------- p3 (4 N-chunks of 256) + straddle-split column sums -------
  // Window rows [64*blk, 64*blk+64) straddle segments s0, s0+1 at local
  // row sp = 100*(s0+1) - 64*blk (sp>=64 -> single segment, cs1 = ~0,
  // written to a slot head1 provably never reads).
  const int wn = w >> 1;
  const int wl = (w & 1) * 64;
  const int s0 = (64 * blk) / 100;
  const int sp = (s0 + 1) * 100 - 64 * blk;
  floatx4 msk[4];
#pragma unroll
  for (int mt = 0; mt < 4; ++mt)
#pragma unroll
    for (int r = 0; r < 4; ++r)
      msk[mt][r] = (mt * 16 + lq * 4 + r < sp) ? 1.f : 0.f;

  for (int c = 0; c < 4; ++c) {
#pragma unroll
    for (int t = 0; t < 16; ++t) acc[t] = fz;

    // ---- p3 chunk: h3[64,256] @ p3w chunk, pipelined ----
    {
      const bf16* bp = wpk + WOFF_P3 +
          ((size_t)(((2 * c + wn) * 8) * 128 + wl + lm)) * 32 + lq * 8;
      bf16x8 bn[4];
#pragma unroll
      for (int j = 0; j < 4; ++j) bn[j] = *(const bf16x8*)(bp + j * 512);
      bf16x8 an[4];
#pragma unroll
      for (int mt = 0; mt < 4; ++mt)
        an[mt] = *(const bf16x8*)(hbuf + (mt * 16 + lm) * LSTR_H3 + lq * 8);
#pragma unroll
      for (int kt = 0; kt < 8; ++kt) {
        bf16x8 bc[4], ac[4];
#pragma unroll
        for (int j = 0; j < 4; ++j) bc[j] = bn[j];
#pragma unroll
        for (int mt = 0; mt < 4; ++mt) ac[mt] = an[mt];
        if (kt < 7) {
#pragma unroll
          for (int j = 0; j < 4; ++j)
            bn[j] = *(const bf16x8*)(bp + (size_t)(kt + 1) * 4096 + j * 512);
#pragma unroll
          for (int mt = 0; mt < 4; ++mt)
            an[mt] = *(const bf16x8*)(hbuf + (mt * 16 + lm) * LSTR_H3 +
                                      (kt + 1) * 32 + lq * 8);
        }
        __builtin_amdgcn_s_setprio(1);
#pragma unroll
        for (int mt = 0; mt < 4; ++mt)
#pragma unroll
          for (int j = 0; j < 4; ++j)
            acc[mt * 4 + j] = mfma16(ac[mt], bc[j], acc[mt * 4 + j]);
        __builtin_amdgcn_s_setprio(0);
      }
    }

#pragma unroll
    for (int j = 0; j < 4; ++j) {
      float tot = 0.f, cs0 = 0.f;
#pragma unroll
      for (int mt = 0; mt < 4; ++mt) {
        floatx4 cc = acc[mt * 4 + j];
#pragma unroll
        for (int r = 0; r < 4; ++r) {
          tot += cc[r];
          cs0 = fmaf(cc[r], msk[mt][r], cs0);
        }
      }
      float cs1 = tot - cs0;
      cs0 += __shfl_xor(cs0, 16, 64);
      cs0 += __shfl_xor(cs0, 32, 64);
      cs1 += __shfl_xor(cs1, 16, 64);
      cs1 += __shfl_xor(cs1, 32, 64);
      if (lq == 0) {
        int col = c * 256 + w * 64 + j * 16 + lm;
        psum[(size_t)(2 * blk) * 1024 + col]     = (bf16)cs0;
        psum[(size_t)(2 * blk + 1) * 1024 + col] = (bf16)cs1;
      }
    }
  }
}

// ---------------------------------------------------------------------------
// head1: combine (mean + p3 bias) + f1 chunk. 500 blocks = 125 row-groups
// x 4 col-chunks of 128. Gathers 2-3 straddle-window partials per segment:
// blocks b in [(100s)>>6, (100s+99)>>6], slot 0 iff 64b >= 100s.
// ---------------------------------------------------------------------------
__global__ __launch_bounds__(256, 2) void head1_kernel(
    const bf16* __restrict__ wpk, const bf16* __restrict__ psum,
    const int* __restrict__ idxp, const float* __restrict__ p3b,
    const float* __restrict__ f1b, bf16* __restrict__ h2) {
  __shared__ __align__(16) bf16 hp[16 * 1032];

  const int tid = threadIdx.x;
  const int w = tid >> 6;
  const int lane = tid & 63;
  const int lm = lane & 15;
  const int lq = lane >> 4;
  const int rg = blockIdx.x >> 2;
  const int cc = blockIdx.x & 3;
  const int r0 = rg * 16;
  const floatx4 fz = {0.f, 0.f, 0.f, 0.f};

  for (int i = tid; i < 16 * 1024; i += 256) {
    int row = i >> 10;
    int c = i & 1023;
    int seg = r0 + row;
    int b_lo = (100 * seg) >> 6;
    int b_hi = (100 * seg + 99) >> 6;
    float s = 0.f;
    for (int b = b_lo; b <= b_hi; ++b) {
      int slot = (64 * b >= 100 * seg) ? 0 : 1;
      s += (float)psum[(size_t)(2 * b + slot) * 1024 + c];
    }
    hp[row * 1032 + c] = (bf16)(s / (float)idxp[seg] + p3b[c]);
  }
  __syncthreads();

  floatx4 a2[2];
  a2[0] = fz; a2[1] = fz;
#pragma unroll 8
  for (int kt = 0; kt < 32; ++kt) {
    bf16x8 a = *(const bf16x8*)(hp + lm * 1032 + kt * 32 + lq * 8);
#pragma unroll
    for (int j = 0; j < 2; ++j) {
      bf16x8 b = *(const bf16x8*)(wpk + WOFF_F1 +
                    ((size_t)((cc * 32 + kt) * 128 + (2 * w + j) * 16 + lm)) * 32 + lq * 8);
      a2[j] = mfma16(a, b, a2[j]);
    }
  }
#pragma unroll
  for (int j = 0; j < 2; ++j) {
    int col = cc * 128 + (2 * w + j) * 16 + lm;
    float bv = f1b[col];
#pragma unroll
    for (int r = 0; r < 4; ++r) {
      float v = a2[j][r] + bv;
      v = v > 0.f ? v : 0.f;
      h2[(size_t)(r0 + lq * 4 + r) * 512 + col] = (bf16)v;
    }
  }
}

// ---------------------------------------------------------------------------
// head2: f2 (relu) + f3. Wave-per-16-rows, 32 blocks x 4 waves. (unchanged)
// ---------------------------------------------------------------------------
__global__ __launch_bounds__(256, 2) void head2_kernel(
    const bf16* __restrict__ wpk, const bf16* __restrict__ h2,
    const float* __restrict__ f2b, const float* __restrict__ f3w,
    const float* __restrict__ f3b, float* __restrict__ out) {
  __shared__ __align__(16) bf16 h3s[4][16 * 40];

  const int tid = threadIdx.x;
  const int w = tid >> 6;
  const int lane = tid & 63;
  const int lm = lane & 15;
  const int lq = lane >> 4;
  const int rg = blockIdx.x * 4 + w;
  if (rg >= 125) return;
  const int r0 = rg * 16;
  const floatx4 fz = {0.f, 0.f, 0.f, 0.f};

  floatx4 c2[2];
  c2[0] = fz; c2[1] = fz;
#pragma unroll
  for (int kt = 0; kt < 16; ++kt) {
    bf16x8 a = *(const bf16x8*)(h2 + (size_t)(r0 + lm) * 512 + kt * 32 + lq * 8);
#pragma unroll
    for (int j = 0; j < 2; ++j) {
      bf16x8 b = *(const bf16x8*)(wpk + WOFF_F2 +
                    ((size_t)(kt * 32 + j * 16 + lm)) * 32 + lq * 8);
      c2[j] = mfma16(a, b, c2[j]);
    }
  }
#pragma unroll
  for (int j = 0; j < 2; ++j) {
    int col = j * 16 + lm;
    float bv = f2b[col];
#pragma unroll
    for (int r = 0; r < 4; ++r) {
      float v = c2[j][r] + bv;
      v = v > 0.f ? v : 0.f;
      h3s[w][(lq * 4 + r) * 40 + col] = (bf16)v;
    }
  }
  float ps = 0.f;
#pragma unroll
  for (int jj = 0; jj < 8; ++jj)
    ps += (float)h3s[w][lm * 40 + lq * 8 + jj] * f3w[lq * 8 + jj];
  ps += __shfl_xor(ps, 16, 64);
  ps += __shfl_xor(ps, 32, 64);
  if (lq == 0) out[r0 + lm] = ps + f3b[0];
}

// ---------------------------------------------------------------------------
extern "C" void kernel_launch(void* const* d_in, const int* in_sizes, int n_in,
                              void* d_out, int out_size, void* d_ws,
                              size_t ws_size, hipStream_t stream) {
  (void)in_sizes; (void)n_in; (void)out_size; (void)ws_size;
  const float* pairs = (const float*)d_in[0];
  const int*   idxp  = (const int*)d_in[1];
  // d_in[2] = ref_feats (unused by the reference)
  const float* aw  = (const float*)d_in[3];
  const float* ab  = (const float*)d_in[4];
  const float* bw  = (const float*)d_in[5];
  const float* bb  = (const float*)d_in[6];
  const float* p1w = (const float*)d_in[7];
  const float* p1b = (const float*)d_in[8];
  const float* p2w = (const float*)d_in[9];
  const float* p2b = (const float*)d_in[10];
  const float* p3w = (const float*)d_in[11];
  const float* p3b = (const float*)d_in[12];
  const float* f1w = (const float*)d_in[13];
  const float* f1b = (const float*)d_in[14];
  const float* f2w = (const float*)d_in[15];
  const float* f2b = (const float*)d_in[16];
  const float* f3w = (const float*)d_in[17];
  const float* f3b = (const float*)d_in[18];

  bf16* wpk = (bf16*)d_ws;

  pack_lds<<<566, 256, 0, stream>>>(aw, bw, p1w, p2w, p3w, f1w, f2w, wpk);
  seg_kernel<<<NWIN, 256, 0, stream>>>(pairs, ab, bb, p1b, p2b, wpk,
                                       wpk + WOFF_PS);
  head1_kernel<<<500, 256, 0, stream>>>(wpk, wpk + WOFF_PS, idxp, p3b, f1b,
                                        wpk + WOFF_H2);
  head2_kernel<<<32, 256, 0, stream>>>(wpk, wpk + WOFF_H2, f2b, f3w, f3b,
                                       (float*)d_out);
}

// Round 5
// 436.054 us; speedup vs baseline: 1.9128x; 1.2800x over previous
//
#include <hip/hip_runtime.h>
#include <cstdint>
#include <cstddef>

// ---------------------------------------------------------------------------
// TGNN fused pipeline v12 = v11 with the p3 phase ELIMINATED algebraically:
//   segsum(h3 @ p3w + p3b) == segsum(h3) @ p3w + cnt*p3b
// seg_kernel now ends at p2: masked row-sums of h3 = relu(acc3+p2b) are
// reduced straight from registers (no h3 LDS write, no p3 B-stream, no
// 1024-wide psum) -> hsum [6250][256] f32. A tiny mid_kernel (125 blocks)
// does mean_h3 @ p3w + p3b -> hpair [2000][1024] bf16. head1 loses its
// scalar psum gather (Common-mistake #2) and becomes a pure GEMM on hpair.
// Per-window MFMA 1192 -> 680 (-43%); column-sum VALU 4x smaller.
// v11 lessons kept: M=64 tile, sliding windows, 1-deep reg pipeline in
// p1/p2, s_setprio around MFMA, (256,2) launch bounds (spill tripwire:
// WRITE_SIZE; v8 lesson).
// ---------------------------------------------------------------------------

typedef __bf16 bf16;
typedef __attribute__((ext_vector_type(8))) __bf16 bf16x8;
typedef __attribute__((ext_vector_type(4))) __bf16 bf16x4;
typedef __attribute__((ext_vector_type(4))) float floatx4;

#define GRP 100
#define NWIN 3125        // 200000 rows / 64

// packed-ws element offsets (bf16 elements)
#define WOFF_AW 0
#define WOFF_BW 8192
#define WOFF_P1 12288
#define WOFF_P2 208896
#define WOFF_P3 339968
#define WOFF_F1 602112
#define WOFF_F2 1126400
#define WOFF_HS 1142784          // hsum  [6250][256] f32  (2 bf16 elems each)
#define WOFF_HP 4342784          // hpair [2000][1024] bf16
#define WOFF_H2 6390784          // h2    [2000][512] bf16

// LDS strides (bf16 elems): %8==0 (16B-aligned b128 rows)
#define LSTR_P  168
#define LSTR_H  392
#define LSTR_H2 136
#define LSTR_MS 264

static __device__ __forceinline__ floatx4 mfma16(bf16x8 a, bf16x8 b, floatx4 c) {
  return __builtin_amdgcn_mfma_f32_16x16x32_bf16(a, b, c, 0, 0, 0);
}

// ---------------------------------------------------------------------------
// Coalesced weight repack: 32k x 64n tiles through an LDS transpose.
// fp32 [K][N] row-major -> bf16 ((nc*KT+kt)*CW + nl)*32 + kk, CW=128.
// 550 standard tiles + 16 tiles for f2w (CW=32). Proven correct in R6.
// (byte-identical to v7/v10/v11)
// ---------------------------------------------------------------------------
__global__ __launch_bounds__(256) void pack_lds(
    const float* __restrict__ aw, const float* __restrict__ bw,
    const float* __restrict__ p1w, const float* __restrict__ p2w,
    const float* __restrict__ p3w, const float* __restrict__ f1w,
    const float* __restrict__ f2w, bf16* __restrict__ wpk) {
  __shared__ float t[32][65];
  const int tid = threadIdx.x;
  int b = blockIdx.x;

  if (b < 550) {
    const float* src; int dstoff, K, N, tt;
    if (b < 4)        { src = aw;  dstoff = WOFF_AW; K = 64;   N = 128;  tt = b; }
    else if (b < 6)   { src = bw;  dstoff = WOFF_BW; K = 32;   N = 128;  tt = b - 4; }
    else if (b < 102) { src = p1w; dstoff = WOFF_P1; K = 384;  N = 512;  tt = b - 6; }
    else if (b < 166) { src = p2w; dstoff = WOFF_P2; K = 512;  N = 256;  tt = b - 102; }
    else if (b < 294) { src = p3w; dstoff = WOFF_P3; K = 256;  N = 1024; tt = b - 166; }
    else              { src = f1w; dstoff = WOFF_F1; K = 1024; N = 512;  tt = b - 294; }
    const int KT = K >> 5;
    const int kt = tt % KT;
    const int n0 = (tt / KT) * 64;
    for (int i = tid; i < 2048; i += 256) {
      int r = i >> 6, c = i & 63;
      t[r][c] = src[(size_t)(kt * 32 + r) * N + n0 + c];
    }
    __syncthreads();
    const int nc = n0 >> 7, nl0 = n0 & 127;
    bf16* dst = wpk + dstoff + ((size_t)(nc * KT + kt) * 128 + nl0) * 32;
    int o = tid * 8;
    int nl = o >> 5, kk = o & 31;
    bf16x8 v;
#pragma unroll
    for (int i = 0; i < 8; ++i) v[i] = (bf16)t[kk + i][nl];
    *(bf16x8*)(dst + nl * 32 + kk) = v;
  } else {
    const int kt = b - 550;
    for (int i = tid; i < 1024; i += 256) {
      int r = i >> 5, c = i & 31;
      t[r][c] = f2w[(size_t)(kt * 32 + r) * 32 + c];
    }
    __syncthreads();
    if (tid < 128) {
      int o = tid * 8;
      int nl = o >> 5, kk = o & 31;
      bf16x8 v;
#pragma unroll
      for (int i = 0; i < 8; ++i) v[i] = (bf16)t[kk + i][nl];
      *(bf16x8*)(wpk + WOFF_F2 + kt * 1024 + nl * 32 + kk) = v;
    }
  }
}

// kstep, 2 B-frags from global: 4 A-reads, 8 MFMA (M=64) -- embed phase only
static __device__ __forceinline__ void kstep2(const bf16* __restrict__ Ab,
                                              int astride, int acol,
                                              const bf16* __restrict__ b0p,
                                              const bf16* __restrict__ b1p,
                                              floatx4* acc, int lm, int lq) {
  bf16x8 b0 = *(const bf16x8*)b0p;
  bf16x8 b1 = *(const bf16x8*)b1p;
#pragma unroll
  for (int mt = 0; mt < 4; ++mt) {
    bf16x8 a = *(const bf16x8*)(Ab + (mt * 16 + lm) * astride + acol + lq * 8);
    acc[mt * 2]     = mfma16(a, b0, acc[mt * 2]);
    acc[mt * 2 + 1] = mfma16(a, b1, acc[mt * 2 + 1]);
  }
}

// epilogue for 2-N-tile acc: relu(acc+bias) -> LDS (M=64)
static __device__ __forceinline__ void epi2(const floatx4* acc,
                                            const float* __restrict__ bias,
                                            bf16* dst, int dstride, int w,
                                            int lm, int lq) {
#pragma unroll
  for (int mt = 0; mt < 4; ++mt)
#pragma unroll
    for (int j = 0; j < 2; ++j) {
      int col = (w + 4 * j) * 16 + lm;
      float bv = bias[col];
      floatx4 c = acc[mt * 2 + j];
#pragma unroll
      for (int r = 0; r < 4; ++r) {
        float v = c[r] + bv;
        v = v > 0.f ? v : 0.f;
        dst[(mt * 16 + lq * 4 + r) * dstride + col] = (bf16)v;
      }
    }
}

// ---------------------------------------------------------------------------
// seg_kernel: one block per 64-row WINDOW (no padding). Ends at p2; masked
// row-sums of h3 = relu(acc3+p2b) reduced straight from registers into
// hsum[2blk] / hsum[2blk+1] (f32, 256 cols). Straddle mask as in v10/v11.
// LDS: hbuf 50176 + pbuf 21504 = 71680 B -> 2 blocks/CU.
// ---------------------------------------------------------------------------
__global__ __launch_bounds__(256, 2) void seg_kernel(
    const float* __restrict__ pairs, const float* __restrict__ ab,
    const float* __restrict__ bb, const float* __restrict__ p1b,
    const float* __restrict__ p2b, const bf16* __restrict__ wpk,
    float* __restrict__ hsum) {
  __shared__ __align__(16) bf16 hbuf[64 * LSTR_H];  // h[64,384]
  __shared__ __align__(16) bf16 pbuf[64 * LSTR_P];  // pairs bf16, then h2 chunk

  const int tid = threadIdx.x;
  const int w = tid >> 6;
  const int lane = tid & 63;
  const int lm = lane & 15;
  const int lq = lane >> 4;
  const int blk = blockIdx.x;

  // ---- stage pairs window [64,160] fp32 -> bf16 LDS (all rows valid) ----
  {
    const float4* src = (const float4*)(pairs + (size_t)blk * (64 * 160));
    for (int i = tid; i < 64 * 40; i += 256) {
      int row = i / 40;
      int c4 = (i - row * 40) * 4;
      float4 v = src[i];
      bf16x4 o = {(bf16)v.x, (bf16)v.y, (bf16)v.z, (bf16)v.w};
      *(bf16x4*)(pbuf + row * LSTR_P + c4) = o;
    }
  }
  __syncthreads();

  const floatx4 fz = {0.f, 0.f, 0.f, 0.f};
  floatx4 acc[8];
  floatx4 acc3[16];

  // ---------------- embed: a1 / a2 / be -> hbuf[64,384] ----------------
#pragma unroll
  for (int t = 0; t < 8; ++t) acc[t] = fz;
#pragma unroll
  for (int kt = 0; kt < 2; ++kt)
    kstep2(pbuf, LSTR_P, kt * 32,
           wpk + WOFF_AW + ((size_t)(kt * 128 + w * 16 + lm)) * 32 + lq * 8,
           wpk + WOFF_AW + ((size_t)(kt * 128 + (w + 4) * 16 + lm)) * 32 + lq * 8,
           acc, lm, lq);
  epi2(acc, ab, hbuf, LSTR_H, w, lm, lq);
#pragma unroll
  for (int t = 0; t < 8; ++t) acc[t] = fz;
#pragma unroll
  for (int kt = 0; kt < 2; ++kt)
    kstep2(pbuf, LSTR_P, 64 + kt * 32,
           wpk + WOFF_AW + ((size_t)(kt * 128 + w * 16 + lm)) * 32 + lq * 8,
           wpk + WOFF_AW + ((size_t)(kt * 128 + (w + 4) * 16 + lm)) * 32 + lq * 8,
           acc, lm, lq);
  epi2(acc, ab, hbuf + 128, LSTR_H, w, lm, lq);
#pragma unroll
  for (int t = 0; t < 8; ++t) acc[t] = fz;
  kstep2(pbuf, LSTR_P, 128,
         wpk + WOFF_BW + ((size_t)(w * 16 + lm)) * 32 + lq * 8,
         wpk + WOFF_BW + ((size_t)((w + 4) * 16 + lm)) * 32 + lq * 8,
         acc, lm, lq);
  epi2(acc, bb, hbuf + 256, LSTR_H, w, lm, lq);

  __syncthreads();

  // ------- p1 (4 N-chunks of 128), each fused into p2 K-accumulation -------
#pragma unroll
  for (int t = 0; t < 16; ++t) acc3[t] = fz;

  for (int nc = 0; nc < 4; ++nc) {
#pragma unroll
    for (int t = 0; t < 8; ++t) acc[t] = fz;

    // ---- p1: h[64,384] @ p1w[:, nc*128..+128), pipelined ----
    {
      const bf16* bp = wpk + WOFF_P1 +
          ((size_t)(nc * 12) * 128 + w * 16 + lm) * 32 + lq * 8;
      bf16x8 b0n = *(const bf16x8*)(bp);
      bf16x8 b1n = *(const bf16x8*)(bp + 2048);   // +4*16 cols
      bf16x8 an[4];
#pragma unroll
      for (int mt = 0; mt < 4; ++mt)
        an[mt] = *(const bf16x8*)(hbuf + (mt * 16 + lm) * LSTR_H + lq * 8);
#pragma unroll
      for (int kt = 0; kt < 12; ++kt) {
        bf16x8 b0 = b0n, b1 = b1n;
        bf16x8 ac[4];
#pragma unroll
        for (int mt = 0; mt < 4; ++mt) ac[mt] = an[mt];
        if (kt < 11) {
          b0n = *(const bf16x8*)(bp + (size_t)(kt + 1) * 4096);
          b1n = *(const bf16x8*)(bp + (size_t)(kt + 1) * 4096 + 2048);
#pragma unroll
          for (int mt = 0; mt < 4; ++mt)
            an[mt] = *(const bf16x8*)(hbuf + (mt * 16 + lm) * LSTR_H +
                                      (kt + 1) * 32 + lq * 8);
        }
        __builtin_amdgcn_s_setprio(1);
#pragma unroll
        for (int mt = 0; mt < 4; ++mt) {
          acc[mt * 2]     = mfma16(ac[mt], b0, acc[mt * 2]);
          acc[mt * 2 + 1] = mfma16(ac[mt], b1, acc[mt * 2 + 1]);
        }
        __builtin_amdgcn_s_setprio(0);
      }
    }
    __syncthreads();                       // prior p2 reads of pbuf done
    epi2(acc, p1b + nc * 128, pbuf, LSTR_H2, w, lm, lq);
    __syncthreads();                       // h2 chunk visible

    // ---- p2: h2chunk[64,128] @ p2w chunk, accumulate acc3, pipelined ----
    {
      const bf16* bp = wpk + WOFF_P2 +
          ((size_t)(((w >> 1) * 16 + nc * 4) * 128 + (w & 1) * 64 + lm)) * 32 +
          lq * 8;
      bf16x8 bn[4];
#pragma unroll
      for (int j = 0; j < 4; ++j) bn[j] = *(const bf16x8*)(bp + j * 512);
      bf16x8 an[4];
#pragma unroll
      for (int mt = 0; mt < 4; ++mt)
        an[mt] = *(const bf16x8*)(pbuf + (mt * 16 + lm) * LSTR_H2 + lq * 8);
#pragma unroll
      for (int kt2 = 0; kt2 < 4; ++kt2) {
        bf16x8 bc[4], ac[4];
#pragma unroll
        for (int j = 0; j < 4; ++j) bc[j] = bn[j];
#pragma unroll
        for (int mt = 0; mt < 4; ++mt) ac[mt] = an[mt];
        if (kt2 < 3) {
#pragma unroll
          for (int j = 0; j < 4; ++j)
            bn[j] = *(const bf16x8*)(bp + (size_t)(kt2 + 1) * 4096 + j * 512);
#pragma unroll
          for (int mt = 0; mt < 4; ++mt)
            an[mt] = *(const bf16x8*)(pbuf + (mt * 16 + lm) * LSTR_H2 +
                                      (kt2 + 1) * 32 + lq * 8);
        }
        __builtin_amdgcn_s_setprio(1);
#pragma unroll
        for (int mt = 0; mt < 4; ++mt)
#pragma unroll
          for (int j = 0; j < 4; ++j)
            acc3[mt * 4 + j] = mfma16(ac[mt], bc[j], acc3[mt * 4 + j]);
        __builtin_amdgcn_s_setprio(0);
      }
    }
  }

  // ---- masked row-sums of h3 = relu(acc3 + p2b), straight from registers ----
  // Window rows [64*blk, 64*blk+64) straddle segments s0, s0+1 at local row
  // sp = 100*(s0+1) - 64*blk (sp>=64 -> single segment; slot-1 garbage is
  // provably never read by mid_kernel's gather).
  const int s0 = (64 * blk) / 100;
  const int sp = (s0 + 1) * 100 - 64 * blk;
  floatx4 msk[4];
#pragma unroll
  for (int mt = 0; mt < 4; ++mt)
#pragma unroll
    for (int r = 0; r < 4; ++r)
      msk[mt][r] = (mt * 16 + lq * 4 + r < sp) ? 1.f : 0.f;

#pragma unroll
  for (int s = 0; s < 4; ++s) {
    int cl = w * 64 + s * 16 + lm;
    float bv = p2b[cl];
    float tot = 0.f, cs0 = 0.f;
#pragma unroll
    for (int mt = 0; mt < 4; ++mt) {
      floatx4 c = acc3[mt * 4 + s];
#pragma unroll
      for (int r = 0; r < 4; ++r) {
        float v = c[r] + bv;
        v = v > 0.f ? v : 0.f;
        tot += v;
        cs0 = fmaf(v, msk[mt][r], cs0);
      }
    }
    float cs1 = tot - cs0;
    cs0 += __shfl_xor(cs0, 16, 64);
    cs0 += __shfl_xor(cs0, 32, 64);
    cs1 += __shfl_xor(cs1, 16, 64);
    cs1 += __shfl_xor(cs1, 32, 64);
    if (lq == 0) {
      hsum[(size_t)(2 * blk) * 256 + cl]     = cs0;
      hsum[(size_t)(2 * blk + 1) * 256 + cl] = cs1;
    }
  }
}

// ---------------------------------------------------------------------------
// mid_kernel: hpair[16,1024] = mean_h3[16,256] @ p3w + p3b, per 16-segment
// block (125 blocks). Gathers 2-3 f32 window partials per segment (float4
// vectorized), stages mean in LDS, 128 MFMA per wave.
// ---------------------------------------------------------------------------
__global__ __launch_bounds__(256, 2) void mid_kernel(
    const bf16* __restrict__ wpk, const float* __restrict__ hsum,
    const int* __restrict__ idxp, const float* __restrict__ p3b,
    bf16* __restrict__ hpair) {
  __shared__ __align__(16) bf16 ms[16 * LSTR_MS];

  const int tid = threadIdx.x;
  const int w = tid >> 6;
  const int lane = tid & 63;
  const int lm = lane & 15;
  const int lq = lane >> 4;
  const int r0 = blockIdx.x * 16;

  for (int i = tid; i < 16 * 64; i += 256) {
    int row = i >> 6, c4 = i & 63;
    int seg = r0 + row;
    int b_lo = (100 * seg) >> 6;
    int b_hi = (100 * seg + 99) >> 6;
    float4 sa = {0.f, 0.f, 0.f, 0.f};
    for (int b = b_lo; b <= b_hi; ++b) {
      int slot = (64 * b >= 100 * seg) ? 0 : 1;
      float4 v = *(const float4*)(hsum + (size_t)(2 * b + slot) * 256 + c4 * 4);
      sa.x += v.x; sa.y += v.y; sa.z += v.z; sa.w += v.w;
    }
    float inv = 1.f / (float)idxp[seg];
    bf16x4 o = {(bf16)(sa.x * inv), (bf16)(sa.y * inv),
                (bf16)(sa.z * inv), (bf16)(sa.w * inv)};
    *(bf16x4*)(ms + row * LSTR_MS + c4 * 4) = o;
  }
  __syncthreads();

  const floatx4 fz = {0.f, 0.f, 0.f, 0.f};
#pragma unroll
  for (int ncl = 0; ncl < 2; ++ncl) {
    int nc = 2 * w + ncl;
#pragma unroll
    for (int nt2 = 0; nt2 < 4; ++nt2) {
      floatx4 a2[2];
      a2[0] = fz; a2[1] = fz;
#pragma unroll
      for (int kt = 0; kt < 8; ++kt) {
        bf16x8 a = *(const bf16x8*)(ms + lm * LSTR_MS + kt * 32 + lq * 8);
#pragma unroll
        for (int j = 0; j < 2; ++j) {
          bf16x8 b = *(const bf16x8*)(wpk + WOFF_P3 +
              ((size_t)((nc * 8 + kt) * 128 + (nt2 * 2 + j) * 16 + lm)) * 32 +
              lq * 8);
          a2[j] = mfma16(a, b, a2[j]);
        }
      }
#pragma unroll
      for (int j = 0; j < 2; ++j) {
        int col = nc * 128 + (nt2 * 2 + j) * 16 + lm;
        float bv = p3b[col];
#pragma unroll
        for (int r = 0; r < 4; ++r)
          hpair[(size_t)(r0 + lq * 4 + r) * 1024 + col] = (bf16)(a2[j][r] + bv);
      }
    }
  }
}

// ---------------------------------------------------------------------------
// head1: pure f1 GEMM now: h2[16,128] = relu(hpair[16,1024] @ f1w chunk+f1b).
// 500 blocks = 125 row-groups x 4 col-chunks. A read directly from global
// hpair (4MB, L2-resident) -- no LDS, no gather.
// ---------------------------------------------------------------------------
__global__ __launch_bounds__(256, 2) void head1_kernel(
    const bf16* __restrict__ wpk, const bf16* __restrict__ hpair,
    const float* __restrict__ f1b, bf16* __restrict__ h2) {
  const int tid = threadIdx.x;
  const int w = tid >> 6;
  const int lane = tid & 63;
  const int lm = lane & 15;
  const int lq = lane >> 4;
  const int rg = blockIdx.x >> 2;
  const int cc = blockIdx.x & 3;
  const int r0 = rg * 16;
  const floatx4 fz = {0.f, 0.f, 0.f, 0.f};

  floatx4 a2[2];
  a2[0] = fz; a2[1] = fz;
#pragma unroll 8
  for (int kt = 0; kt < 32; ++kt) {
    bf16x8 a = *(const bf16x8*)(hpair + (size_t)(r0 + lm) * 1024 + kt * 32 + lq * 8);
#pragma unroll
    for (int j = 0; j < 2; ++j) {
      bf16x8 b = *(const bf16x8*)(wpk + WOFF_F1 +
                    ((size_t)((cc * 32 + kt) * 128 + (2 * w + j) * 16 + lm)) * 32 + lq * 8);
      a2[j] = mfma16(a, b, a2[j]);
    }
  }
#pragma unroll
  for (int j = 0; j < 2; ++j) {
    int col = cc * 128 + (2 * w + j) * 16 + lm;
    float bv = f1b[col];
#pragma unroll
    for (int r = 0; r < 4; ++r) {
      float v = a2[j][r] + bv;
      v = v > 0.f ? v : 0.f;
      h2[(size_t)(r0 + lq * 4 + r) * 512 + col] = (bf16)v;
    }
  }
}

// ---------------------------------------------------------------------------
// head2: f2 (relu) + f3. Wave-per-16-rows, 32 blocks x 4 waves. (unchanged)
// ---------------------------------------------------------------------------
__global__ __launch_bounds__(256, 2) void head2_kernel(
    const bf16* __restrict__ wpk, const bf16* __restrict__ h2,
    const float* __restrict__ f2b, const float* __restrict__ f3w,
    const float* __restrict__ f3b, float* __restrict__ out) {
  __shared__ __align__(16) bf16 h3s[4][16 * 40];

  const int tid = threadIdx.x;
  const int w = tid >> 6;
  const int lane = tid & 63;
  const int lm = lane & 15;
  const int lq = lane >> 4;
  const int rg = blockIdx.x * 4 + w;
  if (rg >= 125) return;
  const int r0 = rg * 16;
  const floatx4 fz = {0.f, 0.f, 0.f, 0.f};

  floatx4 c2[2];
  c2[0] = fz; c2[1] = fz;
#pragma unroll
  for (int kt = 0; kt < 16; ++kt) {
    bf16x8 a = *(const bf16x8*)(h2 + (size_t)(r0 + lm) * 512 + kt * 32 + lq * 8);
#pragma unroll
    for (int j = 0; j < 2; ++j) {
      bf16x8 b = *(const bf16x8*)(wpk + WOFF_F2 +
                    ((size_t)(kt * 32 + j * 16 + lm)) * 32 + lq * 8);
      c2[j] = mfma16(a, b, c2[j]);
    }
  }
#pragma unroll
  for (int j = 0; j < 2; ++j) {
    int col = j * 16 + lm;
    float bv = f2b[col];
#pragma unroll
    for (int r = 0; r < 4; ++r) {
      float v = c2[j][r] + bv;
      v = v > 0.f ? v : 0.f;
      h3s[w][(lq * 4 + r) * 40 + col] = (bf16)v;
    }
  }
  float ps = 0.f;
#pragma unroll
  for (int jj = 0; jj < 8; ++jj)
    ps += (float)h3s[w][lm * 40 + lq * 8 + jj] * f3w[lq * 8 + jj];
  ps += __shfl_xor(ps, 16, 64);
  ps += __shfl_xor(ps, 32, 64);
  if (lq == 0) out[r0 + lm] = ps + f3b[0];
}

// ---------------------------------------------------------------------------
extern "C" void kernel_launch(void* const* d_in, const int* in_sizes, int n_in,
                              void* d_out, int out_size, void* d_ws,
                              size_t ws_size, hipStream_t stream) {
  (void)in_sizes; (void)n_in; (void)out_size; (void)ws_size;
  const float* pairs = (const float*)d_in[0];
  const int*   idxp  = (const int*)d_in[1];
  // d_in[2] = ref_feats (unused by the reference)
  const float* aw  = (const float*)d_in[3];
  const float* ab  = (const float*)d_in[4];
  const float* bw  = (const float*)d_in[5];
  const float* bb  = (const float*)d_in[6];
  const float* p1w = (const float*)d_in[7];
  const float* p1b = (const float*)d_in[8];
  const float* p2w = (const float*)d_in[9];
  const float* p2b = (const float*)d_in[10];
  const float* p3w = (const float*)d_in[11];
  const float* p3b = (const float*)d_in[12];
  const float* f1w = (const float*)d_in[13];
  const float* f1b = (const float*)d_in[14];
  const float* f2w = (const float*)d_in[15];
  const float* f2b = (const float*)d_in[16];
  const float* f3w = (const float*)d_in[17];
  const float* f3b = (const float*)d_in[18];

  bf16* wpk = (bf16*)d_ws;
  float* hsum = (float*)(wpk + WOFF_HS);
  bf16* hpair = wpk + WOFF_HP;
  bf16* h2 = wpk + WOFF_H2;

  pack_lds<<<566, 256, 0, stream>>>(aw, bw, p1w, p2w, p3w, f1w, f2w, wpk);
  seg_kernel<<<NWIN, 256, 0, stream>>>(pairs, ab, bb, p1b, p2b, wpk, hsum);
  mid_kernel<<<125, 256, 0, stream>>>(wpk, hsum, idxp, p3b, hpair);
  head1_kernel<<<500, 256, 0, stream>>>(wpk, hpair, f1b, h2);
  head2_kernel<<<32, 256, 0, stream>>>(wpk, h2, f2b, f3w, f3b,
                                       (float*)d_out);
}

// Round 6
// 415.257 us; speedup vs baseline: 2.0086x; 1.0501x over previous
//
#include <hip/hip_runtime.h>
#include <cstdint>
#include <cstddef>

// ---------------------------------------------------------------------------
// TGNN fused pipeline v13 = v12 with:
//  (A) mid+head1+head2 fused into ONE tail_kernel (125 blocks x 512 thr):
//      gather->mean (LDS ms) -> p3 GEMM (LDS hp) -> f1 GEMM (LDS h2s) ->
//      f2+f3 -> out. Kills 2 launches + 2 device drains + hpair/h2 global
//      round-trips. Same op order/precision as v12 (bitwise-identical).
//  (B) seg p1/p2 B-prefetch deepened 1->2 stages. v12 VGPR=92 (160 regs
//      idle); B is L2-resident ~200cy, 1-deep lead under-covers. Arrays
//      indexed [kt&1] in fully-unrolled loops = static (rule #20 safe).
// v12 postmortem: seg 231us, MfmaUtil*dur=60 as predicted (p3 eliminated);
// WRITE_SIZE exactly hsum (no spill). 139 GFLOP/231us = 602 TF effective.
// Tripwires: seg WRITE_SIZE must stay 6250KB (spill poison, v8 lesson);
// seg VGPR should rise to ~150-200 (pipeline materialized).
// ---------------------------------------------------------------------------

typedef __bf16 bf16;
typedef __attribute__((ext_vector_type(8))) __bf16 bf16x8;
typedef __attribute__((ext_vector_type(4))) __bf16 bf16x4;
typedef __attribute__((ext_vector_type(4))) float floatx4;

#define GRP 100
#define NWIN 3125        // 200000 rows / 64

// packed-ws element offsets (bf16 elements)
#define WOFF_AW 0
#define WOFF_BW 8192
#define WOFF_P1 12288
#define WOFF_P2 208896
#define WOFF_P3 339968
#define WOFF_F1 602112
#define WOFF_F2 1126400
#define WOFF_HS 1142784          // hsum [6250][256] f32 (2 bf16 elems each)

// LDS strides (bf16 elems): %8==0 (16B-aligned b128 rows)
#define LSTR_P  168
#define LSTR_H  392
#define LSTR_H2 136
#define LSTR_MS 264

static __device__ __forceinline__ floatx4 mfma16(bf16x8 a, bf16x8 b, floatx4 c) {
  return __builtin_amdgcn_mfma_f32_16x16x32_bf16(a, b, c, 0, 0, 0);
}

// ---------------------------------------------------------------------------
// Coalesced weight repack: 32k x 64n tiles through an LDS transpose.
// fp32 [K][N] row-major -> bf16 ((nc*KT+kt)*CW + nl)*32 + kk, CW=128.
// 550 standard tiles + 16 tiles for f2w (CW=32). Proven correct in R6.
// (byte-identical to v7/v10/v11/v12)
// ---------------------------------------------------------------------------
__global__ __launch_bounds__(256) void pack_lds(
    const float* __restrict__ aw, const float* __restrict__ bw,
    const float* __restrict__ p1w, const float* __restrict__ p2w,
    const float* __restrict__ p3w, const float* __restrict__ f1w,
    const float* __restrict__ f2w, bf16* __restrict__ wpk) {
  __shared__ float t[32][65];
  const int tid = threadIdx.x;
  int b = blockIdx.x;

  if (b < 550) {
    const float* src; int dstoff, K, N, tt;
    if (b < 4)        { src = aw;  dstoff = WOFF_AW; K = 64;   N = 128;  tt = b; }
    else if (b < 6)   { src = bw;  dstoff = WOFF_BW; K = 32;   N = 128;  tt = b - 4; }
    else if (b < 102) { src = p1w; dstoff = WOFF_P1; K = 384;  N = 512;  tt = b - 6; }
    else if (b < 166) { src = p2w; dstoff = WOFF_P2; K = 512;  N = 256;  tt = b - 102; }
    else if (b < 294) { src = p3w; dstoff = WOFF_P3; K = 256;  N = 1024; tt = b - 166; }
    else              { src = f1w; dstoff = WOFF_F1; K = 1024; N = 512;  tt = b - 294; }
    const int KT = K >> 5;
    const int kt = tt % KT;
    const int n0 = (tt / KT) * 64;
    for (int i = tid; i < 2048; i += 256) {
      int r = i >> 6, c = i & 63;
      t[r][c] = src[(size_t)(kt * 32 + r) * N + n0 + c];
    }
    __syncthreads();
    const int nc = n0 >> 7, nl0 = n0 & 127;
    bf16* dst = wpk + dstoff + ((size_t)(nc * KT + kt) * 128 + nl0) * 32;
    int o = tid * 8;
    int nl = o >> 5, kk = o & 31;
    bf16x8 v;
#pragma unroll
    for (int i = 0; i < 8; ++i) v[i] = (bf16)t[kk + i][nl];
    *(bf16x8*)(dst + nl * 32 + kk) = v;
  } else {
    const int kt = b - 550;
    for (int i = tid; i < 1024; i += 256) {
      int r = i >> 5, c = i & 31;
      t[r][c] = f2w[(size_t)(kt * 32 + r) * 32 + c];
    }
    __syncthreads();
    if (tid < 128) {
      int o = tid * 8;
      int nl = o >> 5, kk = o & 31;
      bf16x8 v;
#pragma unroll
      for (int i = 0; i < 8; ++i) v[i] = (bf16)t[kk + i][nl];
      *(bf16x8*)(wpk + WOFF_F2 + kt * 1024 + nl * 32 + kk) = v;
    }
  }
}

// kstep, 2 B-frags from global: 4 A-reads, 8 MFMA (M=64) -- embed phase only
static __device__ __forceinline__ void kstep2(const bf16* __restrict__ Ab,
                                              int astride, int acol,
                                              const bf16* __restrict__ b0p,
                                              const bf16* __restrict__ b1p,
                                              floatx4* acc, int lm, int lq) {
  bf16x8 b0 = *(const bf16x8*)b0p;
  bf16x8 b1 = *(const bf16x8*)b1p;
#pragma unroll
  for (int mt = 0; mt < 4; ++mt) {
    bf16x8 a = *(const bf16x8*)(Ab + (mt * 16 + lm) * astride + acol + lq * 8);
    acc[mt * 2]     = mfma16(a, b0, acc[mt * 2]);
    acc[mt * 2 + 1] = mfma16(a, b1, acc[mt * 2 + 1]);
  }
}

// epilogue for 2-N-tile acc: relu(acc+bias) -> LDS (M=64)
static __device__ __forceinline__ void epi2(const floatx4* acc,
                                            const float* __restrict__ bias,
                                            bf16* dst, int dstride, int w,
                                            int lm, int lq) {
#pragma unroll
  for (int mt = 0; mt < 4; ++mt)
#pragma unroll
    for (int j = 0; j < 2; ++j) {
      int col = (w + 4 * j) * 16 + lm;
      float bv = bias[col];
      floatx4 c = acc[mt * 2 + j];
#pragma unroll
      for (int r = 0; r < 4; ++r) {
        float v = c[r] + bv;
        v = v > 0.f ? v : 0.f;
        dst[(mt * 16 + lq * 4 + r) * dstride + col] = (bf16)v;
      }
    }
}

// ---------------------------------------------------------------------------
// seg_kernel: one block per 64-row WINDOW (no padding). Ends at p2; masked
// row-sums of h3 = relu(acc3+p2b) reduced straight from registers into
// hsum[2blk] / hsum[2blk+1] (f32, 256 cols). Straddle mask as in v10-v12.
// LDS: hbuf 50176 + pbuf 21504 = 71680 B -> 2 blocks/CU.
// p1/p2: B-prefetch 2-deep, A-prefetch 1-deep (registers; VGPR budget 256).
// ---------------------------------------------------------------------------
__global__ __launch_bounds__(256, 2) void seg_kernel(
    const float* __restrict__ pairs, const float* __restrict__ ab,
    const float* __restrict__ bb, const float* __restrict__ p1b,
    const float* __restrict__ p2b, const bf16* __restrict__ wpk,
    float* __restrict__ hsum) {
  __shared__ __align__(16) bf16 hbuf[64 * LSTR_H];  // h[64,384]
  __shared__ __align__(16) bf16 pbuf[64 * LSTR_P];  // pairs bf16, then h2 chunk

  const int tid = threadIdx.x;
  const int w = tid >> 6;
  const int lane = tid & 63;
  const int lm = lane & 15;
  const int lq = lane >> 4;
  const int blk = blockIdx.x;

  // ---- stage pairs window [64,160] fp32 -> bf16 LDS (all rows valid) ----
  {
    const float4* src = (const float4*)(pairs + (size_t)blk * (64 * 160));
    for (int i = tid; i < 64 * 40; i += 256) {
      int row = i / 40;
      int c4 = (i - row * 40) * 4;
      float4 v = src[i];
      bf16x4 o = {(bf16)v.x, (bf16)v.y, (bf16)v.z, (bf16)v.w};
      *(bf16x4*)(pbuf + row * LSTR_P + c4) = o;
    }
  }
  __syncthreads();

  const floatx4 fz = {0.f, 0.f, 0.f, 0.f};
  floatx4 acc[8];
  floatx4 acc3[16];

  // ---------------- embed: a1 / a2 / be -> hbuf[64,384] ----------------
#pragma unroll
  for (int t = 0; t < 8; ++t) acc[t] = fz;
#pragma unroll
  for (int kt = 0; kt < 2; ++kt)
    kstep2(pbuf, LSTR_P, kt * 32,
           wpk + WOFF_AW + ((size_t)(kt * 128 + w * 16 + lm)) * 32 + lq * 8,
           wpk + WOFF_AW + ((size_t)(kt * 128 + (w + 4) * 16 + lm)) * 32 + lq * 8,
           acc, lm, lq);
  epi2(acc, ab, hbuf, LSTR_H, w, lm, lq);
#pragma unroll
  for (int t = 0; t < 8; ++t) acc[t] = fz;
#pragma unroll
  for (int kt = 0; kt < 2; ++kt)
    kstep2(pbuf, LSTR_P, 64 + kt * 32,
           wpk + WOFF_AW + ((size_t)(kt * 128 + w * 16 + lm)) * 32 + lq * 8,
           wpk + WOFF_AW + ((size_t)(kt * 128 + (w + 4) * 16 + lm)) * 32 + lq * 8,
           acc, lm, lq);
  epi2(acc, ab, hbuf + 128, LSTR_H, w, lm, lq);
#pragma unroll
  for (int t = 0; t < 8; ++t) acc[t] = fz;
  kstep2(pbuf, LSTR_P, 128,
         wpk + WOFF_BW + ((size_t)(w * 16 + lm)) * 32 + lq * 8,
         wpk + WOFF_BW + ((size_t)((w + 4) * 16 + lm)) * 32 + lq * 8,
         acc, lm, lq);
  epi2(acc, bb, hbuf + 256, LSTR_H, w, lm, lq);

  __syncthreads();

  // ------- p1 (4 N-chunks of 128), each fused into p2 K-accumulation -------
#pragma unroll
  for (int t = 0; t < 16; ++t) acc3[t] = fz;

  for (int nc = 0; nc < 4; ++nc) {
#pragma unroll
    for (int t = 0; t < 8; ++t) acc[t] = fz;

    // ---- p1: h[64,384] @ p1w[:, nc*128..+128), B 2-deep pipelined ----
    {
      const bf16* bp = wpk + WOFF_P1 +
          ((size_t)(nc * 12) * 128 + w * 16 + lm) * 32 + lq * 8;
      bf16x8 bs0[2], bs1[2];
      bs0[0] = *(const bf16x8*)(bp);
      bs1[0] = *(const bf16x8*)(bp + 2048);
      bs0[1] = *(const bf16x8*)(bp + 4096);
      bs1[1] = *(const bf16x8*)(bp + 4096 + 2048);
      bf16x8 an[4];
#pragma unroll
      for (int mt = 0; mt < 4; ++mt)
        an[mt] = *(const bf16x8*)(hbuf + (mt * 16 + lm) * LSTR_H + lq * 8);
#pragma unroll
      for (int kt = 0; kt < 12; ++kt) {
        bf16x8 b0 = bs0[kt & 1], b1 = bs1[kt & 1];
        bf16x8 ac[4];
#pragma unroll
        for (int mt = 0; mt < 4; ++mt) ac[mt] = an[mt];
        if (kt < 11) {
#pragma unroll
          for (int mt = 0; mt < 4; ++mt)
            an[mt] = *(const bf16x8*)(hbuf + (mt * 16 + lm) * LSTR_H +
                                      (kt + 1) * 32 + lq * 8);
        }
        if (kt < 10) {
          bs0[kt & 1] = *(const bf16x8*)(bp + (size_t)(kt + 2) * 4096);
          bs1[kt & 1] = *(const bf16x8*)(bp + (size_t)(kt + 2) * 4096 + 2048);
        }
        __builtin_amdgcn_s_setprio(1);
#pragma unroll
        for (int mt = 0; mt < 4; ++mt) {
          acc[mt * 2]     = mfma16(ac[mt], b0, acc[mt * 2]);
          acc[mt * 2 + 1] = mfma16(ac[mt], b1, acc[mt * 2 + 1]);
        }
        __builtin_amdgcn_s_setprio(0);
      }
    }
    __syncthreads();                       // prior p2 reads of pbuf done
    epi2(acc, p1b + nc * 128, pbuf, LSTR_H2, w, lm, lq);
    __syncthreads();                       // h2 chunk visible

    // ---- p2: h2chunk[64,128] @ p2w chunk, acc3 accumulate, B 2-deep ----
    {
      const bf16* bp = wpk + WOFF_P2 +
          ((size_t)(((w >> 1) * 16 + nc * 4) * 128 + (w & 1) * 64 + lm)) * 32 +
          lq * 8;
      bf16x8 bs[2][4];
#pragma unroll
      for (int j = 0; j < 4; ++j) {
        bs[0][j] = *(const bf16x8*)(bp + j * 512);
        bs[1][j] = *(const bf16x8*)(bp + 4096 + j * 512);
      }
      bf16x8 an[4];
#pragma unroll
      for (int mt = 0; mt < 4; ++mt)
        an[mt] = *(const bf16x8*)(pbuf + (mt * 16 + lm) * LSTR_H2 + lq * 8);
#pragma unroll
      for (int kt2 = 0; kt2 < 4; ++kt2) {
        bf16x8 bc[4], ac[4];
#pragma unroll
        for (int j = 0; j < 4; ++j) bc[j] = bs[kt2 & 1][j];
#pragma unroll
        for (int mt = 0; mt < 4; ++mt) ac[mt] = an[mt];
        if (kt2 < 3) {
#pragma unroll
          for (int mt = 0; mt < 4; ++mt)
            an[mt] = *(const bf16x8*)(pbuf + (mt * 16 + lm) * LSTR_H2 +
                                      (kt2 + 1) * 32 + lq * 8);
        }
        if (kt2 < 2) {
#pragma unroll
          for (int j = 0; j < 4; ++j)
            bs[kt2 & 1][j] =
                *(const bf16x8*)(bp + (size_t)(kt2 + 2) * 4096 + j * 512);
        }
        __builtin_amdgcn_s_setprio(1);
#pragma unroll
        for (int mt = 0; mt < 4; ++mt)
#pragma unroll
          for (int j = 0; j < 4; ++j)
            acc3[mt * 4 + j] = mfma16(ac[mt], bc[j], acc3[mt * 4 + j]);
        __builtin_amdgcn_s_setprio(0);
      }
    }
  }

  // ---- masked row-sums of h3 = relu(acc3 + p2b), straight from registers ----
  const int s0 = (64 * blk) / 100;
  const int sp = (s0 + 1) * 100 - 64 * blk;
  floatx4 msk[4];
#pragma unroll
  for (int mt = 0; mt < 4; ++mt)
#pragma unroll
    for (int r = 0; r < 4; ++r)
      msk[mt][r] = (mt * 16 + lq * 4 + r < sp) ? 1.f : 0.f;

#pragma unroll
  for (int s = 0; s < 4; ++s) {
    int cl = w * 64 + s * 16 + lm;
    float bv = p2b[cl];
    float tot = 0.f, cs0 = 0.f;
#pragma unroll
    for (int mt = 0; mt < 4; ++mt) {
      floatx4 c = acc3[mt * 4 + s];
#pragma unroll
      for (int r = 0; r < 4; ++r) {
        float v = c[r] + bv;
        v = v > 0.f ? v : 0.f;
        tot += v;
        cs0 = fmaf(v, msk[mt][r], cs0);
      }
    }
    float cs1 = tot - cs0;
    cs0 += __shfl_xor(cs0, 16, 64);
    cs0 += __shfl_xor(cs0, 32, 64);
    cs1 += __shfl_xor(cs1, 16, 64);
    cs1 += __shfl_xor(cs1, 32, 64);
    if (lq == 0) {
      hsum[(size_t)(2 * blk) * 256 + cl]     = cs0;
      hsum[(size_t)(2 * blk + 1) * 256 + cl] = cs1;
    }
  }
}

// ---------------------------------------------------------------------------
// tail_kernel: mid+head1+head2 fused. 125 blocks x 512 threads (8 waves),
// 16 segments per block, everything through LDS:
//  ph1 gather window sums -> mean (ms[16,264])
//  ph2 hp = ms @ p3w + p3b        (wave w -> cols w*128..; 64 MFMA/wave)
//  ph3 h2 = relu(hp @ f1w + f1b)  (wave w -> cols w*64..; 128 MFMA/wave)
//  ph4 h3 = relu(h2 @ f2w + f2b) (waves 0-1), f3 dot (wave 0) -> out
// LDS 59.4 KB. Same op order/precision as v12's mid/head1/head2.
// ---------------------------------------------------------------------------
__global__ __launch_bounds__(512, 2) void tail_kernel(
    const bf16* __restrict__ wpk, const float* __restrict__ hsum,
    const int* __restrict__ idxp, const float* __restrict__ p3b,
    const float* __restrict__ f1b, const float* __restrict__ f2b,
    const float* __restrict__ f3w, const float* __restrict__ f3b,
    float* __restrict__ out) {
  __shared__ __align__(16) bf16 ms[16 * LSTR_MS];
  __shared__ __align__(16) bf16 hp[16 * 1032];
  __shared__ __align__(16) bf16 h2s[16 * 520];
  __shared__ __align__(16) bf16 h3s[16 * 40];

  const int tid = threadIdx.x;
  const int w = tid >> 6;          // 0..7
  const int lane = tid & 63;
  const int lm = lane & 15;
  const int lq = lane >> 4;
  const int r0 = blockIdx.x * 16;
  const floatx4 fz = {0.f, 0.f, 0.f, 0.f};

  // ---- ph1: gather 2-3 window partials per segment -> mean -> ms ----
  for (int i = tid; i < 16 * 64; i += 512) {
    int row = i >> 6, c4 = i & 63;
    int seg = r0 + row;
    int b_lo = (100 * seg) >> 6;
    int b_hi = (100 * seg + 99) >> 6;
    float4 sa = {0.f, 0.f, 0.f, 0.f};
    for (int b = b_lo; b <= b_hi; ++b) {
      int slot = (64 * b >= 100 * seg) ? 0 : 1;
      float4 v = *(const float4*)(hsum + (size_t)(2 * b + slot) * 256 + c4 * 4);
      sa.x += v.x; sa.y += v.y; sa.z += v.z; sa.w += v.w;
    }
    float inv = 1.f / (float)idxp[seg];
    bf16x4 o = {(bf16)(sa.x * inv), (bf16)(sa.y * inv),
                (bf16)(sa.z * inv), (bf16)(sa.w * inv)};
    *(bf16x4*)(ms + row * LSTR_MS + c4 * 4) = o;
  }
  __syncthreads();

  // ---- ph2: hp = ms @ p3w + p3b  (wave w covers cols w*128..w*128+128) ----
#pragma unroll
  for (int nt2 = 0; nt2 < 4; ++nt2) {
    floatx4 a2[2];
    a2[0] = fz; a2[1] = fz;
#pragma unroll
    for (int kt = 0; kt < 8; ++kt) {
      bf16x8 a = *(const bf16x8*)(ms + lm * LSTR_MS + kt * 32 + lq * 8);
#pragma unroll
      for (int j = 0; j < 2; ++j) {
        bf16x8 b = *(const bf16x8*)(wpk + WOFF_P3 +
            ((size_t)((w * 8 + kt) * 128 + (nt2 * 2 + j) * 16 + lm)) * 32 +
            lq * 8);
        a2[j] = mfma16(a, b, a2[j]);
      }
    }
#pragma unroll
    for (int j = 0; j < 2; ++j) {
      int col = w * 128 + (nt2 * 2 + j) * 16 + lm;
      float bv = p3b[col];
#pragma unroll
      for (int r = 0; r < 4; ++r)
        hp[(lq * 4 + r) * 1032 + col] = (bf16)(a2[j][r] + bv);
    }
  }
  __syncthreads();

  // ---- ph3: h2s = relu(hp @ f1w + f1b)  (wave w covers cols w*64..) ----
  {
    floatx4 a4[4];
#pragma unroll
    for (int j = 0; j < 4; ++j) a4[j] = fz;
#pragma unroll 8
    for (int kt = 0; kt < 32; ++kt) {
      bf16x8 a = *(const bf16x8*)(hp + lm * 1032 + kt * 32 + lq * 8);
#pragma unroll
      for (int j = 0; j < 4; ++j) {
        bf16x8 b = *(const bf16x8*)(wpk + WOFF_F1 +
            ((size_t)(((w >> 1) * 32 + kt) * 128 + (w & 1) * 64 + j * 16 + lm)) * 32 +
            lq * 8);
        a4[j] = mfma16(a, b, a4[j]);
      }
    }
#pragma unroll
    for (int j = 0; j < 4; ++j) {
      int col = w * 64 + j * 16 + lm;
      float bv = f1b[col];
#pragma unroll
      for (int r = 0; r < 4; ++r) {
        float v = a4[j][r] + bv;
        v = v > 0.f ? v : 0.f;
        h2s[(lq * 4 + r) * 520 + col] = (bf16)v;
      }
    }
  }
  __syncthreads();

  // ---- ph4: h3 = relu(h2 @ f2w + f2b) (waves 0-1); f3 dot (wave 0) ----
  if (w < 2) {
    floatx4 c2 = fz;
#pragma unroll
    for (int kt = 0; kt < 16; ++kt) {
      bf16x8 a = *(const bf16x8*)(h2s + lm * 520 + kt * 32 + lq * 8);
      bf16x8 b = *(const bf16x8*)(wpk + WOFF_F2 +
                    ((size_t)(kt * 32 + w * 16 + lm)) * 32 + lq * 8);
      c2 = mfma16(a, b, c2);
    }
    int col = w * 16 + lm;
    float bv = f2b[col];
#pragma unroll
    for (int r = 0; r < 4; ++r) {
      float v = c2[r] + bv;
      v = v > 0.f ? v : 0.f;
      h3s[(lq * 4 + r) * 40 + col] = (bf16)v;
    }
  }
  __syncthreads();
  if (w == 0) {
    float ps = 0.f;
#pragma unroll
    for (int jj = 0; jj < 8; ++jj)
      ps += (float)h3s[lm * 40 + lq * 8 + jj] * f3w[lq * 8 + jj];
    ps += __shfl_xor(ps, 16, 64);
    ps += __shfl_xor(ps, 32, 64);
    if (lq == 0) out[r0 + lm] = ps + f3b[0];
  }
}

// ---------------------------------------------------------------------------
extern "C" void kernel_launch(void* const* d_in, const int* in_sizes, int n_in,
                              void* d_out, int out_size, void* d_ws,
                              size_t ws_size, hipStream_t stream) {
  (void)in_sizes; (void)n_in; (void)out_size; (void)ws_size;
  const float* pairs = (const float*)d_in[0];
  const int*   idxp  = (const int*)d_in[1];
  // d_in[2] = ref_feats (unused by the reference)
  const float* aw  = (const float*)d_in[3];
  const float* ab  = (const float*)d_in[4];
  const float* bw  = (const float*)d_in[5];
  const float* bb  = (const float*)d_in[6];
  const float* p1w = (const float*)d_in[7];
  const float* p1b = (const float*)d_in[8];
  const float* p2w = (const float*)d_in[9];
  const float* p2b = (const float*)d_in[10];
  const float* p3w = (const float*)d_in[11];
  const float* p3b = (const float*)d_in[12];
  const float* f1w = (const float*)d_in[13];
  const float* f1b = (const float*)d_in[14];
  const float* f2w = (const float*)d_in[15];
  const float* f2b = (const float*)d_in[16];
  const float* f3w = (const float*)d_in[17];
  const float* f3b = (const float*)d_in[18];

  bf16* wpk = (bf16*)d_ws;
  float* hsum = (float*)(wpk + WOFF_HS);

  pack_lds<<<566, 256, 0, stream>>>(aw, bw, p1w, p2w, p3w, f1w, f2w, wpk);
  seg_kernel<<<NWIN, 256, 0, stream>>>(pairs, ab, bb, p1b, p2b, wpk, hsum);
  tail_kernel<<<125, 512, 0, stream>>>(wpk, hsum, idxp, p3b, f1b, f2b, f3w,
                                       f3b, (float*)d_out);
}

// Round 7
// 410.091 us; speedup vs baseline: 2.0339x; 1.0126x over previous
//
#include <hip/hip_runtime.h>
#include <cstdint>
#include <cstddef>

// ---------------------------------------------------------------------------
// TGNN fused pipeline v14 = v13 with the p1/p2 register pipeline PINNED:
//  - A and B prefetch both 2-deep ([kt&1] rotation, static indices, rule #20)
//  - asm volatile("" ::: "memory") between load-issue and MFMA cluster per kt:
//    forbids the compiler sinking prefetch loads to first-use (v13 postmortem:
//    VGPR 96 of 256 cap, 2-deep B silently collapsed to ~1-deep; same family
//    as guide rule #18 -- source order doesn't survive scheduling unpinned).
// v13 postmortem: tail fusion -21us (as predicted); seg 231->227 only.
// X = total - seg ~ 188us of which ~150 is launch/harness-fixed; seg's MFMA
// floor ~59us-equiv -> seg is the only target.
// Tripwires: seg VGPR >= 140 (pipeline materialized; else switch to 32x32
// MFMA next); WRITE_SIZE must stay exactly 6250KB (spill poison, v8 lesson).
// ---------------------------------------------------------------------------

typedef __bf16 bf16;
typedef __attribute__((ext_vector_type(8))) __bf16 bf16x8;
typedef __attribute__((ext_vector_type(4))) __bf16 bf16x4;
typedef __attribute__((ext_vector_type(4))) float floatx4;

#define GRP 100
#define NWIN 3125        // 200000 rows / 64

// packed-ws element offsets (bf16 elements)
#define WOFF_AW 0
#define WOFF_BW 8192
#define WOFF_P1 12288
#define WOFF_P2 208896
#define WOFF_P3 339968
#define WOFF_F1 602112
#define WOFF_F2 1126400
#define WOFF_HS 1142784          // hsum [6250][256] f32 (2 bf16 elems each)

// LDS strides (bf16 elems): %8==0 (16B-aligned b128 rows)
#define LSTR_P  168
#define LSTR_H  392
#define LSTR_H2 136
#define LSTR_MS 264

static __device__ __forceinline__ floatx4 mfma16(bf16x8 a, bf16x8 b, floatx4 c) {
  return __builtin_amdgcn_mfma_f32_16x16x32_bf16(a, b, c, 0, 0, 0);
}

// ---------------------------------------------------------------------------
// Coalesced weight repack: 32k x 64n tiles through an LDS transpose.
// fp32 [K][N] row-major -> bf16 ((nc*KT+kt)*CW + nl)*32 + kk, CW=128.
// 550 standard tiles + 16 tiles for f2w (CW=32). Proven correct in R6.
// (byte-identical since v7)
// ---------------------------------------------------------------------------
__global__ __launch_bounds__(256) void pack_lds(
    const float* __restrict__ aw, const float* __restrict__ bw,
    const float* __restrict__ p1w, const float* __restrict__ p2w,
    const float* __restrict__ p3w, const float* __restrict__ f1w,
    const float* __restrict__ f2w, bf16* __restrict__ wpk) {
  __shared__ float t[32][65];
  const int tid = threadIdx.x;
  int b = blockIdx.x;

  if (b < 550) {
    const float* src; int dstoff, K, N, tt;
    if (b < 4)        { src = aw;  dstoff = WOFF_AW; K = 64;   N = 128;  tt = b; }
    else if (b < 6)   { src = bw;  dstoff = WOFF_BW; K = 32;   N = 128;  tt = b - 4; }
    else if (b < 102) { src = p1w; dstoff = WOFF_P1; K = 384;  N = 512;  tt = b - 6; }
    else if (b < 166) { src = p2w; dstoff = WOFF_P2; K = 512;  N = 256;  tt = b - 102; }
    else if (b < 294) { src = p3w; dstoff = WOFF_P3; K = 256;  N = 1024; tt = b - 166; }
    else              { src = f1w; dstoff = WOFF_F1; K = 1024; N = 512;  tt = b - 294; }
    const int KT = K >> 5;
    const int kt = tt % KT;
    const int n0 = (tt / KT) * 64;
    for (int i = tid; i < 2048; i += 256) {
      int r = i >> 6, c = i & 63;
      t[r][c] = src[(size_t)(kt * 32 + r) * N + n0 + c];
    }
    __syncthreads();
    const int nc = n0 >> 7, nl0 = n0 & 127;
    bf16* dst = wpk + dstoff + ((size_t)(nc * KT + kt) * 128 + nl0) * 32;
    int o = tid * 8;
    int nl = o >> 5, kk = o & 31;
    bf16x8 v;
#pragma unroll
    for (int i = 0; i < 8; ++i) v[i] = (bf16)t[kk + i][nl];
    *(bf16x8*)(dst + nl * 32 + kk) = v;
  } else {
    const int kt = b - 550;
    for (int i = tid; i < 1024; i += 256) {
      int r = i >> 5, c = i & 31;
      t[r][c] = f2w[(size_t)(kt * 32 + r) * 32 + c];
    }
    __syncthreads();
    if (tid < 128) {
      int o = tid * 8;
      int nl = o >> 5, kk = o & 31;
      bf16x8 v;
#pragma unroll
      for (int i = 0; i < 8; ++i) v[i] = (bf16)t[kk + i][nl];
      *(bf16x8*)(wpk + WOFF_F2 + kt * 1024 + nl * 32 + kk) = v;
    }
  }
}

// kstep, 2 B-frags from global: 4 A-reads, 8 MFMA (M=64) -- embed phase only
static __device__ __forceinline__ void kstep2(const bf16* __restrict__ Ab,
                                              int astride, int acol,
                                              const bf16* __restrict__ b0p,
                                              const bf16* __restrict__ b1p,
                                              floatx4* acc, int lm, int lq) {
  bf16x8 b0 = *(const bf16x8*)b0p;
  bf16x8 b1 = *(const bf16x8*)b1p;
#pragma unroll
  for (int mt = 0; mt < 4; ++mt) {
    bf16x8 a = *(const bf16x8*)(Ab + (mt * 16 + lm) * astride + acol + lq * 8);
    acc[mt * 2]     = mfma16(a, b0, acc[mt * 2]);
    acc[mt * 2 + 1] = mfma16(a, b1, acc[mt * 2 + 1]);
  }
}

// epilogue for 2-N-tile acc: relu(acc+bias) -> LDS (M=64)
static __device__ __forceinline__ void epi2(const floatx4* acc,
                                            const float* __restrict__ bias,
                                            bf16* dst, int dstride, int w,
                                            int lm, int lq) {
#pragma unroll
  for (int mt = 0; mt < 4; ++mt)
#pragma unroll
    for (int j = 0; j < 2; ++j) {
      int col = (w + 4 * j) * 16 + lm;
      float bv = bias[col];
      floatx4 c = acc[mt * 2 + j];
#pragma unroll
      for (int r = 0; r < 4; ++r) {
        float v = c[r] + bv;
        v = v > 0.f ? v : 0.f;
        dst[(mt * 16 + lq * 4 + r) * dstride + col] = (bf16)v;
      }
    }
}

// ---------------------------------------------------------------------------
// seg_kernel: one block per 64-row WINDOW (no padding). Ends at p2; masked
// row-sums of h3 = relu(acc3+p2b) reduced straight from registers into
// hsum[2blk] / hsum[2blk+1] (f32, 256 cols). Straddle mask as in v10-v13.
// LDS: hbuf 50176 + pbuf 21504 = 71680 B -> 2 blocks/CU.
// p1/p2: A and B prefetch 2-deep, pinned with per-kt compiler memory fences.
// ---------------------------------------------------------------------------
__global__ __launch_bounds__(256, 2) void seg_kernel(
    const float* __restrict__ pairs, const float* __restrict__ ab,
    const float* __restrict__ bb, const float* __restrict__ p1b,
    const float* __restrict__ p2b, const bf16* __restrict__ wpk,
    float* __restrict__ hsum) {
  __shared__ __align__(16) bf16 hbuf[64 * LSTR_H];  // h[64,384]
  __shared__ __align__(16) bf16 pbuf[64 * LSTR_P];  // pairs bf16, then h2 chunk

  const int tid = threadIdx.x;
  const int w = tid >> 6;
  const int lane = tid & 63;
  const int lm = lane & 15;
  const int lq = lane >> 4;
  const int blk = blockIdx.x;

  // ---- stage pairs window [64,160] fp32 -> bf16 LDS (all rows valid) ----
  {
    const float4* src = (const float4*)(pairs + (size_t)blk * (64 * 160));
    for (int i = tid; i < 64 * 40; i += 256) {
      int row = i / 40;
      int c4 = (i - row * 40) * 4;
      float4 v = src[i];
      bf16x4 o = {(bf16)v.x, (bf16)v.y, (bf16)v.z, (bf16)v.w};
      *(bf16x4*)(pbuf + row * LSTR_P + c4) = o;
    }
  }
  __syncthreads();

  const floatx4 fz = {0.f, 0.f, 0.f, 0.f};
  floatx4 acc[8];
  floatx4 acc3[16];

  // ---------------- embed: a1 / a2 / be -> hbuf[64,384] ----------------
#pragma unroll
  for (int t = 0; t < 8; ++t) acc[t] = fz;
#pragma unroll
  for (int kt = 0; kt < 2; ++kt)
    kstep2(pbuf, LSTR_P, kt * 32,
           wpk + WOFF_AW + ((size_t)(kt * 128 + w * 16 + lm)) * 32 + lq * 8,
           wpk + WOFF_AW + ((size_t)(kt * 128 + (w + 4) * 16 + lm)) * 32 + lq * 8,
           acc, lm, lq);
  epi2(acc, ab, hbuf, LSTR_H, w, lm, lq);
#pragma unroll
  for (int t = 0; t < 8; ++t) acc[t] = fz;
#pragma unroll
  for (int kt = 0; kt < 2; ++kt)
    kstep2(pbuf, LSTR_P, 64 + kt * 32,
           wpk + WOFF_AW + ((size_t)(kt * 128 + w * 16 + lm)) * 32 + lq * 8,
           wpk + WOFF_AW + ((size_t)(kt * 128 + (w + 4) * 16 + lm)) * 32 + lq * 8,
           acc, lm, lq);
  epi2(acc, ab, hbuf + 128, LSTR_H, w, lm, lq);
#pragma unroll
  for (int t = 0; t < 8; ++t) acc[t] = fz;
  kstep2(pbuf, LSTR_P, 128,
         wpk + WOFF_BW + ((size_t)(w * 16 + lm)) * 32 + lq * 8,
         wpk + WOFF_BW + ((size_t)((w + 4) * 16 + lm)) * 32 + lq * 8,
         acc, lm, lq);
  epi2(acc, bb, hbuf + 256, LSTR_H, w, lm, lq);

  __syncthreads();

  // ------- p1 (4 N-chunks of 128), each fused into p2 K-accumulation -------
#pragma unroll
  for (int t = 0; t < 16; ++t) acc3[t] = fz;

  for (int nc = 0; nc < 4; ++nc) {
#pragma unroll
    for (int t = 0; t < 8; ++t) acc[t] = fz;

    // ---- p1: h[64,384] @ p1w[:, nc*128..+128), A/B 2-deep, pinned ----
    {
      const bf16* bp = wpk + WOFF_P1 +
          ((size_t)(nc * 12) * 128 + w * 16 + lm) * 32 + lq * 8;
      bf16x8 bs0[2], bs1[2];
      bf16x8 an[2][4];
#pragma unroll
      for (int q = 0; q < 2; ++q) {
        bs0[q] = *(const bf16x8*)(bp + (size_t)q * 4096);
        bs1[q] = *(const bf16x8*)(bp + (size_t)q * 4096 + 2048);
#pragma unroll
        for (int mt = 0; mt < 4; ++mt)
          an[q][mt] = *(const bf16x8*)(hbuf + (mt * 16 + lm) * LSTR_H +
                                       q * 32 + lq * 8);
      }
#pragma unroll
      for (int kt = 0; kt < 12; ++kt) {
        bf16x8 b0 = bs0[kt & 1], b1 = bs1[kt & 1];
        bf16x8 ac[4];
#pragma unroll
        for (int mt = 0; mt < 4; ++mt) ac[mt] = an[kt & 1][mt];
        if (kt < 10) {
          bs0[kt & 1] = *(const bf16x8*)(bp + (size_t)(kt + 2) * 4096);
          bs1[kt & 1] = *(const bf16x8*)(bp + (size_t)(kt + 2) * 4096 + 2048);
#pragma unroll
          for (int mt = 0; mt < 4; ++mt)
            an[kt & 1][mt] = *(const bf16x8*)(hbuf + (mt * 16 + lm) * LSTR_H +
                                              (kt + 2) * 32 + lq * 8);
        }
        asm volatile("" ::: "memory");   // pin: loads above may not sink below
        __builtin_amdgcn_s_setprio(1);
#pragma unroll
        for (int mt = 0; mt < 4; ++mt) {
          acc[mt * 2]     = mfma16(ac[mt], b0, acc[mt * 2]);
          acc[mt * 2 + 1] = mfma16(ac[mt], b1, acc[mt * 2 + 1]);
        }
        __builtin_amdgcn_s_setprio(0);
      }
    }
    __syncthreads();                       // prior p2 reads of pbuf done
    epi2(acc, p1b + nc * 128, pbuf, LSTR_H2, w, lm, lq);
    __syncthreads();                       // h2 chunk visible

    // ---- p2: h2chunk[64,128] @ p2w chunk, acc3 accumulate, 2-deep pinned ----
    {
      const bf16* bp = wpk + WOFF_P2 +
          ((size_t)(((w >> 1) * 16 + nc * 4) * 128 + (w & 1) * 64 + lm)) * 32 +
          lq * 8;
      bf16x8 bs[2][4];
      bf16x8 an[2][4];
#pragma unroll
      for (int q = 0; q < 2; ++q) {
#pragma unroll
        for (int j = 0; j < 4; ++j)
          bs[q][j] = *(const bf16x8*)(bp + (size_t)q * 4096 + j * 512);
#pragma unroll
        for (int mt = 0; mt < 4; ++mt)
          an[q][mt] = *(const bf16x8*)(pbuf + (mt * 16 + lm) * LSTR_H2 +
                                       q * 32 + lq * 8);
      }
#pragma unroll
      for (int kt2 = 0; kt2 < 4; ++kt2) {
        bf16x8 bc[4], ac[4];
#pragma unroll
        for (int j = 0; j < 4; ++j) bc[j] = bs[kt2 & 1][j];
#pragma unroll
        for (int mt = 0; mt < 4; ++mt) ac[mt] = an[kt2 & 1][mt];
        if (kt2 < 2) {
#pragma unroll
          for (int j = 0; j < 4; ++j)
            bs[kt2 & 1][j] =
                *(const bf16x8*)(bp + (size_t)(kt2 + 2) * 4096 + j * 512);
#pragma unroll
          for (int mt = 0; mt < 4; ++mt)
            an[kt2 & 1][mt] = *(const bf16x8*)(pbuf + (mt * 16 + lm) * LSTR_H2 +
                                               (kt2 + 2) * 32 + lq * 8);
        }
        asm volatile("" ::: "memory");   // pin
        __builtin_amdgcn_s_setprio(1);
#pragma unroll
        for (int mt = 0; mt < 4; ++mt)
#pragma unroll
          for (int j = 0; j < 4; ++j)
            acc3[mt * 4 + j] = mfma16(ac[mt], bc[j], acc3[mt * 4 + j]);
        __builtin_amdgcn_s_setprio(0);
      }
    }
  }

  // ---- masked row-sums of h3 = relu(acc3 + p2b), straight from registers ----
  const int s0 = (64 * blk) / 100;
  const int sp = (s0 + 1) * 100 - 64 * blk;
  floatx4 msk[4];
#pragma unroll
  for (int mt = 0; mt < 4; ++mt)
#pragma unroll
    for (int r = 0; r < 4; ++r)
      msk[mt][r] = (mt * 16 + lq * 4 + r < sp) ? 1.f : 0.f;

#pragma unroll
  for (int s = 0; s < 4; ++s) {
    int cl = w * 64 + s * 16 + lm;
    float bv = p2b[cl];
    float tot = 0.f, cs0 = 0.f;
#pragma unroll
    for (int mt = 0; mt < 4; ++mt) {
      floatx4 c = acc3[mt * 4 + s];
#pragma unroll
      for (int r = 0; r < 4; ++r) {
        float v = c[r] + bv;
        v = v > 0.f ? v : 0.f;
        tot += v;
        cs0 = fmaf(v, msk[mt][r], cs0);
      }
    }
    float cs1 = tot - cs0;
    cs0 += __shfl_xor(cs0, 16, 64);
    cs0 += __shfl_xor(cs0, 32, 64);
    cs1 += __shfl_xor(cs1, 16, 64);
    cs1 += __shfl_xor(cs1, 32, 64);
    if (lq == 0) {
      hsum[(size_t)(2 * blk) * 256 + cl]     = cs0;
      hsum[(size_t)(2 * blk + 1) * 256 + cl] = cs1;
    }
  }
}

// ---------------------------------------------------------------------------
// tail_kernel: mid+head1+head2 fused. 125 blocks x 512 threads (8 waves),
// 16 segments per block, everything through LDS. (byte-identical to v13)
// ---------------------------------------------------------------------------
__global__ __launch_bounds__(512, 2) void tail_kernel(
    const bf16* __restrict__ wpk, const float* __restrict__ hsum,
    const int* __restrict__ idxp, const float* __restrict__ p3b,
    const float* __restrict__ f1b, const float* __restrict__ f2b,
    const float* __restrict__ f3w, const float* __restrict__ f3b,
    float* __restrict__ out) {
  __shared__ __align__(16) bf16 ms[16 * LSTR_MS];
  __shared__ __align__(16) bf16 hp[16 * 1032];
  __shared__ __align__(16) bf16 h2s[16 * 520];
  __shared__ __align__(16) bf16 h3s[16 * 40];

  const int tid = threadIdx.x;
  const int w = tid >> 6;          // 0..7
  const int lane = tid & 63;
  const int lm = lane & 15;
  const int lq = lane >> 4;
  const int r0 = blockIdx.x * 16;
  const floatx4 fz = {0.f, 0.f, 0.f, 0.f};

  // ---- ph1: gather 2-3 window partials per segment -> mean -> ms ----
  for (int i = tid; i < 16 * 64; i += 512) {
    int row = i >> 6, c4 = i & 63;
    int seg = r0 + row;
    int b_lo = (100 * seg) >> 6;
    int b_hi = (100 * seg + 99) >> 6;
    float4 sa = {0.f, 0.f, 0.f, 0.f};
    for (int b = b_lo; b <= b_hi; ++b) {
      int slot = (64 * b >= 100 * seg) ? 0 : 1;
      float4 v = *(const float4*)(hsum + (size_t)(2 * b + slot) * 256 + c4 * 4);
      sa.x += v.x; sa.y += v.y; sa.z += v.z; sa.w += v.w;
    }
    float inv = 1.f / (float)idxp[seg];
    bf16x4 o = {(bf16)(sa.x * inv), (bf16)(sa.y * inv),
                (bf16)(sa.z * inv), (bf16)(sa.w * inv)};
    *(bf16x4*)(ms + row * LSTR_MS + c4 * 4) = o;
  }
  __syncthreads();

  // ---- ph2: hp = ms @ p3w + p3b  (wave w covers cols w*128..w*128+128) ----
#pragma unroll
  for (int nt2 = 0; nt2 < 4; ++nt2) {
    floatx4 a2[2];
    a2[0] = fz; a2[1] = fz;
#pragma unroll
    for (int kt = 0; kt < 8; ++kt) {
      bf16x8 a = *(const bf16x8*)(ms + lm * LSTR_MS + kt * 32 + lq * 8);
#pragma unroll
      for (int j = 0; j < 2; ++j) {
        bf16x8 b = *(const bf16x8*)(wpk + WOFF_P3 +
            ((size_t)((w * 8 + kt) * 128 + (nt2 * 2 + j) * 16 + lm)) * 32 +
            lq * 8);
        a2[j] = mfma16(a, b, a2[j]);
      }
    }
#pragma unroll
    for (int j = 0; j < 2; ++j) {
      int col = w * 128 + (nt2 * 2 + j) * 16 + lm;
      float bv = p3b[col];
#pragma unroll
      for (int r = 0; r < 4; ++r)
        hp[(lq * 4 + r) * 1032 + col] = (bf16)(a2[j][r] + bv);
    }
  }
  __syncthreads();

  // ---- ph3: h2s = relu(hp @ f1w + f1b)  (wave w covers cols w*64..) ----
  {
    floatx4 a4[4];
#pragma unroll
    for (int j = 0; j < 4; ++j) a4[j] = fz;
#pragma unroll 8
    for (int kt = 0; kt < 32; ++kt) {
      bf16x8 a = *(const bf16x8*)(hp + lm * 1032 + kt * 32 + lq * 8);
#pragma unroll
      for (int j = 0; j < 4; ++j) {
        bf16x8 b = *(const bf16x8*)(wpk + WOFF_F1 +
            ((size_t)(((w >> 1) * 32 + kt) * 128 + (w & 1) * 64 + j * 16 + lm)) * 32 +
            lq * 8);
        a4[j] = mfma16(a, b, a4[j]);
      }
    }
#pragma unroll
    for (int j = 0; j < 4; ++j) {
      int col = w * 64 + j * 16 + lm;
      float bv = f1b[col];
#pragma unroll
      for (int r = 0; r < 4; ++r) {
        float v = a4[j][r] + bv;
        v = v > 0.f ? v : 0.f;
        h2s[(lq * 4 + r) * 520 + col] = (bf16)v;
      }
    }
  }
  __syncthreads();

  // ---- ph4: h3 = relu(h2 @ f2w + f2b) (waves 0-1); f3 dot (wave 0) ----
  if (w < 2) {
    floatx4 c2 = fz;
#pragma unroll
    for (int kt = 0; kt < 16; ++kt) {
      bf16x8 a = *(const bf16x8*)(h2s + lm * 520 + kt * 32 + lq * 8);
      bf16x8 b = *(const bf16x8*)(wpk + WOFF_F2 +
                    ((size_t)(kt * 32 + w * 16 + lm)) * 32 + lq * 8);
      c2 = mfma16(a, b, c2);
    }
    int col = w * 16 + lm;
    float bv = f2b[col];
#pragma unroll
    for (int r = 0; r < 4; ++r) {
      float v = c2[r] + bv;
      v = v > 0.f ? v : 0.f;
      h3s[(lq * 4 + r) * 40 + col] = (bf16)v;
    }
  }
  __syncthreads();
  if (w == 0) {
    float ps = 0.f;
#pragma unroll
    for (int jj = 0; jj < 8; ++jj)
      ps += (float)h3s[lm * 40 + lq * 8 + jj] * f3w[lq * 8 + jj];
    ps += __shfl_xor(ps, 16, 64);
    ps += __shfl_xor(ps, 32, 64);
    if (lq == 0) out[r0 + lm] = ps + f3b[0];
  }
}

// ---------------------------------------------------------------------------
extern "C" void kernel_launch(void* const* d_in, const int* in_sizes, int n_in,
                              void* d_out, int out_size, void* d_ws,
                              size_t ws_size, hipStream_t stream) {
  (void)in_sizes; (void)n_in; (void)out_size; (void)ws_size;
  const float* pairs = (const float*)d_in[0];
  const int*   idxp  = (const int*)d_in[1];
  // d_in[2] = ref_feats (unused by the reference)
  const float* aw  = (const float*)d_in[3];
  const float* ab  = (const float*)d_in[4];
  const float* bw  = (const float*)d_in[5];
  const float* bb  = (const float*)d_in[6];
  const float* p1w = (const float*)d_in[7];
  const float* p1b = (const float*)d_in[8];
  const float* p2w = (const float*)d_in[9];
  const float* p2b = (const float*)d_in[10];
  const float* p3w = (const float*)d_in[11];
  const float* p3b = (const float*)d_in[12];
  const float* f1w = (const float*)d_in[13];
  const float* f1b = (const float*)d_in[14];
  const float* f2w = (const float*)d_in[15];
  const float* f2b = (const float*)d_in[16];
  const float* f3w = (const float*)d_in[17];
  const float* f3b = (const float*)d_in[18];

  bf16* wpk = (bf16*)d_ws;
  float* hsum = (float*)(wpk + WOFF_HS);

  pack_lds<<<566, 256, 0, stream>>>(aw, bw, p1w, p2w, p3w, f1w, f2w, wpk);
  seg_kernel<<<NWIN, 256, 0, stream>>>(pairs, ab, bb, p1b, p2b, wpk, hsum);
  tail_kernel<<<125, 512, 0, stream>>>(wpk, hsum, idxp, p3b, f1b, f2b, f3w,
                                       f3b, (float*)d_out);
}

// Round 8
// 399.478 us; speedup vs baseline: 2.0879x; 1.0266x over previous
//
#include <hip/hip_runtime.h>
#include <cstdint>
#include <cstddef>

// ---------------------------------------------------------------------------
// TGNN fused pipeline v15 = v14 with seg's p1/p2 B-stream moved to INLINE-ASM
// global_load_dwordx4 + hand-counted s_waitcnt vmcnt(N) + sched_barrier(0),
// and all __syncthreads() replaced by {s_waitcnt lgkmcnt(0); s_barrier}.
// Why: v13/v14 proved hipcc reorders invariant loads across "memory" clobbers
// (VGPR stuck 96-104, MfmaUtil*dur invariant 59 across all tweaks), and
// __syncthreads' vmcnt(0) drain kills any cross-phase prefetch (10 barriers/
// block). Weights are read-only -> global loads may stay in flight across
// barriers; LDS hazards only need lgkmcnt(0). Volatile asm ordering is the
// one thing the scheduler cannot undo (guide T3/T4, m201-verified).
// Schedule: p1 B 4-slot/3-kt lead (waits 6/6..6,4,2,0); p2 B 3-slot with
// phase-start 8 loads hoisted across both barriers+epi2 (waits 8,14,10,6);
// next-nc p1 prologue (6 loads) issued mid-p2 (dummy wrap at nc=3 keeps the
// count schedule nc-invariant). Biases preloaded to regs (a compiler bias
// load inside epi2 would emit vmcnt(0) and drain everything). nc loop fully
// unrolled -> all slots/waits literal (rule #20).
// Tripwires: WRITE_SIZE must stay exactly 6250KB (spill); absmax 0 (asm
// hazard); VGPR should jump to ~170-220.
// ---------------------------------------------------------------------------

typedef __bf16 bf16;
typedef __attribute__((ext_vector_type(8))) __bf16 bf16x8;
typedef __attribute__((ext_vector_type(4))) __bf16 bf16x4;
typedef __attribute__((ext_vector_type(4))) float floatx4;

#define GRP 100
#define NWIN 3125        // 200000 rows / 64

// packed-ws element offsets (bf16 elements)
#define WOFF_AW 0
#define WOFF_BW 8192
#define WOFF_P1 12288
#define WOFF_P2 208896
#define WOFF_P3 339968
#define WOFF_F1 602112
#define WOFF_F2 1126400
#define WOFF_HS 1142784          // hsum [6250][256] f32 (2 bf16 elems each)

// LDS strides (bf16 elems): %8==0 (16B-aligned b128 rows)
#define LSTR_P  168
#define LSTR_H  392
#define LSTR_H2 136
#define LSTR_MS 264

static __device__ __forceinline__ floatx4 mfma16(bf16x8 a, bf16x8 b, floatx4 c) {
  return __builtin_amdgcn_mfma_f32_16x16x32_bf16(a, b, c, 0, 0, 0);
}

// async B-load: 16B global -> 4 VGPR; completion tracked ONLY by our vmcnt
static __device__ __forceinline__ void gload(floatx4& d, const bf16* p) {
  asm volatile("global_load_dwordx4 %0, %1, off" : "=v"(d) : "v"(p));
}
static __device__ __forceinline__ bf16x8 bc8(floatx4 v) {
  return __builtin_bit_cast(bf16x8, v);
}

// wait until <=N of our asm loads outstanding, then fence the scheduler so
// MFMAs can't hoist above the wait (guide rule #18)
#define VMW(N)                                         \
  do {                                                 \
    asm volatile("s_waitcnt vmcnt(" #N ")");           \
    __builtin_amdgcn_sched_barrier(0);                 \
  } while (0)

// barrier with LDS-only drain: global loads stay in flight across it
#define SYNCL()                                        \
  do {                                                 \
    asm volatile("s_waitcnt lgkmcnt(0)" ::: "memory"); \
    __builtin_amdgcn_s_barrier();                      \
  } while (0)

// ---------------------------------------------------------------------------
// Coalesced weight repack (byte-identical since v7).
// ---------------------------------------------------------------------------
__global__ __launch_bounds__(256) void pack_lds(
    const float* __restrict__ aw, const float* __restrict__ bw,
    const float* __restrict__ p1w, const float* __restrict__ p2w,
    const float* __restrict__ p3w, const float* __restrict__ f1w,
    const float* __restrict__ f2w, bf16* __restrict__ wpk) {
  __shared__ float t[32][65];
  const int tid = threadIdx.x;
  int b = blockIdx.x;

  if (b < 550) {
    const float* src; int dstoff, K, N, tt;
    if (b < 4)        { src = aw;  dstoff = WOFF_AW; K = 64;   N = 128;  tt = b; }
    else if (b < 6)   { src = bw;  dstoff = WOFF_BW; K = 32;   N = 128;  tt = b - 4; }
    else if (b < 102) { src = p1w; dstoff = WOFF_P1; K = 384;  N = 512;  tt = b - 6; }
    else if (b < 166) { src = p2w; dstoff = WOFF_P2; K = 512;  N = 256;  tt = b - 102; }
    else if (b < 294) { src = p3w; dstoff = WOFF_P3; K = 256;  N = 1024; tt = b - 166; }
    else              { src = f1w; dstoff = WOFF_F1; K = 1024; N = 512;  tt = b - 294; }
    const int KT = K >> 5;
    const int kt = tt % KT;
    const int n0 = (tt / KT) * 64;
    for (int i = tid; i < 2048; i += 256) {
      int r = i >> 6, c = i & 63;
      t[r][c] = src[(size_t)(kt * 32 + r) * N + n0 + c];
    }
    __syncthreads();
    const int nc = n0 >> 7, nl0 = n0 & 127;
    bf16* dst = wpk + dstoff + ((size_t)(nc * KT + kt) * 128 + nl0) * 32;
    int o = tid * 8;
    int nl = o >> 5, kk = o & 31;
    bf16x8 v;
#pragma unroll
    for (int i = 0; i < 8; ++i) v[i] = (bf16)t[kk + i][nl];
    *(bf16x8*)(dst + nl * 32 + kk) = v;
  } else {
    const int kt = b - 550;
    for (int i = tid; i < 1024; i += 256) {
      int r = i >> 5, c = i & 31;
      t[r][c] = f2w[(size_t)(kt * 32 + r) * 32 + c];
    }
    __syncthreads();
    if (tid < 128) {
      int o = tid * 8;
      int nl = o >> 5, kk = o & 31;
      bf16x8 v;
#pragma unroll
      for (int i = 0; i < 8; ++i) v[i] = (bf16)t[kk + i][nl];
      *(bf16x8*)(wpk + WOFF_F2 + kt * 1024 + nl * 32 + kk) = v;
    }
  }
}

// kstep, 2 B-frags from global: 4 A-reads, 8 MFMA (M=64) -- embed phase only
static __device__ __forceinline__ void kstep2(const bf16* __restrict__ Ab,
                                              int astride, int acol,
                                              const bf16* __restrict__ b0p,
                                              const bf16* __restrict__ b1p,
                                              floatx4* acc, int lm, int lq) {
  bf16x8 b0 = *(const bf16x8*)b0p;
  bf16x8 b1 = *(const bf16x8*)b1p;
#pragma unroll
  for (int mt = 0; mt < 4; ++mt) {
    bf16x8 a = *(const bf16x8*)(Ab + (mt * 16 + lm) * astride + acol + lq * 8);
    acc[mt * 2]     = mfma16(a, b0, acc[mt * 2]);
    acc[mt * 2 + 1] = mfma16(a, b1, acc[mt * 2 + 1]);
  }
}

// epilogue for 2-N-tile acc, pointer-bias version (embed only)
static __device__ __forceinline__ void epi2(const floatx4* acc,
                                            const float* __restrict__ bias,
                                            bf16* dst, int dstride, int w,
                                            int lm, int lq) {
#pragma unroll
  for (int mt = 0; mt < 4; ++mt)
#pragma unroll
    for (int j = 0; j < 2; ++j) {
      int col = (w + 4 * j) * 16 + lm;
      float bv = bias[col];
      floatx4 c = acc[mt * 2 + j];
#pragma unroll
      for (int r = 0; r < 4; ++r) {
        float v = c[r] + bv;
        v = v > 0.f ? v : 0.f;
        dst[(mt * 16 + lq * 4 + r) * dstride + col] = (bf16)v;
      }
    }
}

// epilogue, register-bias version (p1 phases; no vmem => no vmcnt drain)
static __device__ __forceinline__ void epi2v(const floatx4* acc, float bv0,
                                             float bv1, bf16* dst, int dstride,
                                             int w, int lm, int lq) {
#pragma unroll
  for (int mt = 0; mt < 4; ++mt)
#pragma unroll
    for (int j = 0; j < 2; ++j) {
      int col = (w + 4 * j) * 16 + lm;
      float bv = j ? bv1 : bv0;
      floatx4 c = acc[mt * 2 + j];
#pragma unroll
      for (int r = 0; r < 4; ++r) {
        float v = c[r] + bv;
        v = v > 0.f ? v : 0.f;
        dst[(mt * 16 + lq * 4 + r) * dstride + col] = (bf16)v;
      }
    }
}

// ---------------------------------------------------------------------------
// seg_kernel: one block per 64-row WINDOW. Ends at p2; masked row-sums of
// h3 = relu(acc3+p2b) straight from registers -> hsum (f32). LDS 71680 B
// -> 2 blocks/CU. p1/p2 B-stream fully asm-pipelined (see header).
// ---------------------------------------------------------------------------
__global__ __launch_bounds__(256, 2) void seg_kernel(
    const float* __restrict__ pairs, const float* __restrict__ ab,
    const float* __restrict__ bb, const float* __restrict__ p1b,
    const float* __restrict__ p2b, const bf16* __restrict__ wpk,
    float* __restrict__ hsum) {
  __shared__ __align__(16) bf16 hbuf[64 * LSTR_H];  // h[64,384]
  __shared__ __align__(16) bf16 pbuf[64 * LSTR_P];  // pairs bf16, then h2 chunk

  const int tid = threadIdx.x;
  const int w = tid >> 6;
  const int lane = tid & 63;
  const int lm = lane & 15;
  const int lq = lane >> 4;
  const int blk = blockIdx.x;

  // ---- stage pairs window [64,160] fp32 -> bf16 LDS (all rows valid) ----
  {
    const float4* src = (const float4*)(pairs + (size_t)blk * (64 * 160));
    for (int i = tid; i < 64 * 40; i += 256) {
      int row = i / 40;
      int c4 = (i - row * 40) * 4;
      float4 v = src[i];
      bf16x4 o = {(bf16)v.x, (bf16)v.y, (bf16)v.z, (bf16)v.w};
      *(bf16x4*)(pbuf + row * LSTR_P + c4) = o;
    }
  }
  SYNCL();

  const floatx4 fz = {0.f, 0.f, 0.f, 0.f};
  floatx4 acc[8];
  floatx4 acc3[16];

  // ---------------- embed: a1 / a2 / be -> hbuf[64,384] ----------------
#pragma unroll
  for (int t = 0; t < 8; ++t) acc[t] = fz;
#pragma unroll
  for (int kt = 0; kt < 2; ++kt)
    kstep2(pbuf, LSTR_P, kt * 32,
           wpk + WOFF_AW + ((size_t)(kt * 128 + w * 16 + lm)) * 32 + lq * 8,
           wpk + WOFF_AW + ((size_t)(kt * 128 + (w + 4) * 16 + lm)) * 32 + lq * 8,
           acc, lm, lq);
  epi2(acc, ab, hbuf, LSTR_H, w, lm, lq);
#pragma unroll
  for (int t = 0; t < 8; ++t) acc[t] = fz;
#pragma unroll
  for (int kt = 0; kt < 2; ++kt)
    kstep2(pbuf, LSTR_P, 64 + kt * 32,
           wpk + WOFF_AW + ((size_t)(kt * 128 + w * 16 + lm)) * 32 + lq * 8,
           wpk + WOFF_AW + ((size_t)(kt * 128 + (w + 4) * 16 + lm)) * 32 + lq * 8,
           acc, lm, lq);
  epi2(acc, ab, hbuf + 128, LSTR_H, w, lm, lq);
#pragma unroll
  for (int t = 0; t < 8; ++t) acc[t] = fz;
  kstep2(pbuf, LSTR_P, 128,
         wpk + WOFF_BW + ((size_t)(w * 16 + lm)) * 32 + lq * 8,
         wpk + WOFF_BW + ((size_t)((w + 4) * 16 + lm)) * 32 + lq * 8,
         acc, lm, lq);
  epi2(acc, bb, hbuf + 256, LSTR_H, w, lm, lq);

  // ---- preload all p1/p2 biases into registers (no vmem inside phases) ----
  float p1bv0[4], p1bv1[4], p2bv[4];
#pragma unroll
  for (int nc = 0; nc < 4; ++nc) {
    p1bv0[nc] = p1b[nc * 128 + w * 16 + lm];
    p1bv1[nc] = p1b[nc * 128 + (w + 4) * 16 + lm];
  }
#pragma unroll
  for (int s = 0; s < 4; ++s) p2bv[s] = p2b[w * 64 + s * 16 + lm];
  asm volatile("" : "+v"(p1bv0[0]), "+v"(p1bv0[1]), "+v"(p1bv0[2]),
                    "+v"(p1bv0[3]), "+v"(p1bv1[0]), "+v"(p1bv1[1]),
                    "+v"(p1bv1[2]), "+v"(p1bv1[3]), "+v"(p2bv[0]),
                    "+v"(p2bv[1]), "+v"(p2bv[2]), "+v"(p2bv[3]));

  // B-stream bases (per-lane)
  const bf16* bp0 = wpk + WOFF_P1 + ((size_t)(w * 16 + lm)) * 32 + lq * 8;
  const bf16* bp2 = wpk + WOFF_P2 +
      ((size_t)(((w >> 1) * 16) * 128 + (w & 1) * 64 + lm)) * 32 + lq * 8;

  floatx4 p1r0[4], p1r1[4];   // p1 B slots (4-slot, 3-kt lead)
  floatx4 p2r[3][4];          // p2 B slots (3-slot)

  // prologue: nc=0 p1 pairs kt=0..2 (6 loads) -- in flight across SYNCL
#pragma unroll
  for (int q = 0; q < 3; ++q) {
    gload(p1r0[q], bp0 + (size_t)q * 4096);
    gload(p1r1[q], bp0 + (size_t)q * 4096 + 2048);
  }
  SYNCL();   // hbuf visible; p1 B loads stay in flight

#pragma unroll
  for (int t = 0; t < 16; ++t) acc3[t] = fz;

#pragma unroll
  for (int nc = 0; nc < 4; ++nc) {
#pragma unroll
    for (int t = 0; t < 8; ++t) acc[t] = fz;

    // ---- p1: h[64,384] @ p1w[:, nc*128..+128) ----
    {
      bf16x8 an[2][4];
#pragma unroll
      for (int q = 0; q < 2; ++q)
#pragma unroll
        for (int mt = 0; mt < 4; ++mt)
          an[q][mt] = *(const bf16x8*)(hbuf + (mt * 16 + lm) * LSTR_H +
                                       q * 32 + lq * 8);
#pragma unroll
      for (int kt = 0; kt < 12; ++kt) {
        bf16x8 ac[4];
#pragma unroll
        for (int mt = 0; mt < 4; ++mt) ac[mt] = an[kt & 1][mt];
        if (kt < 10) {
#pragma unroll
          for (int mt = 0; mt < 4; ++mt)
            an[kt & 1][mt] = *(const bf16x8*)(hbuf + (mt * 16 + lm) * LSTR_H +
                                              (kt + 2) * 32 + lq * 8);
        }
        if (kt < 9) {
          gload(p1r0[(kt + 3) & 3], bp0 + (size_t)(nc * 12 + kt + 3) * 4096);
          gload(p1r1[(kt + 3) & 3],
                bp0 + (size_t)(nc * 12 + kt + 3) * 4096 + 2048);
        }
        if (kt < 9)       { VMW(6); }
        else if (kt == 9) { VMW(4); }
        else if (kt == 10){ VMW(2); }
        else              { VMW(0); }
        __builtin_amdgcn_s_setprio(1);
        bf16x8 b0 = bc8(p1r0[kt & 3]);
        bf16x8 b1 = bc8(p1r1[kt & 3]);
#pragma unroll
        for (int mt = 0; mt < 4; ++mt) {
          acc[mt * 2]     = mfma16(ac[mt], b0, acc[mt * 2]);
          acc[mt * 2 + 1] = mfma16(ac[mt], b1, acc[mt * 2 + 1]);
        }
        __builtin_amdgcn_s_setprio(0);
      }
    }

    // issue p2 B for kt2=0,1 BEFORE the barriers: hidden under them + epi2
#pragma unroll
    for (int q = 0; q < 2; ++q)
#pragma unroll
      for (int j = 0; j < 4; ++j)
        gload(p2r[q][j], bp2 + (size_t)(nc * 4 + q) * 4096 + j * 512);

    SYNCL();                       // prior p2 reads of pbuf done (lgkm only)
    epi2v(acc, p1bv0[nc], p1bv1[nc], pbuf, LSTR_H2, w, lm, lq);
    SYNCL();                       // h2 chunk visible (lgkm only)

    // ---- p2: h2chunk[64,128] @ p2w chunk, acc3 accumulate ----
    {
      bf16x8 an2[2][4];
#pragma unroll
      for (int q = 0; q < 2; ++q)
#pragma unroll
        for (int mt = 0; mt < 4; ++mt)
          an2[q][mt] = *(const bf16x8*)(pbuf + (mt * 16 + lm) * LSTR_H2 +
                                        q * 32 + lq * 8);
#pragma unroll
      for (int kt2 = 0; kt2 < 4; ++kt2) {
        bf16x8 ac[4];
#pragma unroll
        for (int mt = 0; mt < 4; ++mt) ac[mt] = an2[kt2 & 1][mt];
        if (kt2 < 2) {
#pragma unroll
          for (int mt = 0; mt < 4; ++mt)
            an2[kt2 & 1][mt] = *(const bf16x8*)(pbuf + (mt * 16 + lm) * LSTR_H2 +
                                                (kt2 + 2) * 32 + lq * 8);
#pragma unroll
          for (int j = 0; j < 4; ++j)
            gload(p2r[(kt2 + 2) % 3][j],
                  bp2 + (size_t)(nc * 4 + kt2 + 2) * 4096 + j * 512);
        }
        if (kt2 == 1) {
          // next nc's p1 prologue (dummy wrap at nc=3 keeps counts invariant)
          const int ncn = (nc + 1) & 3;
#pragma unroll
          for (int q = 0; q < 3; ++q) {
            gload(p1r0[q], bp0 + (size_t)(ncn * 12 + q) * 4096);
            gload(p1r1[q], bp0 + (size_t)(ncn * 12 + q) * 4096 + 2048);
          }
        }
        if (kt2 == 0)      { VMW(8); }
        else if (kt2 == 1) { VMW(14); }
        else if (kt2 == 2) { VMW(10); }
        else               { VMW(6); }
        __builtin_amdgcn_s_setprio(1);
#pragma unroll
        for (int mt = 0; mt < 4; ++mt)
#pragma unroll
          for (int j = 0; j < 4; ++j)
            acc3[mt * 4 + j] =
                mfma16(ac[mt], bc8(p2r[kt2 % 3][j]), acc3[mt * 4 + j]);
        __builtin_amdgcn_s_setprio(0);
      }
    }
  }

  // ---- masked row-sums of h3 = relu(acc3 + p2b), straight from registers ----
  const int s0 = (64 * blk) / 100;
  const int sp = (s0 + 1) * 100 - 64 * blk;
  floatx4 msk[4];
#pragma unroll
  for (int mt = 0; mt < 4; ++mt)
#pragma unroll
    for (int r = 0; r < 4; ++r)
      msk[mt][r] = (mt * 16 + lq * 4 + r < sp) ? 1.f : 0.f;

#pragma unroll
  for (int s = 0; s < 4; ++s) {
    int cl = w * 64 + s * 16 + lm;
    float bv = p2bv[s];
    float tot = 0.f, cs0 = 0.f;
#pragma unroll
    for (int mt = 0; mt < 4; ++mt) {
      floatx4 c = acc3[mt * 4 + s];
#pragma unroll
      for (int r = 0; r < 4; ++r) {
        float v = c[r] + bv;
        v = v > 0.f ? v : 0.f;
        tot += v;
        cs0 = fmaf(v, msk[mt][r], cs0);
      }
    }
    float cs1 = tot - cs0;
    cs0 += __shfl_xor(cs0, 16, 64);
    cs0 += __shfl_xor(cs0, 32, 64);
    cs1 += __shfl_xor(cs1, 16, 64);
    cs1 += __shfl_xor(cs1, 32, 64);
    if (lq == 0) {
      hsum[(size_t)(2 * blk) * 256 + cl]     = cs0;
      hsum[(size_t)(2 * blk + 1) * 256 + cl] = cs1;
    }
  }
}

// ---------------------------------------------------------------------------
// tail_kernel: mid+head1+head2 fused. (byte-identical to v13/v14)
// ---------------------------------------------------------------------------
__global__ __launch_bounds__(512, 2) void tail_kernel(
    const bf16* __restrict__ wpk, const float* __restrict__ hsum,
    const int* __restrict__ idxp, const float* __restrict__ p3b,
    const float* __restrict__ f1b, const float* __restrict__ f2b,
    const float* __restrict__ f3w, const float* __restrict__ f3b,
    float* __restrict__ out) {
  __shared__ __align__(16) bf16 ms[16 * LSTR_MS];
  __shared__ __align__(16) bf16 hp[16 * 1032];
  __shared__ __align__(16) bf16 h2s[16 * 520];
  __shared__ __align__(16) bf16 h3s[16 * 40];

  const int tid = threadIdx.x;
  const int w = tid >> 6;          // 0..7
  const int lane = tid & 63;
  const int lm = lane & 15;
  const int lq = lane >> 4;
  const int r0 = blockIdx.x * 16;
  const floatx4 fz = {0.f, 0.f, 0.f, 0.f};

  for (int i = tid; i < 16 * 64; i += 512) {
    int row = i >> 6, c4 = i & 63;
    int seg = r0 + row;
    int b_lo = (100 * seg) >> 6;
    int b_hi = (100 * seg + 99) >> 6;
    float4 sa = {0.f, 0.f, 0.f, 0.f};
    for (int b = b_lo; b <= b_hi; ++b) {
      int slot = (64 * b >= 100 * seg) ? 0 : 1;
      float4 v = *(const float4*)(hsum + (size_t)(2 * b + slot) * 256 + c4 * 4);
      sa.x += v.x; sa.y += v.y; sa.z += v.z; sa.w += v.w;
    }
    float inv = 1.f / (float)idxp[seg];
    bf16x4 o = {(bf16)(sa.x * inv), (bf16)(sa.y * inv),
                (bf16)(sa.z * inv), (bf16)(sa.w * inv)};
    *(bf16x4*)(ms + row * LSTR_MS + c4 * 4) = o;
  }
  __syncthreads();

#pragma unroll
  for (int nt2 = 0; nt2 < 4; ++nt2) {
    floatx4 a2[2];
    a2[0] = fz; a2[1] = fz;
#pragma unroll
    for (int kt = 0; kt < 8; ++kt) {
      bf16x8 a = *(const bf16x8*)(ms + lm * LSTR_MS + kt * 32 + lq * 8);
#pragma unroll
      for (int j = 0; j < 2; ++j) {
        bf16x8 b = *(const bf16x8*)(wpk + WOFF_P3 +
            ((size_t)((w * 8 + kt) * 128 + (nt2 * 2 + j) * 16 + lm)) * 32 +
            lq * 8);
        a2[j] = mfma16(a, b, a2[j]);
      }
    }
#pragma unroll
    for (int j = 0; j < 2; ++j) {
      int col = w * 128 + (nt2 * 2 + j) * 16 + lm;
      float bv = p3b[col];
#pragma unroll
      for (int r = 0; r < 4; ++r)
        hp[(lq * 4 + r) * 1032 + col] = (bf16)(a2[j][r] + bv);
    }
  }
  __syncthreads();

  {
    floatx4 a4[4];
#pragma unroll
    for (int j = 0; j < 4; ++j) a4[j] = fz;
#pragma unroll 8
    for (int kt = 0; kt < 32; ++kt) {
      bf16x8 a = *(const bf16x8*)(hp + lm * 1032 + kt * 32 + lq * 8);
#pragma unroll
      for (int j = 0; j < 4; ++j) {
        bf16x8 b = *(const bf16x8*)(wpk + WOFF_F1 +
            ((size_t)(((w >> 1) * 32 + kt) * 128 + (w & 1) * 64 + j * 16 + lm)) * 32 +
            lq * 8);
        a4[j] = mfma16(a, b, a4[j]);
      }
    }
#pragma unroll
    for (int j = 0; j < 4; ++j) {
      int col = w * 64 + j * 16 + lm;
      float bv = f1b[col];
#pragma unroll
      for (int r = 0; r < 4; ++r) {
        float v = a4[j][r] + bv;
        v = v > 0.f ? v : 0.f;
        h2s[(lq * 4 + r) * 520 + col] = (bf16)v;
      }
    }
  }
  __syncthreads();

  if (w < 2) {
    floatx4 c2 = fz;
#pragma unroll
    for (int kt = 0; kt < 16; ++kt) {
      bf16x8 a = *(const bf16x8*)(h2s + lm * 520 + kt * 32 + lq * 8);
      bf16x8 b = *(const bf16x8*)(wpk + WOFF_F2 +
                    ((size_t)(kt * 32 + w * 16 + lm)) * 32 + lq * 8);
      c2 = mfma16(a, b, c2);
    }
    int col = w * 16 + lm;
    float bv = f2b[col];
#pragma unroll
    for (int r = 0; r < 4; ++r) {
      float v = c2[r] + bv;
      v = v > 0.f ? v : 0.f;
      h3s[(lq * 4 + r) * 40 + col] = (bf16)v;
    }
  }
  __syncthreads();
  if (w == 0) {
    float ps = 0.f;
#pragma unroll
    for (int jj = 0; jj < 8; ++jj)
      ps += (float)h3s[lm * 40 + lq * 8 + jj] * f3w[lq * 8 + jj];
    ps += __shfl_xor(ps, 16, 64);
    ps += __shfl_xor(ps, 32, 64);
    if (lq == 0) out[r0 + lm] = ps + f3b[0];
  }
}

// ---------------------------------------------------------------------------
extern "C" void kernel_launch(void* const* d_in, const int* in_sizes, int n_in,
                              void* d_out, int out_size, void* d_ws,
                              size_t ws_size, hipStream_t stream) {
  (void)in_sizes; (void)n_in; (void)out_size; (void)ws_size;
  const float* pairs = (const float*)d_in[0];
  const int*   idxp  = (const int*)d_in[1];
  // d_in[2] = ref_feats (unused by the reference)
  const float* aw  = (const float*)d_in[3];
  const float* ab  = (const float*)d_in[4];
  const float* bw  = (const float*)d_in[5];
  const float* bb  = (const float*)d_in[6];
  const float* p1w = (const float*)d_in[7];
  const float* p1b = (const float*)d_in[8];
  const float* p2w = (const float*)d_in[9];
  const float* p2b = (const float*)d_in[10];
  const float* p3w = (const float*)d_in[11];
  const float* p3b = (const float*)d_in[12];
  const float* f1w = (const float*)d_in[13];
  const float* f1b = (const float*)d_in[14];
  const float* f2w = (const float*)d_in[15];
  const float* f2b = (const float*)d_in[16];
  const float* f3w = (const float*)d_in[17];
  const float* f3b = (const float*)d_in[18];

  bf16* wpk = (bf16*)d_ws;
  float* hsum = (float*)(wpk + WOFF_HS);

  pack_lds<<<566, 256, 0, stream>>>(aw, bw, p1w, p2w, p3w, f1w, f2w, wpk);
  seg_kernel<<<NWIN, 256, 0, stream>>>(pairs, ab, bb, p1b, p2b, wpk, hsum);
  tail_kernel<<<125, 512, 0, stream>>>(wpk, hsum, idxp, p3b, f1b, f2b, f3w,
                                       f3b, (float*)d_out);
}

// Round 9
// 387.009 us; speedup vs baseline: 2.1552x; 1.0322x over previous
//
#include <hip/hip_runtime.h>
#include <cstdint>
#include <cstddef>

// ---------------------------------------------------------------------------
// TGNN fused pipeline v16 = v15 with seg's p1/p2 converted from
// mfma_f32_16x16x32_bf16 to mfma_f32_32x32x16_bf16.
// v15 postmortem: MfmaUtil*dur invariant ~60 across v12-v15 -> scheduling is
// exhausted; the lever is matrix-cycle count. 32x32x16 runs 4061 F/cyc/CU
// (m119 2495 TF) vs 16x16x32's 3377 (m06) = -16% matrix cycles, and halves
// MFMA instruction count (issue slots freed for ds_read/gload stream).
// Same A-read count/kt, same B-load count/kt -> v15's PROVEN vmcnt schedule
// (4-slot p1 w/ waits 6/4/2/0; 3-slot p2 w/ waits 8/14/10/6; 6-load
// prologue hoisted into prior p2) is carried over verbatim.
// Layouts: p1w/p2w repacked to 1KB chunks per (32-col group g, kt, k-half h):
// elem(c,k) at lane=c+32*(k>>3), j=k&7 -> gload = base+lane*16B, fully
// coalesced. A frag: row=lane&31, k=(lane>>5)*8+j (family pattern verified by
// the working 16x16 path). C/D: col=lane&31, row=(reg&3)+8*(reg>>2)+
// 4*(lane>>5) [m74/m101-verified]. Embed stays 16x16 (40/680 MFMA); tail and
// aw/bw/p3w/f1w/f2w packing untouched.
// Tripwires: absmax 0 (operand layout); WRITE_SIZE exactly 6250KB (spill);
// SQ_LDS_BANK_CONFLICT may rise <=1.5x (32-row reads 4-way-balanced).
// ---------------------------------------------------------------------------

typedef __bf16 bf16;
typedef __attribute__((ext_vector_type(8))) __bf16 bf16x8;
typedef __attribute__((ext_vector_type(4))) __bf16 bf16x4;
typedef __attribute__((ext_vector_type(4))) float floatx4;
typedef __attribute__((ext_vector_type(16))) float floatx16;

#define GRP 100
#define NWIN 3125        // 200000 rows / 64

// packed-ws element offsets (bf16 elements)
#define WOFF_AW 0
#define WOFF_BW 8192
#define WOFF_P1 12288
#define WOFF_P2 208896
#define WOFF_P3 339968
#define WOFF_F1 602112
#define WOFF_F2 1126400
#define WOFF_HS 1142784          // hsum [6250][256] f32 (2 bf16 elems each)

// LDS strides (bf16 elems): %8==0 (16B-aligned b128 rows)
#define LSTR_P  168
#define LSTR_H  392
#define LSTR_H2 136
#define LSTR_MS 264

static __device__ __forceinline__ floatx4 mfma16(bf16x8 a, bf16x8 b, floatx4 c) {
  return __builtin_amdgcn_mfma_f32_16x16x32_bf16(a, b, c, 0, 0, 0);
}
static __device__ __forceinline__ floatx16 mfma32(bf16x8 a, bf16x8 b, floatx16 c) {
  return __builtin_amdgcn_mfma_f32_32x32x16_bf16(a, b, c, 0, 0, 0);
}

// async B-load: 16B global -> 4 VGPR; completion tracked ONLY by our vmcnt
static __device__ __forceinline__ void gload(floatx4& d, const bf16* p) {
  asm volatile("global_load_dwordx4 %0, %1, off" : "=v"(d) : "v"(p));
}
static __device__ __forceinline__ bf16x8 bc8(floatx4 v) {
  return __builtin_bit_cast(bf16x8, v);
}

// wait until <=N of our asm loads outstanding, then fence the scheduler so
// MFMAs can't hoist above the wait (guide rule #18)
#define VMW(N)                                         \
  do {                                                 \
    asm volatile("s_waitcnt vmcnt(" #N ")");           \
    __builtin_amdgcn_sched_barrier(0);                 \
  } while (0)

// barrier with LDS-only drain: global loads stay in flight across it
#define SYNCL()                                        \
  do {                                                 \
    asm volatile("s_waitcnt lgkmcnt(0)" ::: "memory"); \
    __builtin_amdgcn_s_barrier();                      \
  } while (0)

// ---------------------------------------------------------------------------
// Coalesced weight repack. Old layout (aw/bw/p3w/f1w/f2w): 32k x 64n tiles,
// dest ((nc*KT+kt)*128 + nl)*32 + kk, CW=128. NEW layout (p1w/p2w only):
// 1KB chunk per (g=32-col group, kt, h=k-half16): elem(c, k16) at
// chunk + (c + 32*(k16>>3))*8 + (k16&7), chunk = ((g*KT+kt)*2+h)*512.
// ---------------------------------------------------------------------------
__global__ __launch_bounds__(256) void pack_lds(
    const float* __restrict__ aw, const float* __restrict__ bw,
    const float* __restrict__ p1w, const float* __restrict__ p2w,
    const float* __restrict__ p3w, const float* __restrict__ f1w,
    const float* __restrict__ f2w, bf16* __restrict__ wpk) {
  __shared__ float t[32][65];
  const int tid = threadIdx.x;
  int b = blockIdx.x;

  if (b < 550) {
    const float* src; int dstoff, K, N, tt;
    bool newf = false;
    if (b < 4)        { src = aw;  dstoff = WOFF_AW; K = 64;   N = 128;  tt = b; }
    else if (b < 6)   { src = bw;  dstoff = WOFF_BW; K = 32;   N = 128;  tt = b - 4; }
    else if (b < 102) { src = p1w; dstoff = WOFF_P1; K = 384;  N = 512;  tt = b - 6;   newf = true; }
    else if (b < 166) { src = p2w; dstoff = WOFF_P2; K = 512;  N = 256;  tt = b - 102; newf = true; }
    else if (b < 294) { src = p3w; dstoff = WOFF_P3; K = 256;  N = 1024; tt = b - 166; }
    else              { src = f1w; dstoff = WOFF_F1; K = 1024; N = 512;  tt = b - 294; }
    const int KT = K >> 5;
    const int kt = tt % KT;
    const int n0 = (tt / KT) * 64;
    for (int i = tid; i < 2048; i += 256) {
      int r = i >> 6, c = i & 63;
      t[r][c] = src[(size_t)(kt * 32 + r) * N + n0 + c];
    }
    __syncthreads();
    if (newf) {
      // new 32x32-MFMA layout
      const int cpp = tid & 63, rb = tid >> 6;      // col-in-64, k-oct
      const int g = (n0 >> 5) + (cpp >> 5);
      const int c = cpp & 31;
      bf16x8 v;
#pragma unroll
      for (int i = 0; i < 8; ++i) v[i] = (bf16)t[rb * 8 + i][cpp];
      *(bf16x8*)(wpk + dstoff +
                 (((size_t)g * KT + kt) * 2 + (rb >> 1)) * 512 +
                 (c + 32 * (rb & 1)) * 8) = v;
    } else {
      const int nc = n0 >> 7, nl0 = n0 & 127;
      bf16* dst = wpk + dstoff + ((size_t)(nc * KT + kt) * 128 + nl0) * 32;
      int o = tid * 8;
      int nl = o >> 5, kk = o & 31;
      bf16x8 v;
#pragma unroll
      for (int i = 0; i < 8; ++i) v[i] = (bf16)t[kk + i][nl];
      *(bf16x8*)(dst + nl * 32 + kk) = v;
    }
  } else {
    const int kt = b - 550;
    for (int i = tid; i < 1024; i += 256) {
      int r = i >> 5, c = i & 31;
      t[r][c] = f2w[(size_t)(kt * 32 + r) * 32 + c];
    }
    __syncthreads();
    if (tid < 128) {
      int o = tid * 8;
      int nl = o >> 5, kk = o & 31;
      bf16x8 v;
#pragma unroll
      for (int i = 0; i < 8; ++i) v[i] = (bf16)t[kk + i][nl];
      *(bf16x8*)(wpk + WOFF_F2 + kt * 1024 + nl * 32 + kk) = v;
    }
  }
}

// kstep, 2 B-frags from global: 4 A-reads, 8 MFMA (M=64) -- embed phase only
static __device__ __forceinline__ void kstep2(const bf16* __restrict__ Ab,
                                              int astride, int acol,
                                              const bf16* __restrict__ b0p,
                                              const bf16* __restrict__ b1p,
                                              floatx4* acc, int lm, int lq) {
  bf16x8 b0 = *(const bf16x8*)b0p;
  bf16x8 b1 = *(const bf16x8*)b1p;
#pragma unroll
  for (int mt = 0; mt < 4; ++mt) {
    bf16x8 a = *(const bf16x8*)(Ab + (mt * 16 + lm) * astride + acol + lq * 8);
    acc[mt * 2]     = mfma16(a, b0, acc[mt * 2]);
    acc[mt * 2 + 1] = mfma16(a, b1, acc[mt * 2 + 1]);
  }
}

// epilogue for 2-N-tile acc, pointer-bias version (embed only; 16x16 layout)
static __device__ __forceinline__ void epi2(const floatx4* acc,
                                            const float* __restrict__ bias,
                                            bf16* dst, int dstride, int w,
                                            int lm, int lq) {
#pragma unroll
  for (int mt = 0; mt < 4; ++mt)
#pragma unroll
    for (int j = 0; j < 2; ++j) {
      int col = (w + 4 * j) * 16 + lm;
      float bv = bias[col];
      floatx4 c = acc[mt * 2 + j];
#pragma unroll
      for (int r = 0; r < 4; ++r) {
        float v = c[r] + bv;
        v = v > 0.f ? v : 0.f;
        dst[(mt * 16 + lq * 4 + r) * dstride + col] = (bf16)v;
      }
    }
}

// ---------------------------------------------------------------------------
// seg_kernel: one block per 64-row WINDOW. Embed on 16x16 MFMA (unchanged);
// p1/p2 on 32x32x16 MFMA with v15's asm B-pipeline. Masked row-sums of
// h3 = relu(acc3+p2b) straight from registers -> hsum (f32). LDS 71680 B
// -> 2 blocks/CU.
// ---------------------------------------------------------------------------
__global__ __launch_bounds__(256, 2) void seg_kernel(
    const float* __restrict__ pairs, const float* __restrict__ ab,
    const float* __restrict__ bb, const float* __restrict__ p1b,
    const float* __restrict__ p2b, const bf16* __restrict__ wpk,
    float* __restrict__ hsum) {
  __shared__ __align__(16) bf16 hbuf[64 * LSTR_H];  // h[64,384]
  __shared__ __align__(16) bf16 pbuf[64 * LSTR_P];  // pairs bf16, then h2 chunk

  const int tid = threadIdx.x;
  const int w = tid >> 6;
  const int lane = tid & 63;
  const int lm = lane & 15;
  const int lq = lane >> 4;
  const int l31 = lane & 31;
  const int hi = lane >> 5;
  const int hi8 = hi * 8;
  const int ln8 = lane * 8;
  const int blk = blockIdx.x;

  // ---- stage pairs window [64,160] fp32 -> bf16 LDS (all rows valid) ----
  {
    const float4* src = (const float4*)(pairs + (size_t)blk * (64 * 160));
    for (int i = tid; i < 64 * 40; i += 256) {
      int row = i / 40;
      int c4 = (i - row * 40) * 4;
      float4 v = src[i];
      bf16x4 o = {(bf16)v.x, (bf16)v.y, (bf16)v.z, (bf16)v.w};
      *(bf16x4*)(pbuf + row * LSTR_P + c4) = o;
    }
  }
  SYNCL();

  const floatx4 fz = {0.f, 0.f, 0.f, 0.f};
  const floatx16 fz16 = {0.f, 0.f, 0.f, 0.f, 0.f, 0.f, 0.f, 0.f,
                         0.f, 0.f, 0.f, 0.f, 0.f, 0.f, 0.f, 0.f};
  floatx4 acc[8];

  // ---------------- embed: a1 / a2 / be -> hbuf[64,384] (16x16 path) ----
#pragma unroll
  for (int t = 0; t < 8; ++t) acc[t] = fz;
#pragma unroll
  for (int kt = 0; kt < 2; ++kt)
    kstep2(pbuf, LSTR_P, kt * 32,
           wpk + WOFF_AW + ((size_t)(kt * 128 + w * 16 + lm)) * 32 + lq * 8,
           wpk + WOFF_AW + ((size_t)(kt * 128 + (w + 4) * 16 + lm)) * 32 + lq * 8,
           acc, lm, lq);
  epi2(acc, ab, hbuf, LSTR_H, w, lm, lq);
#pragma unroll
  for (int t = 0; t < 8; ++t) acc[t] = fz;
#pragma unroll
  for (int kt = 0; kt < 2; ++kt)
    kstep2(pbuf, LSTR_P, 64 + kt * 32,
           wpk + WOFF_AW + ((size_t)(kt * 128 + w * 16 + lm)) * 32 + lq * 8,
           wpk + WOFF_AW + ((size_t)(kt * 128 + (w + 4) * 16 + lm)) * 32 + lq * 8,
           acc, lm, lq);
  epi2(acc, ab, hbuf + 128, LSTR_H, w, lm, lq);
#pragma unroll
  for (int t = 0; t < 8; ++t) acc[t] = fz;
  kstep2(pbuf, LSTR_P, 128,
         wpk + WOFF_BW + ((size_t)(w * 16 + lm)) * 32 + lq * 8,
         wpk + WOFF_BW + ((size_t)((w + 4) * 16 + lm)) * 32 + lq * 8,
         acc, lm, lq);
  epi2(acc, bb, hbuf + 256, LSTR_H, w, lm, lq);

  // ---- preload p1/p2 biases into registers (no vmem inside phases) ----
  // p1: wave col group gw = nc*4+w -> cols nc*128 + w*32 + l31 (one per nc)
  // p2: wave col groups {w, w+4} -> cols {w,w+4}*32 + l31
  float p1bv[4], p2bv[2];
#pragma unroll
  for (int nc = 0; nc < 4; ++nc) p1bv[nc] = p1b[nc * 128 + w * 32 + l31];
  p2bv[0] = p2b[w * 32 + l31];
  p2bv[1] = p2b[(w + 4) * 32 + l31];
  asm volatile("" : "+v"(p1bv[0]), "+v"(p1bv[1]), "+v"(p1bv[2]),
                    "+v"(p1bv[3]), "+v"(p2bv[0]), "+v"(p2bv[1]));

  floatx4 p1r0[4], p1r1[4];   // p1 B slots (4-slot, 3-kt lead; h=0 / h=1)
  floatx4 p2r[3][4];          // p2 B slots (3-slot; j = cg*2+h)
  floatx16 acc3[4];           // p2 out: [rg*2+cg], 64x64 per wave

  // prologue: nc=0 (gw=w) p1 chunks kt=0..2, h=0/1 -- in flight across SYNCL
#pragma unroll
  for (int q = 0; q < 3; ++q) {
    gload(p1r0[q], wpk + WOFF_P1 + (((size_t)w * 12 + q) * 2 + 0) * 512 + ln8);
    gload(p1r1[q], wpk + WOFF_P1 + (((size_t)w * 12 + q) * 2 + 1) * 512 + ln8);
  }
  SYNCL();   // hbuf visible; p1 B loads stay in flight

#pragma unroll
  for (int t = 0; t < 4; ++t) acc3[t] = fz16;

#pragma unroll
  for (int nc = 0; nc < 4; ++nc) {
    const int gw = nc * 4 + w;
    floatx16 acc2[2];
    acc2[0] = fz16; acc2[1] = fz16;

    // ---- p1: h[64,384] @ p1w cols gw*32..+32 (32x32x16) ----
    {
      bf16x8 an[2][4];   // [kt&1][rg*2+h]
#pragma unroll
      for (int q = 0; q < 2; ++q)
#pragma unroll
        for (int rg = 0; rg < 2; ++rg)
#pragma unroll
          for (int h = 0; h < 2; ++h)
            an[q][rg * 2 + h] = *(const bf16x8*)(
                hbuf + (rg * 32 + l31) * LSTR_H + q * 32 + h * 16 + hi8);
#pragma unroll
      for (int kt = 0; kt < 12; ++kt) {
        bf16x8 a00 = an[kt & 1][0], a01 = an[kt & 1][1];
        bf16x8 a10 = an[kt & 1][2], a11 = an[kt & 1][3];
        if (kt < 10) {
#pragma unroll
          for (int rg = 0; rg < 2; ++rg)
#pragma unroll
            for (int h = 0; h < 2; ++h)
              an[kt & 1][rg * 2 + h] = *(const bf16x8*)(
                  hbuf + (rg * 32 + l31) * LSTR_H + (kt + 2) * 32 + h * 16 + hi8);
        }
        if (kt < 9) {
          gload(p1r0[(kt + 3) & 3],
                wpk + WOFF_P1 + (((size_t)gw * 12 + kt + 3) * 2 + 0) * 512 + ln8);
          gload(p1r1[(kt + 3) & 3],
                wpk + WOFF_P1 + (((size_t)gw * 12 + kt + 3) * 2 + 1) * 512 + ln8);
        }
        if (kt < 9)       { VMW(6); }
        else if (kt == 9) { VMW(4); }
        else if (kt == 10){ VMW(2); }
        else              { VMW(0); }
        __builtin_amdgcn_s_setprio(1);
        bf16x8 b0 = bc8(p1r0[kt & 3]);
        bf16x8 b1 = bc8(p1r1[kt & 3]);
        acc2[0] = mfma32(a00, b0, acc2[0]);
        acc2[1] = mfma32(a10, b0, acc2[1]);
        acc2[0] = mfma32(a01, b1, acc2[0]);
        acc2[1] = mfma32(a11, b1, acc2[1]);
        __builtin_amdgcn_s_setprio(0);
      }
    }

    // issue p2 B for kt2=0,1 BEFORE the barriers: hidden under them + epi
#pragma unroll
    for (int q = 0; q < 2; ++q)
#pragma unroll
      for (int cg = 0; cg < 2; ++cg)
#pragma unroll
        for (int h = 0; h < 2; ++h)
          gload(p2r[q][cg * 2 + h],
                wpk + WOFF_P2 +
                    (((size_t)(cg ? w + 4 : w) * 16 + nc * 4 + q) * 2 + h) * 512 +
                    ln8);

    SYNCL();                       // prior p2 reads of pbuf done (lgkm only)
    // p1 epilogue: relu(acc2 + p1bv) -> pbuf h2 chunk, 32x32 C/D layout
    {
      float bv = p1bv[nc];
#pragma unroll
      for (int rg = 0; rg < 2; ++rg)
#pragma unroll
        for (int r = 0; r < 16; ++r) {
          float v = acc2[rg][r] + bv;
          v = v > 0.f ? v : 0.f;
          int row = rg * 32 + (r & 3) + 8 * (r >> 2) + 4 * hi;
          pbuf[row * LSTR_H2 + w * 32 + l31] = (bf16)v;
        }
    }
    SYNCL();                       // h2 chunk visible (lgkm only)

    // ---- p2: h2chunk[64,128] @ p2w chunk -> acc3 (32x32x16) ----
    {
      bf16x8 an2[2][4];   // [kt2&1][rg*2+h]
#pragma unroll
      for (int q = 0; q < 2; ++q)
#pragma unroll
        for (int rg = 0; rg < 2; ++rg)
#pragma unroll
          for (int h = 0; h < 2; ++h)
            an2[q][rg * 2 + h] = *(const bf16x8*)(
                pbuf + (rg * 32 + l31) * LSTR_H2 + q * 32 + h * 16 + hi8);
#pragma unroll
      for (int kt2 = 0; kt2 < 4; ++kt2) {
        bf16x8 ac[4];
#pragma unroll
        for (int f = 0; f < 4; ++f) ac[f] = an2[kt2 & 1][f];
        if (kt2 < 2) {
#pragma unroll
          for (int rg = 0; rg < 2; ++rg)
#pragma unroll
            for (int h = 0; h < 2; ++h)
              an2[kt2 & 1][rg * 2 + h] = *(const bf16x8*)(
                  pbuf + (rg * 32 + l31) * LSTR_H2 + (kt2 + 2) * 32 + h * 16 + hi8);
#pragma unroll
          for (int cg = 0; cg < 2; ++cg)
#pragma unroll
            for (int h = 0; h < 2; ++h)
              gload(p2r[(kt2 + 2) % 3][cg * 2 + h],
                    wpk + WOFF_P2 +
                        (((size_t)(cg ? w + 4 : w) * 16 + nc * 4 + kt2 + 2) * 2 + h) *
                            512 + ln8);
        }
        if (kt2 == 1) {
          // next nc's p1 prologue (dummy wrap at nc=3 keeps counts invariant)
          const int gn = ((nc + 1) & 3) * 4 + w;
#pragma unroll
          for (int q = 0; q < 3; ++q) {
            gload(p1r0[q],
                  wpk + WOFF_P1 + (((size_t)gn * 12 + q) * 2 + 0) * 512 + ln8);
            gload(p1r1[q],
                  wpk + WOFF_P1 + (((size_t)gn * 12 + q) * 2 + 1) * 512 + ln8);
          }
        }
        if (kt2 == 0)      { VMW(8); }
        else if (kt2 == 1) { VMW(14); }
        else if (kt2 == 2) { VMW(10); }
        else               { VMW(6); }
        __builtin_amdgcn_s_setprio(1);
#pragma unroll
        for (int h = 0; h < 2; ++h) {
          bf16x8 b0 = bc8(p2r[kt2 % 3][0 * 2 + h]);
          bf16x8 b1 = bc8(p2r[kt2 % 3][1 * 2 + h]);
          acc3[0] = mfma32(ac[0 * 2 + h], b0, acc3[0]);   // rg0 cg0
          acc3[1] = mfma32(ac[0 * 2 + h], b1, acc3[1]);   // rg0 cg1
          acc3[2] = mfma32(ac[1 * 2 + h], b0, acc3[2]);   // rg1 cg0
          acc3[3] = mfma32(ac[1 * 2 + h], b1, acc3[3]);   // rg1 cg1
        }
        __builtin_amdgcn_s_setprio(0);
      }
    }
  }

  // ---- masked row-sums of h3 = relu(acc3 + p2b), 32x32 C/D layout ----
  // row = rg*32 + (r&3) + 8*(r>>2) + 4*hi; col = cg_col + l31.
  // Lanes l and l+32 hold complementary row halves of the same column ->
  // one shfl_xor(32) completes the column sum; lanes <32 store.
  const int s0 = (64 * blk) / 100;
  const int sp = (s0 + 1) * 100 - 64 * blk;

#pragma unroll
  for (int cg = 0; cg < 2; ++cg) {
    float bv = p2bv[cg];
    float tot = 0.f, cs0 = 0.f;
#pragma unroll
    for (int rg = 0; rg < 2; ++rg)
#pragma unroll
      for (int r = 0; r < 16; ++r) {
        float v = acc3[rg * 2 + cg][r] + bv;
        v = v > 0.f ? v : 0.f;
        tot += v;
        int row = rg * 32 + (r & 3) + 8 * (r >> 2) + 4 * hi;
        cs0 += (row < sp) ? v : 0.f;
      }
    float cs1 = tot - cs0;
    cs0 += __shfl_xor(cs0, 32, 64);
    cs1 += __shfl_xor(cs1, 32, 64);
    if (lane < 32) {
      int col = (cg ? w + 4 : w) * 32 + lane;
      hsum[(size_t)(2 * blk) * 256 + col]     = cs0;
      hsum[(size_t)(2 * blk + 1) * 256 + col] = cs1;
    }
  }
}

// ---------------------------------------------------------------------------
// tail_kernel: mid+head1+head2 fused. (byte-identical to v13-v15)
// ---------------------------------------------------------------------------
__global__ __launch_bounds__(512, 2) void tail_kernel(
    const bf16* __restrict__ wpk, const float* __restrict__ hsum,
    const int* __restrict__ idxp, const float* __restrict__ p3b,
    const float* __restrict__ f1b, const float* __restrict__ f2b,
    const float* __restrict__ f3w, const float* __restrict__ f3b,
    float* __restrict__ out) {
  __shared__ __align__(16) bf16 ms[16 * LSTR_MS];
  __shared__ __align__(16) bf16 hp[16 * 1032];
  __shared__ __align__(16) bf16 h2s[16 * 520];
  __shared__ __align__(16) bf16 h3s[16 * 40];

  const int tid = threadIdx.x;
  const int w = tid >> 6;          // 0..7
  const int lane = tid & 63;
  const int lm = lane & 15;
  const int lq = lane >> 4;
  const int r0 = blockIdx.x * 16;
  const floatx4 fz = {0.f, 0.f, 0.f, 0.f};

  for (int i = tid; i < 16 * 64; i += 512) {
    int row = i >> 6, c4 = i & 63;
    int seg = r0 + row;
    int b_lo = (100 * seg) >> 6;
    int b_hi = (100 * seg + 99) >> 6;
    float4 sa = {0.f, 0.f, 0.f, 0.f};
    for (int b = b_lo; b <= b_hi; ++b) {
      int slot = (64 * b >= 100 * seg) ? 0 : 1;
      float4 v = *(const float4*)(hsum + (size_t)(2 * b + slot) * 256 + c4 * 4);
      sa.x += v.x; sa.y += v.y; sa.z += v.z; sa.w += v.w;
    }
    float inv = 1.f / (float)idxp[seg];
    bf16x4 o = {(bf16)(sa.x * inv), (bf16)(sa.y * inv),
                (bf16)(sa.z * inv), (bf16)(sa.w * inv)};
    *(bf16x4*)(ms + row * LSTR_MS + c4 * 4) = o;
  }
  __syncthreads();

#pragma unroll
  for (int nt2 = 0; nt2 < 4; ++nt2) {
    floatx4 a2[2];
    a2[0] = fz; a2[1] = fz;
#pragma unroll
    for (int kt = 0; kt < 8; ++kt) {
      bf16x8 a = *(const bf16x8*)(ms + lm * LSTR_MS + kt * 32 + lq * 8);
#pragma unroll
      for (int j = 0; j < 2; ++j) {
        bf16x8 b = *(const bf16x8*)(wpk + WOFF_P3 +
            ((size_t)((w * 8 + kt) * 128 + (nt2 * 2 + j) * 16 + lm)) * 32 +
            lq * 8);
        a2[j] = mfma16(a, b, a2[j]);
      }
    }
#pragma unroll
    for (int j = 0; j < 2; ++j) {
      int col = w * 128 + (nt2 * 2 + j) * 16 + lm;
      float bv = p3b[col];
#pragma unroll
      for (int r = 0; r < 4; ++r)
        hp[(lq * 4 + r) * 1032 + col] = (bf16)(a2[j][r] + bv);
    }
  }
  __syncthreads();

  {
    floatx4 a4[4];
#pragma unroll
    for (int j = 0; j < 4; ++j) a4[j] = fz;
#pragma unroll 8
    for (int kt = 0; kt < 32; ++kt) {
      bf16x8 a = *(const bf16x8*)(hp + lm * 1032 + kt * 32 + lq * 8);
#pragma unroll
      for (int j = 0; j < 4; ++j) {
        bf16x8 b = *(const bf16x8*)(wpk + WOFF_F1 +
            ((size_t)(((w >> 1) * 32 + kt) * 128 + (w & 1) * 64 + j * 16 + lm)) * 32 +
            lq * 8);
        a4[j] = mfma16(a, b, a4[j]);
      }
    }
#pragma unroll
    for (int j = 0; j < 4; ++j) {
      int col = w * 64 + j * 16 + lm;
      float bv = f1b[col];
#pragma unroll
      for (int r = 0; r < 4; ++r) {
        float v = a4[j][r] + bv;
        v = v > 0.f ? v : 0.f;
        h2s[(lq * 4 + r) * 520 + col] = (bf16)v;
      }
    }
  }
  __syncthreads();

  if (w < 2) {
    floatx4 c2 = fz;
#pragma unroll
    for (int kt = 0; kt < 16; ++kt) {
      bf16x8 a = *(const bf16x8*)(h2s + lm * 520 + kt * 32 + lq * 8);
      bf16x8 b = *(const bf16x8*)(wpk + WOFF_F2 +
                    ((size_t)(kt * 32 + w * 16 + lm)) * 32 + lq * 8);
      c2 = mfma16(a, b, c2);
    }
    int col = w * 16 + lm;
    float bv = f2b[col];
#pragma unroll
    for (int r = 0; r < 4; ++r) {
      float v = c2[r] + bv;
      v = v > 0.f ? v : 0.f;
      h3s[(lq * 4 + r) * 40 + col] = (bf16)v;
    }
  }
  __syncthreads();
  if (w == 0) {
    float ps = 0.f;
#pragma unroll
    for (int jj = 0; jj < 8; ++jj)
      ps += (float)h3s[lm * 40 + lq * 8 + jj] * f3w[lq * 8 + jj];
    ps += __shfl_xor(ps, 16, 64);
    ps += __shfl_xor(ps, 32, 64);
    if (lq == 0) out[r0 + lm] = ps + f3b[0];
  }
}

// ---------------------------------------------------------------------------
extern "C" void kernel_launch(void* const* d_in, const int* in_sizes, int n_in,
                              void* d_out, int out_size, void* d_ws,
                              size_t ws_size, hipStream_t stream) {
  (void)in_sizes; (void)n_in; (void)out_size; (void)ws_size;
  const float* pairs = (const float*)d_in[0];
  const int*   idxp  = (const int*)d_in[1];
  // d_in[2] = ref_feats (unused by the reference)
  const float* aw  = (const float*)d_in[3];
  const float* ab  = (const float*)d_in[4];
  const float* bw  = (const float*)d_in[5];
  const float* bb  = (const float*)d_in[6];
  const float* p1w = (const float*)d_in[7];
  const float* p1b = (const float*)d_in[8];
  const float* p2w = (const float*)d_in[9];
  const float* p2b = (const float*)d_in[10];
  const float* p3w = (const float*)d_in[11];
  const float* p3b = (const float*)d_in[12];
  const float* f1w = (const float*)d_in[13];
  const float* f1b = (const float*)d_in[14];
  const float* f2w = (const float*)d_in[15];
  const float* f2b = (const float*)d_in[16];
  const float* f3w = (const float*)d_in[17];
  const float* f3b = (const float*)d_in[18];

  bf16* wpk = (bf16*)d_ws;
  float* hsum = (float*)(wpk + WOFF_HS);

  pack_lds<<<566, 256, 0, stream>>>(aw, bw, p1w, p2w, p3w, f1w, f2w, wpk);
  seg_kernel<<<NWIN, 256, 0, stream>>>(pairs, ab, bb, p1b, p2b, wpk, hsum);
  tail_kernel<<<125, 512, 0, stream>>>(wpk, hsum, idxp, p3b, f1b, f2b, f3w,
                                       f3b, (float*)d_out);
}